// Round 1
// baseline (2541.922 us; speedup 1.0000x reference)
//
#include <hip/hip_runtime.h>
#include <hip/hip_bf16.h>

// Problem constants
#define BATCH   2
#define SEQ     1024
#define DMODEL  1024
#define DINNER  2048
#define DSTATE  16
#define DTRANK  64
#define DCONV   4
#define NLAYERS 2
#define ROWS    (BATCH*SEQ)        // 2048 (b,l) rows

// ---------------------------------------------------------------------------
// RMSNorm: one block per row of DMODEL
__global__ __launch_bounds__(256) void rmsnorm_kernel(
    const float* __restrict__ x, const float* __restrict__ w,
    float* __restrict__ out)
{
  const int row = blockIdx.x;
  const float* xr = x + (size_t)row * DMODEL;
  float ss = 0.f;
  #pragma unroll
  for (int i = threadIdx.x; i < DMODEL; i += 256) { float v = xr[i]; ss += v * v; }
  #pragma unroll
  for (int m = 1; m < 64; m <<= 1) ss += __shfl_xor(ss, m);
  __shared__ float red[4];
  if ((threadIdx.x & 63) == 0) red[threadIdx.x >> 6] = ss;
  __syncthreads();
  float tot = red[0] + red[1] + red[2] + red[3];
  float scale = rsqrtf(tot * (1.f / DMODEL) + 1e-5f);
  #pragma unroll
  for (int i = threadIdx.x; i < DMODEL; i += 256)
    out[(size_t)row * DMODEL + i] = xr[i] * scale * w[i];
}

// ---------------------------------------------------------------------------
// Tiled fp32 GEMM: C[M][N] = A[M][K] * B[N][K]^T (+C if ACC). Exact tiling
// assumed: M%BM==0, N%BN==0, K%16==0.
template<int BM, int BN, int TM, int TN, bool ACC>
__global__ __launch_bounds__(256) void gemm_nt_kernel(
    const float* __restrict__ A, const float* __restrict__ B,
    float* __restrict__ C, int K, int lda, int ldb, int ldc)
{
  constexpr int BK = 16;
  constexpr int NX = BN / TN;        // threads along N
  __shared__ float As[BK][BM + 4];
  __shared__ float Bs[BK][BN + 4];
  const int tid = threadIdx.x;
  const int tx = tid % NX, ty = tid / NX;
  const int row0 = blockIdx.y * BM, col0 = blockIdx.x * BN;
  float acc[TM][TN] = {};

  for (int kb = 0; kb < K; kb += BK) {
    #pragma unroll
    for (int p = 0; p < BM / 64; ++p) {
      const int lr = tid / 4 + p * 64;
      const int lk = (tid % 4) * 4;
      const float4 v = *reinterpret_cast<const float4*>(
          &A[(size_t)(row0 + lr) * lda + kb + lk]);
      As[lk + 0][lr] = v.x; As[lk + 1][lr] = v.y;
      As[lk + 2][lr] = v.z; As[lk + 3][lr] = v.w;
    }
    #pragma unroll
    for (int p = 0; p < BN / 64; ++p) {
      const int lc = tid / 4 + p * 64;
      const int lk = (tid % 4) * 4;
      const float4 v = *reinterpret_cast<const float4*>(
          &B[(size_t)(col0 + lc) * ldb + kb + lk]);
      Bs[lk + 0][lc] = v.x; Bs[lk + 1][lc] = v.y;
      Bs[lk + 2][lc] = v.z; Bs[lk + 3][lc] = v.w;
    }
    __syncthreads();
    #pragma unroll
    for (int kk = 0; kk < BK; ++kk) {
      float a[TM], bf[TN];
      #pragma unroll
      for (int i = 0; i < TM / 4; ++i)
        *reinterpret_cast<float4*>(&a[i * 4]) =
            *reinterpret_cast<const float4*>(&As[kk][ty * TM + i * 4]);
      #pragma unroll
      for (int j = 0; j < TN / 4; ++j)
        *reinterpret_cast<float4*>(&bf[j * 4]) =
            *reinterpret_cast<const float4*>(&Bs[kk][tx * TN + j * 4]);
      #pragma unroll
      for (int i = 0; i < TM; ++i)
        #pragma unroll
        for (int j = 0; j < TN; ++j)
          acc[i][j] += a[i] * bf[j];
    }
    __syncthreads();
  }
  #pragma unroll
  for (int i = 0; i < TM; ++i) {
    const int r = row0 + ty * TM + i;
    #pragma unroll
    for (int j = 0; j < TN; ++j) {
      const int c = col0 + tx * TN + j;
      const size_t o = (size_t)r * ldc + c;
      C[o] = (ACC ? C[o] : 0.f) + acc[i][j];
    }
  }
}

// ---------------------------------------------------------------------------
// Depthwise causal conv (k=4) + bias + SiLU.  xz row-major (ROWS, 2*DINNER),
// first DINNER cols are the conv input; output xc (ROWS, DINNER).
__global__ __launch_bounds__(256) void conv_silu_kernel(
    const float* __restrict__ xz, const float* __restrict__ cw,
    const float* __restrict__ cb, float* __restrict__ xc)
{
  const int idx = blockIdx.x * 256 + threadIdx.x;  // over ROWS*DINNER
  const int e  = idx % DINNER;
  const int bl = idx / DINNER;
  const int l  = bl % SEQ;
  float acc = cb[e];
  #pragma unroll
  for (int k = 0; k < DCONV; ++k) {
    const int lk = l + k - (DCONV - 1);
    if (lk >= 0)
      acc += xz[(size_t)(bl + k - (DCONV - 1)) * (2 * DINNER) + e] * cw[e * DCONV + k];
  }
  xc[idx] = acc / (1.f + __expf(-acc));
}

// ---------------------------------------------------------------------------
// x_proj: dbc[row][j] = sum_k xc[row][k]*xpw[j][k], j<96.  4 rows per block.
__global__ __launch_bounds__(192) void xproj_kernel(
    const float* __restrict__ xc, const float* __restrict__ xpw,
    float* __restrict__ dbc)
{
  __shared__ float s[4 * DINNER];
  const int r0 = blockIdx.x * 4;
  const float4* src = reinterpret_cast<const float4*>(xc + (size_t)r0 * DINNER);
  for (int i = threadIdx.x; i < 4 * DINNER / 4; i += 192)
    reinterpret_cast<float4*>(s)[i] = src[i];
  __syncthreads();
  const int j  = threadIdx.x % 96;
  const int rh = threadIdx.x / 96;            // 0 or 1 -> rows rh*2, rh*2+1
  const float4* wj = reinterpret_cast<const float4*>(xpw + (size_t)j * DINNER);
  const float4* s0 = reinterpret_cast<const float4*>(s + (rh * 2 + 0) * DINNER);
  const float4* s1 = reinterpret_cast<const float4*>(s + (rh * 2 + 1) * DINNER);
  float a0 = 0.f, a1 = 0.f;
  for (int k4 = 0; k4 < DINNER / 4; ++k4) {
    const float4 w4 = wj[k4];
    const float4 x0 = s0[k4], x1 = s1[k4];
    a0 += w4.x * x0.x + w4.y * x0.y + w4.z * x0.z + w4.w * x0.w;
    a1 += w4.x * x1.x + w4.y * x1.y + w4.z * x1.z + w4.w * x1.w;
  }
  dbc[(size_t)(r0 + rh * 2 + 0) * 96 + j] = a0;
  dbc[(size_t)(r0 + rh * 2 + 1) * 96 + j] = a1;
}

// ---------------------------------------------------------------------------
// delta = softplus(delta_pre + bias[e]), in place
__global__ __launch_bounds__(256) void softplus_bias_kernel(
    float* __restrict__ delta, const float* __restrict__ bias)
{
  const int idx = blockIdx.x * 256 + threadIdx.x;
  const float v = delta[idx] + bias[idx % DINNER];
  delta[idx] = (v > 20.f) ? v : log1pf(__expf(v));
}

// ---------------------------------------------------------------------------
// Selective scan, 16 lanes per (b,e) channel (one per state), fused with
// D-skip and z gate.  Writes y*silu(z) in place over the delta buffer.
__global__ __launch_bounds__(256) void scan_kernel(
    float* __restrict__ delta,         // (ROWS, DINNER)  in/out
    const float* __restrict__ xc,      // (ROWS, DINNER)
    const float* __restrict__ dbc,     // (ROWS, 96): [64..80)=B, [80..96)=C
    const float* __restrict__ xz,      // (ROWS, 2*DINNER): z at col 2048+e
    const float* __restrict__ A_log,   // (DINNER, 16)
    const float* __restrict__ Dp)      // (DINNER)
{
  const int grp = blockIdx.x * 16 + (threadIdx.x >> 4);  // b*DINNER + e
  const int n = threadIdx.x & 15;
  const int b = grp / DINNER, e = grp % DINNER;
  const float Aen = -__expf(A_log[e * DSTATE + n]);
  const float dpe = Dp[e];
  float h = 0.f;
  const size_t rowE0 = (size_t)b * SEQ * DINNER + e;
  const size_t row96 = (size_t)b * SEQ * 96;
  const size_t rowZ0 = (size_t)b * SEQ * (2 * DINNER) + DINNER + e;
  for (int t = 0; t < SEQ; ++t) {
    const float dv = delta[rowE0 + (size_t)t * DINNER];
    const float xv = xc[rowE0 + (size_t)t * DINNER];
    const float Bv = dbc[row96 + t * 96 + DTRANK + n];
    const float Cv = dbc[row96 + t * 96 + DTRANK + DSTATE + n];
    const float dA = __expf(dv * Aen);
    h = dA * h + (dv * xv) * Bv;
    float p = h * Cv;
    p += __shfl_xor(p, 1);
    p += __shfl_xor(p, 2);
    p += __shfl_xor(p, 4);
    p += __shfl_xor(p, 8);
    if (n == 0) {
      const float y = p + dpe * xv;
      const float zv = xz[rowZ0 + (size_t)t * (2 * DINNER)];
      const float sz = zv / (1.f + __expf(-zv));
      delta[rowE0 + (size_t)t * DINNER] = y * sz;
    }
  }
}

// ---------------------------------------------------------------------------
extern "C" void kernel_launch(void* const* d_in, const int* in_sizes, int n_in,
                              void* d_out, int out_size, void* d_ws, size_t ws_size,
                              hipStream_t stream)
{
  const float* x         = (const float*)d_in[0];
  const float* norm_w    = (const float*)d_in[1];
  const float* in_proj_w = (const float*)d_in[2];
  const float* conv_w    = (const float*)d_in[3];
  const float* conv_b    = (const float*)d_in[4];
  const float* x_proj_w  = (const float*)d_in[5];
  const float* dt_proj_w = (const float*)d_in[6];
  const float* dt_proj_b = (const float*)d_in[7];
  const float* A_log     = (const float*)d_in[8];
  const float* D_param   = (const float*)d_in[9];
  const float* out_proj_w= (const float*)d_in[10];
  float* out = (float*)d_out;

  float* ws = (float*)d_ws;
  float* h_buf   = ws;                          // ROWS*DMODEL      = 2,097,152
  float* xz_buf  = h_buf  + (size_t)ROWS * DMODEL;   // ROWS*2*DINNER = 8,388,608
  float* xc_buf  = xz_buf + (size_t)ROWS * 2 * DINNER; // ROWS*DINNER = 4,194,304
  float* dbc_buf = xc_buf + (size_t)ROWS * DINNER;     // ROWS*96     =   196,608
  float* dl_buf  = dbc_buf + (size_t)ROWS * 96;        // ROWS*DINNER = 4,194,304

  // residual stream lives in d_out
  hipMemcpyAsync(out, x, (size_t)ROWS * DMODEL * sizeof(float),
                 hipMemcpyDeviceToDevice, stream);

  for (int layer = 0; layer < NLAYERS; ++layer) {
    const float* nw  = norm_w     + (size_t)layer * DMODEL;
    const float* iw  = in_proj_w  + (size_t)layer * 2 * DINNER * DMODEL;
    const float* cw  = conv_w     + (size_t)layer * DINNER * DCONV;
    const float* cb  = conv_b     + (size_t)layer * DINNER;
    const float* xpw = x_proj_w   + (size_t)layer * 96 * DINNER;
    const float* dtw = dt_proj_w  + (size_t)layer * DINNER * DTRANK;
    const float* dtb = dt_proj_b  + (size_t)layer * DINNER;
    const float* Al  = A_log      + (size_t)layer * DINNER * DSTATE;
    const float* Dpp = D_param    + (size_t)layer * DINNER;
    const float* ow  = out_proj_w + (size_t)layer * DMODEL * DINNER;

    // 1. h = rmsnorm(residual)
    rmsnorm_kernel<<<ROWS, 256, 0, stream>>>(out, nw, h_buf);

    // 2. xz = h @ in_w^T   (2048 x 4096 x 1024)
    gemm_nt_kernel<128, 128, 8, 8, false>
        <<<dim3(2 * DINNER / 128, ROWS / 128), 256, 0, stream>>>(
            h_buf, iw, xz_buf, DMODEL, DMODEL, DMODEL, 2 * DINNER);

    // 3. xc = silu(causal_conv(xz[:, :DINNER]) + cb)
    conv_silu_kernel<<<(size_t)ROWS * DINNER / 256, 256, 0, stream>>>(
        xz_buf, cw, cb, xc_buf);

    // 4. dbc = xc @ xpw^T  (2048 x 96 x 2048)
    xproj_kernel<<<ROWS / 4, 192, 0, stream>>>(xc_buf, xpw, dbc_buf);

    // 5. delta_pre = dbc[:, :64] @ dtw^T  (2048 x 2048 x 64)
    gemm_nt_kernel<128, 128, 8, 8, false>
        <<<dim3(DINNER / 128, ROWS / 128), 256, 0, stream>>>(
            dbc_buf, dtw, dl_buf, DTRANK, 96, DTRANK, DINNER);

    // 6. delta = softplus(delta_pre + dtb)
    softplus_bias_kernel<<<(size_t)ROWS * DINNER / 256, 256, 0, stream>>>(
        dl_buf, dtb);

    // 7. selective scan + D skip + z gate  (in place into dl_buf)
    scan_kernel<<<BATCH * DINNER * 16 / 256, 256, 0, stream>>>(
        dl_buf, xc_buf, dbc_buf, xz_buf, Al, Dpp);

    // 8. residual += yz @ ow^T  (2048 x 1024 x 2048)
    gemm_nt_kernel<128, 64, 8, 4, true>
        <<<dim3(DMODEL / 64, ROWS / 128), 256, 0, stream>>>(
            dl_buf, ow, out, DINNER, DINNER, DINNER, DMODEL);
  }
}

// Round 2
// 1366.375 us; speedup vs baseline: 1.8603x; 1.8603x over previous
//
#include <hip/hip_runtime.h>
#include <hip/hip_bf16.h>

// Problem constants
#define BATCH   2
#define SEQ     1024
#define DMODEL  1024
#define DINNER  2048
#define DSTATE  16
#define DTRANK  64
#define DCONV   4
#define NLAYERS 2
#define ROWS    (BATCH*SEQ)        // 2048 (b,l) rows
#define NCHUNK  16
#define CHUNK   64                 // SEQ / NCHUNK

// ---------------------------------------------------------------------------
// RMSNorm: one block per row of DMODEL
__global__ __launch_bounds__(256) void rmsnorm_kernel(
    const float* __restrict__ x, const float* __restrict__ w,
    float* __restrict__ out)
{
  const int row = blockIdx.x;
  const float* xr = x + (size_t)row * DMODEL;
  float ss = 0.f;
  #pragma unroll
  for (int i = threadIdx.x; i < DMODEL; i += 256) { float v = xr[i]; ss += v * v; }
  #pragma unroll
  for (int m = 1; m < 64; m <<= 1) ss += __shfl_xor(ss, m);
  __shared__ float red[4];
  if ((threadIdx.x & 63) == 0) red[threadIdx.x >> 6] = ss;
  __syncthreads();
  float tot = red[0] + red[1] + red[2] + red[3];
  float scale = rsqrtf(tot * (1.f / DMODEL) + 1e-5f);
  #pragma unroll
  for (int i = threadIdx.x; i < DMODEL; i += 256)
    out[(size_t)row * DMODEL + i] = xr[i] * scale * w[i];
}

// ---------------------------------------------------------------------------
// Tiled fp32 GEMM: C[M][N] = A[M][K] * B[N][K]^T (+C if ACC). Exact tiling
// assumed: M%BM==0, N%BN==0, K%16==0.
template<int BM, int BN, int TM, int TN, bool ACC>
__global__ __launch_bounds__(256) void gemm_nt_kernel(
    const float* __restrict__ A, const float* __restrict__ B,
    float* __restrict__ C, int K, int lda, int ldb, int ldc)
{
  constexpr int BK = 16;
  constexpr int NX = BN / TN;        // threads along N
  __shared__ float As[BK][BM + 4];
  __shared__ float Bs[BK][BN + 4];
  const int tid = threadIdx.x;
  const int tx = tid % NX, ty = tid / NX;
  const int row0 = blockIdx.y * BM, col0 = blockIdx.x * BN;
  float acc[TM][TN] = {};

  for (int kb = 0; kb < K; kb += BK) {
    #pragma unroll
    for (int p = 0; p < BM / 64; ++p) {
      const int lr = tid / 4 + p * 64;
      const int lk = (tid % 4) * 4;
      const float4 v = *reinterpret_cast<const float4*>(
          &A[(size_t)(row0 + lr) * lda + kb + lk]);
      As[lk + 0][lr] = v.x; As[lk + 1][lr] = v.y;
      As[lk + 2][lr] = v.z; As[lk + 3][lr] = v.w;
    }
    #pragma unroll
    for (int p = 0; p < BN / 64; ++p) {
      const int lc = tid / 4 + p * 64;
      const int lk = (tid % 4) * 4;
      const float4 v = *reinterpret_cast<const float4*>(
          &B[(size_t)(col0 + lc) * ldb + kb + lk]);
      Bs[lk + 0][lc] = v.x; Bs[lk + 1][lc] = v.y;
      Bs[lk + 2][lc] = v.z; Bs[lk + 3][lc] = v.w;
    }
    __syncthreads();
    #pragma unroll
    for (int kk = 0; kk < BK; ++kk) {
      float a[TM], bf[TN];
      #pragma unroll
      for (int i = 0; i < TM / 4; ++i)
        *reinterpret_cast<float4*>(&a[i * 4]) =
            *reinterpret_cast<const float4*>(&As[kk][ty * TM + i * 4]);
      #pragma unroll
      for (int j = 0; j < TN / 4; ++j)
        *reinterpret_cast<float4*>(&bf[j * 4]) =
            *reinterpret_cast<const float4*>(&Bs[kk][tx * TN + j * 4]);
      #pragma unroll
      for (int i = 0; i < TM; ++i)
        #pragma unroll
        for (int j = 0; j < TN; ++j)
          acc[i][j] += a[i] * bf[j];
    }
    __syncthreads();
  }
  #pragma unroll
  for (int i = 0; i < TM; ++i) {
    const int r = row0 + ty * TM + i;
    #pragma unroll
    for (int j = 0; j < TN; ++j) {
      const int c = col0 + tx * TN + j;
      const size_t o = (size_t)r * ldc + c;
      C[o] = (ACC ? C[o] : 0.f) + acc[i][j];
    }
  }
}

// ---------------------------------------------------------------------------
// Depthwise causal conv (k=4) + bias + SiLU.  xz row-major (ROWS, 2*DINNER),
// first DINNER cols are the conv input; output xc (ROWS, DINNER).
__global__ __launch_bounds__(256) void conv_silu_kernel(
    const float* __restrict__ xz, const float* __restrict__ cw,
    const float* __restrict__ cb, float* __restrict__ xc)
{
  const int idx = blockIdx.x * 256 + threadIdx.x;  // over ROWS*DINNER
  const int e  = idx % DINNER;
  const int bl = idx / DINNER;
  const int l  = bl % SEQ;
  float acc = cb[e];
  #pragma unroll
  for (int k = 0; k < DCONV; ++k) {
    const int lk = l + k - (DCONV - 1);
    if (lk >= 0)
      acc += xz[(size_t)(bl + k - (DCONV - 1)) * (2 * DINNER) + e] * cw[e * DCONV + k];
  }
  xc[idx] = acc / (1.f + __expf(-acc));
}

// ---------------------------------------------------------------------------
// x_proj: dbc[row][j] = sum_k xc[row][k]*xpw[j][k], j<96.  4 rows per block.
__global__ __launch_bounds__(192) void xproj_kernel(
    const float* __restrict__ xc, const float* __restrict__ xpw,
    float* __restrict__ dbc)
{
  __shared__ float s[4 * DINNER];
  const int r0 = blockIdx.x * 4;
  const float4* src = reinterpret_cast<const float4*>(xc + (size_t)r0 * DINNER);
  for (int i = threadIdx.x; i < 4 * DINNER / 4; i += 192)
    reinterpret_cast<float4*>(s)[i] = src[i];
  __syncthreads();
  const int j  = threadIdx.x % 96;
  const int rh = threadIdx.x / 96;            // 0 or 1 -> rows rh*2, rh*2+1
  const float4* wj = reinterpret_cast<const float4*>(xpw + (size_t)j * DINNER);
  const float4* s0 = reinterpret_cast<const float4*>(s + (rh * 2 + 0) * DINNER);
  const float4* s1 = reinterpret_cast<const float4*>(s + (rh * 2 + 1) * DINNER);
  float a0 = 0.f, a1 = 0.f;
  for (int k4 = 0; k4 < DINNER / 4; ++k4) {
    const float4 w4 = wj[k4];
    const float4 x0 = s0[k4], x1 = s1[k4];
    a0 += w4.x * x0.x + w4.y * x0.y + w4.z * x0.z + w4.w * x0.w;
    a1 += w4.x * x1.x + w4.y * x1.y + w4.z * x1.z + w4.w * x1.w;
  }
  dbc[(size_t)(r0 + rh * 2 + 0) * 96 + j] = a0;
  dbc[(size_t)(r0 + rh * 2 + 1) * 96 + j] = a1;
}

// ---------------------------------------------------------------------------
// delta = softplus(delta_pre + bias[e]), in place
__global__ __launch_bounds__(256) void softplus_bias_kernel(
    float* __restrict__ delta, const float* __restrict__ bias)
{
  const int idx = blockIdx.x * 256 + threadIdx.x;
  const float v = delta[idx] + bias[idx % DINNER];
  delta[idx] = (v > 20.f) ? v : log1pf(__expf(v));
}

// ---------------------------------------------------------------------------
// Chunked selective scan, pass A: per-(b,e,chunk) local scan from h=0.
// 16 lanes per group (one per state n).  Emits chunk decay product P and
// chunk-final local state hfin, layout [b][e][chunk][n].
__global__ __launch_bounds__(256) void scan_chunk_kernel(
    const float* __restrict__ delta,   // (ROWS, DINNER) softplus'd
    const float* __restrict__ xc,      // (ROWS, DINNER)
    const float* __restrict__ dbc,     // (ROWS, 96): [64..80)=B
    const float* __restrict__ A_log,   // (DINNER, 16)
    float* __restrict__ Pbuf,          // (BATCH, DINNER, NCHUNK, 16)
    float* __restrict__ Hbuf)          // (BATCH, DINNER, NCHUNK, 16)
{
  const int g  = blockIdx.x * 16 + (threadIdx.x >> 4); // ((b*NCHUNK+c)*DINNER+e)
  const int n  = threadIdx.x & 15;
  const int e  = g % DINNER;
  const int bc = g / DINNER;
  const int c  = bc % NCHUNK;
  const int b  = bc / NCHUNK;
  const float Aen = -__expf(A_log[e * DSTATE + n]);
  float h = 0.f, sd = 0.f;
  const size_t rowE  = ((size_t)b * SEQ + c * CHUNK) * DINNER + e;
  const size_t row96 = ((size_t)b * SEQ + c * CHUNK) * 96;
  for (int t = 0; t < CHUNK; ++t) {
    const float dv = delta[rowE + (size_t)t * DINNER];
    const float xv = xc[rowE + (size_t)t * DINNER];
    const float Bv = dbc[row96 + t * 96 + DTRANK + n];
    const float dA = __expf(dv * Aen);
    h = dA * h + (dv * xv) * Bv;
    sd += dv;
  }
  const size_t o = (((size_t)b * DINNER + e) * NCHUNK + c) * 16 + n;
  Pbuf[o] = __expf(Aen * sd);
  Hbuf[o] = h;
}

// ---------------------------------------------------------------------------
// Pass B: serial combine over the NCHUNK chunk summaries.  One thread per
// (b,e,n).  Overwrites Hbuf[..c..] with the TRUE initial state of chunk c.
__global__ __launch_bounds__(256) void scan_combine_kernel(
    const float* __restrict__ Pbuf, float* __restrict__ Hbuf)
{
  const int idx = blockIdx.x * 256 + threadIdx.x;  // (b*DINNER+e)*16+n
  const int be = idx >> 4, n = idx & 15;
  float H = 0.f;
  for (int c = 0; c < NCHUNK; ++c) {
    const size_t o = ((size_t)be * NCHUNK + c) * 16 + n;
    const float P = Pbuf[o], hf = Hbuf[o];
    Hbuf[o] = H;                 // initial state for chunk c
    H = P * H + hf;
  }
}

// ---------------------------------------------------------------------------
// Pass C: re-run each chunk seeded with its true initial state; fused C-dot,
// D skip and z gate.  Writes y*silu(z) in place over the delta buffer.
__global__ __launch_bounds__(256) void scan_out_kernel(
    float* __restrict__ delta,         // (ROWS, DINNER)  in/out
    const float* __restrict__ xc,      // (ROWS, DINNER)
    const float* __restrict__ dbc,     // (ROWS, 96): [64..80)=B, [80..96)=C
    const float* __restrict__ xz,      // (ROWS, 2*DINNER): z at col 2048+e
    const float* __restrict__ A_log,   // (DINNER, 16)
    const float* __restrict__ Dp,      // (DINNER)
    const float* __restrict__ Hbuf)    // (BATCH, DINNER, NCHUNK, 16) init states
{
  const int g  = blockIdx.x * 16 + (threadIdx.x >> 4);
  const int n  = threadIdx.x & 15;
  const int e  = g % DINNER;
  const int bc = g / DINNER;
  const int c  = bc % NCHUNK;
  const int b  = bc / NCHUNK;
  const float Aen = -__expf(A_log[e * DSTATE + n]);
  const float dpe = Dp[e];
  float h = Hbuf[(((size_t)b * DINNER + e) * NCHUNK + c) * 16 + n];
  const size_t rowE  = ((size_t)b * SEQ + c * CHUNK) * DINNER + e;
  const size_t row96 = ((size_t)b * SEQ + c * CHUNK) * 96;
  const size_t rowZ  = ((size_t)b * SEQ + c * CHUNK) * (2 * DINNER) + DINNER + e;
  for (int t = 0; t < CHUNK; ++t) {
    const float dv = delta[rowE + (size_t)t * DINNER];
    const float xv = xc[rowE + (size_t)t * DINNER];
    const float Bv = dbc[row96 + t * 96 + DTRANK + n];
    const float Cv = dbc[row96 + t * 96 + DTRANK + DSTATE + n];
    const float dA = __expf(dv * Aen);
    h = dA * h + (dv * xv) * Bv;
    float p = h * Cv;
    p += __shfl_xor(p, 1);
    p += __shfl_xor(p, 2);
    p += __shfl_xor(p, 4);
    p += __shfl_xor(p, 8);
    if (n == 0) {
      const float y = p + dpe * xv;
      const float zv = xz[rowZ + (size_t)t * (2 * DINNER)];
      const float sz = zv / (1.f + __expf(-zv));
      delta[rowE + (size_t)t * DINNER] = y * sz;
    }
  }
}

// ---------------------------------------------------------------------------
extern "C" void kernel_launch(void* const* d_in, const int* in_sizes, int n_in,
                              void* d_out, int out_size, void* d_ws, size_t ws_size,
                              hipStream_t stream)
{
  const float* x         = (const float*)d_in[0];
  const float* norm_w    = (const float*)d_in[1];
  const float* in_proj_w = (const float*)d_in[2];
  const float* conv_w    = (const float*)d_in[3];
  const float* conv_b    = (const float*)d_in[4];
  const float* x_proj_w  = (const float*)d_in[5];
  const float* dt_proj_w = (const float*)d_in[6];
  const float* dt_proj_b = (const float*)d_in[7];
  const float* A_log     = (const float*)d_in[8];
  const float* D_param   = (const float*)d_in[9];
  const float* out_proj_w= (const float*)d_in[10];
  float* out = (float*)d_out;

  float* ws = (float*)d_ws;
  float* h_buf   = ws;                                 // ROWS*DMODEL   (2M floats)
  float* xz_buf  = h_buf  + (size_t)ROWS * DMODEL;     // ROWS*2*DINNER (8M)
  float* xc_buf  = xz_buf + (size_t)ROWS * 2 * DINNER; // ROWS*DINNER   (4M)
  float* dbc_buf = xc_buf + (size_t)ROWS * DINNER;     // ROWS*96
  float* dl_buf  = dbc_buf + (size_t)ROWS * 96;        // ROWS*DINNER   (4M)
  // Chunk-summary buffers alias h_buf (dead after the in_proj GEMM):
  float* P_buf   = h_buf;                              // 1M floats
  float* Hc_buf  = h_buf + (size_t)BATCH * DINNER * NCHUNK * 16; // 1M floats

  // residual stream lives in d_out
  hipMemcpyAsync(out, x, (size_t)ROWS * DMODEL * sizeof(float),
                 hipMemcpyDeviceToDevice, stream);

  for (int layer = 0; layer < NLAYERS; ++layer) {
    const float* nw  = norm_w     + (size_t)layer * DMODEL;
    const float* iw  = in_proj_w  + (size_t)layer * 2 * DINNER * DMODEL;
    const float* cw  = conv_w     + (size_t)layer * DINNER * DCONV;
    const float* cb  = conv_b     + (size_t)layer * DINNER;
    const float* xpw = x_proj_w   + (size_t)layer * 96 * DINNER;
    const float* dtw = dt_proj_w  + (size_t)layer * DINNER * DTRANK;
    const float* dtb = dt_proj_b  + (size_t)layer * DINNER;
    const float* Al  = A_log      + (size_t)layer * DINNER * DSTATE;
    const float* Dpp = D_param    + (size_t)layer * DINNER;
    const float* ow  = out_proj_w + (size_t)layer * DMODEL * DINNER;

    // 1. h = rmsnorm(residual)
    rmsnorm_kernel<<<ROWS, 256, 0, stream>>>(out, nw, h_buf);

    // 2. xz = h @ in_w^T   (2048 x 4096 x 1024)
    gemm_nt_kernel<128, 128, 8, 8, false>
        <<<dim3(2 * DINNER / 128, ROWS / 128), 256, 0, stream>>>(
            h_buf, iw, xz_buf, DMODEL, DMODEL, DMODEL, 2 * DINNER);

    // 3. xc = silu(causal_conv(xz[:, :DINNER]) + cb)
    conv_silu_kernel<<<(size_t)ROWS * DINNER / 256, 256, 0, stream>>>(
        xz_buf, cw, cb, xc_buf);

    // 4. dbc = xc @ xpw^T  (2048 x 96 x 2048)
    xproj_kernel<<<ROWS / 4, 192, 0, stream>>>(xc_buf, xpw, dbc_buf);

    // 5. delta_pre = dbc[:, :64] @ dtw^T  (2048 x 2048 x 64)
    gemm_nt_kernel<128, 128, 8, 8, false>
        <<<dim3(DINNER / 128, ROWS / 128), 256, 0, stream>>>(
            dbc_buf, dtw, dl_buf, DTRANK, 96, DTRANK, DINNER);

    // 6. delta = softplus(delta_pre + dtb)
    softplus_bias_kernel<<<(size_t)ROWS * DINNER / 256, 256, 0, stream>>>(
        dl_buf, dtb);

    // 7. chunked selective scan + D skip + z gate (in place into dl_buf)
    scan_chunk_kernel<<<BATCH * NCHUNK * DINNER / 16, 256, 0, stream>>>(
        dl_buf, xc_buf, dbc_buf, Al, P_buf, Hc_buf);
    scan_combine_kernel<<<BATCH * DINNER * 16 / 256, 256, 0, stream>>>(
        P_buf, Hc_buf);
    scan_out_kernel<<<BATCH * NCHUNK * DINNER / 16, 256, 0, stream>>>(
        dl_buf, xc_buf, dbc_buf, xz_buf, Al, Dpp, Hc_buf);

    // 8. residual += yz @ ow^T  (2048 x 1024 x 2048)
    gemm_nt_kernel<128, 64, 8, 4, true>
        <<<dim3(DMODEL / 64, ROWS / 128), 256, 0, stream>>>(
            dl_buf, ow, out, DINNER, DINNER, DINNER, DMODEL);
  }
}

// Round 4
// 760.749 us; speedup vs baseline: 3.3413x; 1.7961x over previous
//
#include <hip/hip_runtime.h>
#include <hip/hip_bf16.h>

// Problem constants
#define BATCH   2
#define SEQ     1024
#define DMODEL  1024
#define DINNER  2048
#define DSTATE  16
#define DTRANK  64
#define DCONV   4
#define NLAYERS 2
#define ROWS    (BATCH*SEQ)        // 2048 (b,l) rows
#define NCHUNK  16
#define CHUNK   64                 // SEQ / NCHUNK

typedef unsigned short ushort_t;
typedef __attribute__((ext_vector_type(8))) short short8;
typedef __attribute__((ext_vector_type(4))) float f32x4;

// fp32 -> bf16 round-to-nearest-even
__device__ __forceinline__ ushort_t f2bf(float f) {
  union { float f; unsigned u; } v; v.f = f;
  unsigned r = v.u + 0x7fffu + ((v.u >> 16) & 1u);
  return (ushort_t)(r >> 16);
}
__device__ __forceinline__ float bf2f(ushort_t h) {
  union { unsigned u; float f; } v; v.u = ((unsigned)h) << 16;
  return v.f;
}

// async global->LDS 16B (literal size per guide)
__device__ __forceinline__ void g2lds16(const ushort_t* g, ushort_t* l) {
  __builtin_amdgcn_global_load_lds(
      (const __attribute__((address_space(1))) void*)g,
      (__attribute__((address_space(3))) void*)l, 16, 0, 0);
}

// ---------------------------------------------------------------------------
// cast fp32 -> bf16, 4 elems/thread
__global__ __launch_bounds__(256) void cast_bf16_kernel(
    const float* __restrict__ in, ushort_t* __restrict__ out)
{
  const int i = blockIdx.x * 256 + threadIdx.x;
  const float4 v = reinterpret_cast<const float4*>(in)[i];
  ushort4 o;
  o.x = f2bf(v.x); o.y = f2bf(v.y); o.z = f2bf(v.z); o.w = f2bf(v.w);
  reinterpret_cast<ushort4*>(out)[i] = o;
}

// ---------------------------------------------------------------------------
// RMSNorm: one block per row of DMODEL, bf16 output
__global__ __launch_bounds__(256) void rmsnorm_kernel(
    const float* __restrict__ x, const float* __restrict__ w,
    ushort_t* __restrict__ out)
{
  const int row = blockIdx.x;
  const float* xr = x + (size_t)row * DMODEL;
  float ss = 0.f;
  #pragma unroll
  for (int i = threadIdx.x; i < DMODEL; i += 256) { float v = xr[i]; ss += v * v; }
  #pragma unroll
  for (int m = 1; m < 64; m <<= 1) ss += __shfl_xor(ss, m);
  __shared__ float red[4];
  if ((threadIdx.x & 63) == 0) red[threadIdx.x >> 6] = ss;
  __syncthreads();
  float tot = red[0] + red[1] + red[2] + red[3];
  float scale = rsqrtf(tot * (1.f / DMODEL) + 1e-5f);
  #pragma unroll
  for (int i = threadIdx.x; i < DMODEL; i += 256)
    out[(size_t)row * DMODEL + i] = f2bf(xr[i] * scale * w[i]);
}

// ---------------------------------------------------------------------------
// bf16 MFMA GEMM: D[M][N] = A[M][K] * B[N][K]^T (+C if ACC).
// BM=BN=128, BK=32, 256 threads = 4 waves (2x2), 64x64 per wave.
// m97 structure: global_load_lds dwordx4 staging, linear LDS, 2 barriers/K-step.
// If ZSPLIT: cols [0,DINNER) -> fp32 C (ldc), cols [DINNER,2*DINNER) -> bf16 C2.
template<bool ACC, bool ZSPLIT>
__global__ __launch_bounds__(256) void gemm_bf16_kernel(
    const ushort_t* __restrict__ A, const ushort_t* __restrict__ B,
    float* __restrict__ C, ushort_t* __restrict__ C2,
    int K, int lda, int ldb, int ldc)
{
  __shared__ __align__(16) ushort_t As[128 * 32];
  __shared__ __align__(16) ushort_t Bs[128 * 32];
  const int tid = threadIdx.x;
  const int lane = tid & 63, wid = tid >> 6;
  const int wr = wid >> 1, wc = wid & 1;
  const int row0 = blockIdx.y * 128, col0 = blockIdx.x * 128;

  // staging: chunk tid covers (row tid>>2, 8 elems at (tid&3)*8); +256 -> rows 64..127
  const ushort_t* ga0 = A + (size_t)(row0 + (tid >> 2)) * lda + (tid & 3) * 8;
  const ushort_t* ga1 = A + (size_t)(row0 + 64 + (tid >> 2)) * lda + (tid & 3) * 8;
  const ushort_t* gb0 = B + (size_t)(col0 + (tid >> 2)) * ldb + (tid & 3) * 8;
  const ushort_t* gb1 = B + (size_t)(col0 + 64 + (tid >> 2)) * ldb + (tid & 3) * 8;
  ushort_t* la0 = &As[tid * 8];
  ushort_t* la1 = &As[(256 + tid) * 8];
  ushort_t* lb0 = &Bs[tid * 8];
  ushort_t* lb1 = &Bs[(256 + tid) * 8];

  const int lk = (lane >> 4) * 8;        // k offset in elems
  const int lr16 = lane & 15;            // row/col within 16-tile

  f32x4 acc[4][4] = {};

  for (int kb = 0; kb < K; kb += 32) {
    g2lds16(ga0 + kb, la0);
    g2lds16(ga1 + kb, la1);
    g2lds16(gb0 + kb, lb0);
    g2lds16(gb1 + kb, lb1);
    __syncthreads();

    short8 af[4], bfr[4];
    #pragma unroll
    for (int i = 0; i < 4; ++i)
      af[i] = *reinterpret_cast<const short8*>(
          &As[(wr * 64 + i * 16 + lr16) * 32 + lk]);
    #pragma unroll
    for (int j = 0; j < 4; ++j)
      bfr[j] = *reinterpret_cast<const short8*>(
          &Bs[(wc * 64 + j * 16 + lr16) * 32 + lk]);
    #pragma unroll
    for (int i = 0; i < 4; ++i)
      #pragma unroll
      for (int j = 0; j < 4; ++j)
        acc[i][j] = __builtin_amdgcn_mfma_f32_16x16x32_bf16(
            af[i], bfr[j], acc[i][j], 0, 0, 0);
    __syncthreads();
  }

  // C/D layout: col = lane&15, row = (lane>>4)*4 + reg  [m89 verified]
  const int cr = (lane >> 4) * 4;
  #pragma unroll
  for (int i = 0; i < 4; ++i) {
    #pragma unroll
    for (int j = 0; j < 4; ++j) {
      const int col = col0 + wc * 64 + j * 16 + lr16;
      #pragma unroll
      for (int r = 0; r < 4; ++r) {
        const int row = row0 + wr * 64 + i * 16 + cr + r;
        if (ZSPLIT) {
          if (col < DINNER)
            C[(size_t)row * ldc + col] = acc[i][j][r];
          else
            C2[(size_t)row * DINNER + (col - DINNER)] = f2bf(acc[i][j][r]);
        } else {
          const size_t o = (size_t)row * ldc + col;
          C[o] = (ACC ? C[o] : 0.f) + acc[i][j][r];
        }
      }
    }
  }
}

// ---------------------------------------------------------------------------
// Tiled fp32 GEMM (kept for dt_proj, K=64): C = A * B^T.
template<int BM, int BN, int TM, int TN, bool ACC>
__global__ __launch_bounds__(256) void gemm_nt_kernel(
    const float* __restrict__ A, const float* __restrict__ B,
    float* __restrict__ C, int K, int lda, int ldb, int ldc)
{
  constexpr int BK = 16;
  constexpr int NX = BN / TN;
  __shared__ float As[BK][BM + 4];
  __shared__ float Bs[BK][BN + 4];
  const int tid = threadIdx.x;
  const int tx = tid % NX, ty = tid / NX;
  const int row0 = blockIdx.y * BM, col0 = blockIdx.x * BN;
  float acc[TM][TN] = {};

  for (int kb = 0; kb < K; kb += BK) {
    #pragma unroll
    for (int p = 0; p < BM / 64; ++p) {
      const int lr = tid / 4 + p * 64;
      const int lk = (tid % 4) * 4;
      const float4 v = *reinterpret_cast<const float4*>(
          &A[(size_t)(row0 + lr) * lda + kb + lk]);
      As[lk + 0][lr] = v.x; As[lk + 1][lr] = v.y;
      As[lk + 2][lr] = v.z; As[lk + 3][lr] = v.w;
    }
    #pragma unroll
    for (int p = 0; p < BN / 64; ++p) {
      const int lc = tid / 4 + p * 64;
      const int lk = (tid % 4) * 4;
      const float4 v = *reinterpret_cast<const float4*>(
          &B[(size_t)(col0 + lc) * ldb + kb + lk]);
      Bs[lk + 0][lc] = v.x; Bs[lk + 1][lc] = v.y;
      Bs[lk + 2][lc] = v.z; Bs[lk + 3][lc] = v.w;
    }
    __syncthreads();
    #pragma unroll
    for (int kk = 0; kk < BK; ++kk) {
      float a[TM], bf[TN];
      #pragma unroll
      for (int i = 0; i < TM / 4; ++i)
        *reinterpret_cast<float4*>(&a[i * 4]) =
            *reinterpret_cast<const float4*>(&As[kk][ty * TM + i * 4]);
      #pragma unroll
      for (int j = 0; j < TN / 4; ++j)
        *reinterpret_cast<float4*>(&bf[j * 4]) =
            *reinterpret_cast<const float4*>(&Bs[kk][tx * TN + j * 4]);
      #pragma unroll
      for (int i = 0; i < TM; ++i)
        #pragma unroll
        for (int j = 0; j < TN; ++j)
          acc[i][j] += a[i] * bf[j];
    }
    __syncthreads();
  }
  #pragma unroll
  for (int i = 0; i < TM; ++i) {
    const int r = row0 + ty * TM + i;
    #pragma unroll
    for (int j = 0; j < TN; ++j) {
      const int c = col0 + tx * TN + j;
      const size_t o = (size_t)r * ldc + c;
      C[o] = (ACC ? C[o] : 0.f) + acc[i][j];
    }
  }
}

// ---------------------------------------------------------------------------
// Depthwise causal conv (k=4) + bias + SiLU.  xcpre row-major (ROWS, DINNER).
__global__ __launch_bounds__(256) void conv_silu_kernel(
    const float* __restrict__ xcpre, const float* __restrict__ cw,
    const float* __restrict__ cb, float* __restrict__ xc)
{
  const int idx = blockIdx.x * 256 + threadIdx.x;  // over ROWS*DINNER
  const int e  = idx % DINNER;
  const int bl = idx / DINNER;
  const int l  = bl % SEQ;
  float acc = cb[e];
  #pragma unroll
  for (int k = 0; k < DCONV; ++k) {
    const int lk = l + k - (DCONV - 1);
    if (lk >= 0)
      acc += xcpre[(size_t)(bl + k - (DCONV - 1)) * DINNER + e] * cw[e * DCONV + k];
  }
  xc[idx] = acc / (1.f + __expf(-acc));
}

// ---------------------------------------------------------------------------
// x_proj: dbc[row][j] = sum_k xc[row][k]*xpw[j][k], j<96.  4 rows per block.
__global__ __launch_bounds__(192) void xproj_kernel(
    const float* __restrict__ xc, const float* __restrict__ xpw,
    float* __restrict__ dbc)
{
  __shared__ float s[4 * DINNER];
  const int r0 = blockIdx.x * 4;
  const float4* src = reinterpret_cast<const float4*>(xc + (size_t)r0 * DINNER);
  for (int i = threadIdx.x; i < 4 * DINNER / 4; i += 192)
    reinterpret_cast<float4*>(s)[i] = src[i];
  __syncthreads();
  const int j  = threadIdx.x % 96;
  const int rh = threadIdx.x / 96;
  const float4* wj = reinterpret_cast<const float4*>(xpw + (size_t)j * DINNER);
  const float4* s0 = reinterpret_cast<const float4*>(s + (rh * 2 + 0) * DINNER);
  const float4* s1 = reinterpret_cast<const float4*>(s + (rh * 2 + 1) * DINNER);
  float a0 = 0.f, a1 = 0.f;
  for (int k4 = 0; k4 < DINNER / 4; ++k4) {
    const float4 w4 = wj[k4];
    const float4 x0 = s0[k4], x1 = s1[k4];
    a0 += w4.x * x0.x + w4.y * x0.y + w4.z * x0.z + w4.w * x0.w;
    a1 += w4.x * x1.x + w4.y * x1.y + w4.z * x1.z + w4.w * x1.w;
  }
  dbc[(size_t)(r0 + rh * 2 + 0) * 96 + j] = a0;
  dbc[(size_t)(r0 + rh * 2 + 1) * 96 + j] = a1;
}

// ---------------------------------------------------------------------------
// delta = softplus(delta_pre + bias[e]), in place
__global__ __launch_bounds__(256) void softplus_bias_kernel(
    float* __restrict__ delta, const float* __restrict__ bias)
{
  const int idx = blockIdx.x * 256 + threadIdx.x;
  const float v = delta[idx] + bias[idx % DINNER];
  delta[idx] = (v > 20.f) ? v : log1pf(__expf(v));
}

// ---------------------------------------------------------------------------
// Chunked selective scan, pass A: per-(b,e,chunk) local scan from h=0.
__global__ __launch_bounds__(256) void scan_chunk_kernel(
    const float* __restrict__ delta,   // (ROWS, DINNER) softplus'd
    const float* __restrict__ xc,      // (ROWS, DINNER)
    const float* __restrict__ dbc,     // (ROWS, 96): [64..80)=B
    const float* __restrict__ A_log,   // (DINNER, 16)
    float* __restrict__ Pbuf,          // (BATCH, DINNER, NCHUNK, 16)
    float* __restrict__ Hbuf)          // (BATCH, DINNER, NCHUNK, 16)
{
  const int g  = blockIdx.x * 16 + (threadIdx.x >> 4);
  const int n  = threadIdx.x & 15;
  const int e  = g % DINNER;
  const int bc = g / DINNER;
  const int c  = bc % NCHUNK;
  const int b  = bc / NCHUNK;
  const float Aen = -__expf(A_log[e * DSTATE + n]);
  float h = 0.f, sd = 0.f;
  const size_t rowE  = ((size_t)b * SEQ + c * CHUNK) * DINNER + e;
  const size_t row96 = ((size_t)b * SEQ + c * CHUNK) * 96;
  for (int t = 0; t < CHUNK; ++t) {
    const float dv = delta[rowE + (size_t)t * DINNER];
    const float xv = xc[rowE + (size_t)t * DINNER];
    const float Bv = dbc[row96 + t * 96 + DTRANK + n];
    const float dA = __expf(dv * Aen);
    h = dA * h + (dv * xv) * Bv;
    sd += dv;
  }
  const size_t o = (((size_t)b * DINNER + e) * NCHUNK + c) * 16 + n;
  Pbuf[o] = __expf(Aen * sd);
  Hbuf[o] = h;
}

// ---------------------------------------------------------------------------
// Pass B: serial combine over NCHUNK chunk summaries, one thread per (b,e,n).
__global__ __launch_bounds__(256) void scan_combine_kernel(
    const float* __restrict__ Pbuf, float* __restrict__ Hbuf)
{
  const int idx = blockIdx.x * 256 + threadIdx.x;
  const int be = idx >> 4;
  float H = 0.f;
  for (int c = 0; c < NCHUNK; ++c) {
    const size_t o = ((size_t)be * NCHUNK + c) * 16 + (idx & 15);
    const float P = Pbuf[o], hf = Hbuf[o];
    Hbuf[o] = H;
    H = P * H + hf;
  }
}

// ---------------------------------------------------------------------------
// Pass C: re-run each chunk seeded; fused C-dot, D skip, z gate.
// Writes bf16 y*silu(z) to yz16 (A operand of out_proj MFMA GEMM).
__global__ __launch_bounds__(256) void scan_out_kernel(
    const float* __restrict__ delta,   // (ROWS, DINNER)
    const float* __restrict__ xc,      // (ROWS, DINNER)
    const float* __restrict__ dbc,     // (ROWS, 96)
    const ushort_t* __restrict__ z16,  // (ROWS, DINNER) bf16 z
    const float* __restrict__ A_log,   // (DINNER, 16)
    const float* __restrict__ Dp,      // (DINNER)
    const float* __restrict__ Hbuf,    // init states
    ushort_t* __restrict__ yz16)       // (ROWS, DINNER) bf16 out
{
  const int g  = blockIdx.x * 16 + (threadIdx.x >> 4);
  const int n  = threadIdx.x & 15;
  const int e  = g % DINNER;
  const int bc = g / DINNER;
  const int c  = bc % NCHUNK;
  const int b  = bc / NCHUNK;
  const float Aen = -__expf(A_log[e * DSTATE + n]);
  const float dpe = Dp[e];
  float h = Hbuf[(((size_t)b * DINNER + e) * NCHUNK + c) * 16 + n];
  const size_t rowE  = ((size_t)b * SEQ + c * CHUNK) * DINNER + e;
  const size_t row96 = ((size_t)b * SEQ + c * CHUNK) * 96;
  for (int t = 0; t < CHUNK; ++t) {
    const float dv = delta[rowE + (size_t)t * DINNER];
    const float xv = xc[rowE + (size_t)t * DINNER];
    const float Bv = dbc[row96 + t * 96 + DTRANK + n];
    const float Cv = dbc[row96 + t * 96 + DTRANK + DSTATE + n];
    const float dA = __expf(dv * Aen);
    h = dA * h + (dv * xv) * Bv;
    float p = h * Cv;
    p += __shfl_xor(p, 1);
    p += __shfl_xor(p, 2);
    p += __shfl_xor(p, 4);
    p += __shfl_xor(p, 8);
    if (n == 0) {
      const float y = p + dpe * xv;
      const float zv = bf2f(z16[rowE + (size_t)t * DINNER]);
      const float sz = zv / (1.f + __expf(-zv));
      yz16[rowE + (size_t)t * DINNER] = f2bf(y * sz);
    }
  }
}

// ---------------------------------------------------------------------------
extern "C" void kernel_launch(void* const* d_in, const int* in_sizes, int n_in,
                              void* d_out, int out_size, void* d_ws, size_t ws_size,
                              hipStream_t stream)
{
  const float* x         = (const float*)d_in[0];
  const float* norm_w    = (const float*)d_in[1];
  const float* in_proj_w = (const float*)d_in[2];
  const float* conv_w    = (const float*)d_in[3];
  const float* conv_b    = (const float*)d_in[4];
  const float* x_proj_w  = (const float*)d_in[5];
  const float* dt_proj_w = (const float*)d_in[6];
  const float* dt_proj_b = (const float*)d_in[7];
  const float* A_log     = (const float*)d_in[8];
  const float* D_param   = (const float*)d_in[9];
  const float* out_proj_w= (const float*)d_in[10];
  float* out = (float*)d_out;

  // Workspace layout (float offsets), total 18.1875M floats = 72.75 MB
  // (identical footprint to the R1-proven layout):
  float* ws = (float*)d_ws;
  float* h_buf    = ws;                                   // [0, 2M)
  float* xcpre    = ws + (size_t)2 * 1024 * 1024;         // [2M, 6M)
  ushort_t* z16   = (ushort_t*)(ws + (size_t)6 * 1024 * 1024);   // [6M, 8M)
  float* xc_buf   = ws + (size_t)8 * 1024 * 1024;         // [8M, 12M)
  float* dbc_buf  = ws + (size_t)12 * 1024 * 1024;        // [12M, 12M+192K)
  float* dl_buf   = dbc_buf + (size_t)ROWS * 96;          // 4M floats
  ushort_t* yz16  = (ushort_t*)(dl_buf + (size_t)ROWS * DINNER); // 2M floats
  // aliases:
  ushort_t* h16   = (ushort_t*)h_buf;                     // dead after step 2
  float* P_buf    = h_buf;                                // 1M floats
  float* Hc_buf   = h_buf + (size_t)1024 * 1024;          // 1M floats
  ushort_t* w16i  = (ushort_t*)xc_buf;                    // 8M ushorts, dead before conv
  ushort_t* w16o  = (ushort_t*)dl_buf;                    // 2M ushorts, delta dead by then

  hipMemcpyAsync(out, x, (size_t)ROWS * DMODEL * sizeof(float),
                 hipMemcpyDeviceToDevice, stream);

  for (int layer = 0; layer < NLAYERS; ++layer) {
    const float* nw  = norm_w     + (size_t)layer * DMODEL;
    const float* iw  = in_proj_w  + (size_t)layer * 2 * DINNER * DMODEL;
    const float* cw  = conv_w     + (size_t)layer * DINNER * DCONV;
    const float* cb  = conv_b     + (size_t)layer * DINNER;
    const float* xpw = x_proj_w   + (size_t)layer * 96 * DINNER;
    const float* dtw = dt_proj_w  + (size_t)layer * DINNER * DTRANK;
    const float* dtb = dt_proj_b  + (size_t)layer * DINNER;
    const float* Al  = A_log      + (size_t)layer * DINNER * DSTATE;
    const float* Dpp = D_param    + (size_t)layer * DINNER;
    const float* ow  = out_proj_w + (size_t)layer * DMODEL * DINNER;

    // 1. h = rmsnorm(residual) -> bf16
    rmsnorm_kernel<<<ROWS, 256, 0, stream>>>(out, nw, h16);

    // 1b. cast in_proj weights to bf16 (into xc_buf region, dead here)
    cast_bf16_kernel<<<(2 * DINNER * DMODEL) / 1024, 256, 0, stream>>>(iw, w16i);

    // 2. xz = h @ in_w^T  (bf16 MFMA, 2048 x 4096 x 1024)
    //    cols<2048 -> xcpre fp32; cols>=2048 -> z16 bf16
    gemm_bf16_kernel<false, true>
        <<<dim3(2 * DINNER / 128, ROWS / 128), 256, 0, stream>>>(
            h16, w16i, xcpre, z16, DMODEL, DMODEL, DMODEL, DINNER);

    // 3. xc = silu(causal_conv(xcpre) + cb)
    conv_silu_kernel<<<(size_t)ROWS * DINNER / 256, 256, 0, stream>>>(
        xcpre, cw, cb, xc_buf);

    // 4. dbc = xc @ xpw^T  (2048 x 96 x 2048)
    xproj_kernel<<<ROWS / 4, 192, 0, stream>>>(xc_buf, xpw, dbc_buf);

    // 5. delta_pre = dbc[:, :64] @ dtw^T  (2048 x 2048 x 64, fp32)
    gemm_nt_kernel<128, 128, 8, 8, false>
        <<<dim3(DINNER / 128, ROWS / 128), 256, 0, stream>>>(
            dbc_buf, dtw, dl_buf, DTRANK, 96, DTRANK, DINNER);

    // 6. delta = softplus(delta_pre + dtb)
    softplus_bias_kernel<<<(size_t)ROWS * DINNER / 256, 256, 0, stream>>>(
        dl_buf, dtb);

    // 7. chunked selective scan + D skip + z gate -> yz16 (bf16)
    scan_chunk_kernel<<<BATCH * NCHUNK * DINNER / 16, 256, 0, stream>>>(
        dl_buf, xc_buf, dbc_buf, Al, P_buf, Hc_buf);
    scan_combine_kernel<<<BATCH * DINNER * 16 / 256, 256, 0, stream>>>(
        P_buf, Hc_buf);
    scan_out_kernel<<<BATCH * NCHUNK * DINNER / 16, 256, 0, stream>>>(
        dl_buf, xc_buf, dbc_buf, z16, Al, Dpp, Hc_buf, yz16);

    // 7b. cast out_proj weights to bf16 (into dl_buf region, delta now dead)
    cast_bf16_kernel<<<(DMODEL * DINNER) / 1024, 256, 0, stream>>>(ow, w16o);

    // 8. residual += yz @ ow^T  (bf16 MFMA, 2048 x 1024 x 2048, ACC)
    gemm_bf16_kernel<true, false>
        <<<dim3(DMODEL / 128, ROWS / 128), 256, 0, stream>>>(
            yz16, w16o, out, nullptr, DINNER, DINNER, DINNER, DMODEL);
  }
}

// Round 7
// 605.354 us; speedup vs baseline: 4.1991x; 1.2567x over previous
//
#include <hip/hip_runtime.h>
#include <hip/hip_bf16.h>

// Problem constants
#define BATCH   2
#define SEQ     1024
#define DMODEL  1024
#define DINNER  2048
#define DSTATE  16
#define DTRANK  64
#define DCONV   4
#define NLAYERS 2
#define ROWS    (BATCH*SEQ)        // 2048 (b,l) rows
#define NCHUNK  64
#define CHUNK   16                 // SEQ / NCHUNK

typedef unsigned short ushort_t;
typedef __attribute__((ext_vector_type(8))) short short8;
typedef __attribute__((ext_vector_type(4))) float f32x4;

// fp32 -> bf16 round-to-nearest-even
__device__ __forceinline__ ushort_t f2bf(float f) {
  union { float f; unsigned u; } v; v.f = f;
  unsigned r = v.u + 0x7fffu + ((v.u >> 16) & 1u);
  return (ushort_t)(r >> 16);
}
__device__ __forceinline__ float bf2f(ushort_t h) {
  union { unsigned u; float f; } v; v.u = ((unsigned)h) << 16;
  return v.f;
}

// async global->LDS 16B
__device__ __forceinline__ void g2lds16(const ushort_t* g, ushort_t* l) {
  __builtin_amdgcn_global_load_lds(
      (const __attribute__((address_space(1))) void*)g,
      (__attribute__((address_space(3))) void*)l, 16, 0, 0);
}

// ---------------------------------------------------------------------------
// cast fp32 -> bf16, 4 elems/thread
__global__ __launch_bounds__(256) void cast_bf16_kernel(
    const float* __restrict__ in, ushort_t* __restrict__ out)
{
  const int i = blockIdx.x * 256 + threadIdx.x;
  const float4 v = reinterpret_cast<const float4*>(in)[i];
  ushort4 o;
  o.x = f2bf(v.x); o.y = f2bf(v.y); o.z = f2bf(v.z); o.w = f2bf(v.w);
  reinterpret_cast<ushort4*>(out)[i] = o;
}

// ---------------------------------------------------------------------------
// RMSNorm: one block per row of DMODEL, bf16 output
__global__ __launch_bounds__(256) void rmsnorm_kernel(
    const float* __restrict__ x, const float* __restrict__ w,
    ushort_t* __restrict__ out)
{
  const int row = blockIdx.x;
  const float* xr = x + (size_t)row * DMODEL;
  float ss = 0.f;
  #pragma unroll
  for (int i = threadIdx.x; i < DMODEL; i += 256) { float v = xr[i]; ss += v * v; }
  #pragma unroll
  for (int m = 1; m < 64; m <<= 1) ss += __shfl_xor(ss, m);
  __shared__ float red[4];
  if ((threadIdx.x & 63) == 0) red[threadIdx.x >> 6] = ss;
  __syncthreads();
  float tot = red[0] + red[1] + red[2] + red[3];
  float scale = rsqrtf(tot * (1.f / DMODEL) + 1e-5f);
  #pragma unroll
  for (int i = threadIdx.x; i < DMODEL; i += 256)
    out[(size_t)row * DMODEL + i] = f2bf(xr[i] * scale * w[i]);
}

// ---------------------------------------------------------------------------
// bf16 MFMA GEMM: D[M][N] = A[M][K] * B[N][K]^T (+C if ACC).
// BM=BN=128, BK=32, 256 threads = 4 waves (2x2), 64x64 per wave.
// If ZSPLIT: cols [0,DINNER) -> fp32 C, cols [DINNER,2*DINNER) -> bf16 C2.
template<bool ACC, bool ZSPLIT>
__global__ __launch_bounds__(256) void gemm_bf16_kernel(
    const ushort_t* __restrict__ A, const ushort_t* __restrict__ B,
    float* __restrict__ C, ushort_t* __restrict__ C2,
    int K, int lda, int ldb, int ldc)
{
  __shared__ __align__(16) ushort_t As[128 * 32];
  __shared__ __align__(16) ushort_t Bs[128 * 32];
  const int tid = threadIdx.x;
  const int lane = tid & 63, wid = tid >> 6;
  const int wr = wid >> 1, wc = wid & 1;
  const int row0 = blockIdx.y * 128, col0 = blockIdx.x * 128;

  const ushort_t* ga0 = A + (size_t)(row0 + (tid >> 2)) * lda + (tid & 3) * 8;
  const ushort_t* ga1 = A + (size_t)(row0 + 64 + (tid >> 2)) * lda + (tid & 3) * 8;
  const ushort_t* gb0 = B + (size_t)(col0 + (tid >> 2)) * ldb + (tid & 3) * 8;
  const ushort_t* gb1 = B + (size_t)(col0 + 64 + (tid >> 2)) * ldb + (tid & 3) * 8;
  ushort_t* la0 = &As[tid * 8];
  ushort_t* la1 = &As[(256 + tid) * 8];
  ushort_t* lb0 = &Bs[tid * 8];
  ushort_t* lb1 = &Bs[(256 + tid) * 8];

  const int lk = (lane >> 4) * 8;
  const int lr16 = lane & 15;

  f32x4 acc[4][4] = {};

  for (int kb = 0; kb < K; kb += 32) {
    g2lds16(ga0 + kb, la0);
    g2lds16(ga1 + kb, la1);
    g2lds16(gb0 + kb, lb0);
    g2lds16(gb1 + kb, lb1);
    __syncthreads();

    short8 af[4], bfr[4];
    #pragma unroll
    for (int i = 0; i < 4; ++i)
      af[i] = *reinterpret_cast<const short8*>(
          &As[(wr * 64 + i * 16 + lr16) * 32 + lk]);
    #pragma unroll
    for (int j = 0; j < 4; ++j)
      bfr[j] = *reinterpret_cast<const short8*>(
          &Bs[(wc * 64 + j * 16 + lr16) * 32 + lk]);
    #pragma unroll
    for (int i = 0; i < 4; ++i)
      #pragma unroll
      for (int j = 0; j < 4; ++j)
        acc[i][j] = __builtin_amdgcn_mfma_f32_16x16x32_bf16(
            af[i], bfr[j], acc[i][j], 0, 0, 0);
    __syncthreads();
  }

  // C/D layout: col = lane&15, row = (lane>>4)*4 + reg
  const int cr = (lane >> 4) * 4;
  #pragma unroll
  for (int i = 0; i < 4; ++i) {
    #pragma unroll
    for (int j = 0; j < 4; ++j) {
      const int col = col0 + wc * 64 + j * 16 + lr16;
      #pragma unroll
      for (int r = 0; r < 4; ++r) {
        const int row = row0 + wr * 64 + i * 16 + cr + r;
        if (ZSPLIT) {
          if (col < DINNER)
            C[(size_t)row * ldc + col] = acc[i][j][r];
          else
            C2[(size_t)row * DINNER + (col - DINNER)] = f2bf(acc[i][j][r]);
        } else {
          const size_t o = (size_t)row * ldc + col;
          C[o] = (ACC ? C[o] : 0.f) + acc[i][j][r];
        }
      }
    }
  }
}

// ---------------------------------------------------------------------------
// Tiled fp32 GEMM (dt_proj, K=64), optional fused bias+softplus epilogue.
template<int BM, int BN, int TM, int TN, bool SOFTPLUS>
__global__ __launch_bounds__(256) void gemm_nt_kernel(
    const float* __restrict__ A, const float* __restrict__ B,
    float* __restrict__ C, const float* __restrict__ bias,
    int K, int lda, int ldb, int ldc)
{
  constexpr int BK = 16;
  constexpr int NX = BN / TN;
  __shared__ float As[BK][BM + 4];
  __shared__ float Bs[BK][BN + 4];
  const int tid = threadIdx.x;
  const int tx = tid % NX, ty = tid / NX;
  const int row0 = blockIdx.y * BM, col0 = blockIdx.x * BN;
  float acc[TM][TN] = {};

  for (int kb = 0; kb < K; kb += BK) {
    #pragma unroll
    for (int p = 0; p < BM / 64; ++p) {
      const int lr = tid / 4 + p * 64;
      const int lk = (tid % 4) * 4;
      const float4 v = *reinterpret_cast<const float4*>(
          &A[(size_t)(row0 + lr) * lda + kb + lk]);
      As[lk + 0][lr] = v.x; As[lk + 1][lr] = v.y;
      As[lk + 2][lr] = v.z; As[lk + 3][lr] = v.w;
    }
    #pragma unroll
    for (int p = 0; p < BN / 64; ++p) {
      const int lc = tid / 4 + p * 64;
      const int lk = (tid % 4) * 4;
      const float4 v = *reinterpret_cast<const float4*>(
          &B[(size_t)(col0 + lc) * ldb + kb + lk]);
      Bs[lk + 0][lc] = v.x; Bs[lk + 1][lc] = v.y;
      Bs[lk + 2][lc] = v.z; Bs[lk + 3][lc] = v.w;
    }
    __syncthreads();
    #pragma unroll
    for (int kk = 0; kk < BK; ++kk) {
      float a[TM], bf[TN];
      #pragma unroll
      for (int i = 0; i < TM / 4; ++i)
        *reinterpret_cast<float4*>(&a[i * 4]) =
            *reinterpret_cast<const float4*>(&As[kk][ty * TM + i * 4]);
      #pragma unroll
      for (int j = 0; j < TN / 4; ++j)
        *reinterpret_cast<float4*>(&bf[j * 4]) =
            *reinterpret_cast<const float4*>(&Bs[kk][tx * TN + j * 4]);
      #pragma unroll
      for (int i = 0; i < TM; ++i)
        #pragma unroll
        for (int j = 0; j < TN; ++j)
          acc[i][j] += a[i] * bf[j];
    }
    __syncthreads();
  }
  #pragma unroll
  for (int i = 0; i < TM; ++i) {
    const int r = row0 + ty * TM + i;
    #pragma unroll
    for (int j = 0; j < TN; ++j) {
      const int c = col0 + tx * TN + j;
      float v = acc[i][j];
      if (SOFTPLUS) {
        v += bias[c];
        v = (v > 20.f) ? v : log1pf(__expf(v));
      }
      C[(size_t)r * ldc + c] = v;
    }
  }
}

// ---------------------------------------------------------------------------
// Depthwise causal conv (k=4) + bias + SiLU.  xcpre row-major (ROWS, DINNER).
__global__ __launch_bounds__(256) void conv_silu_kernel(
    const float* __restrict__ xcpre, const float* __restrict__ cw,
    const float* __restrict__ cb, float* __restrict__ xc)
{
  const int idx = blockIdx.x * 256 + threadIdx.x;
  const int e  = idx % DINNER;
  const int bl = idx / DINNER;
  const int l  = bl % SEQ;
  float acc = cb[e];
  #pragma unroll
  for (int k = 0; k < DCONV; ++k) {
    const int lk = l + k - (DCONV - 1);
    if (lk >= 0)
      acc += xcpre[(size_t)(bl + k - (DCONV - 1)) * DINNER + e] * cw[e * DCONV + k];
  }
  xc[idx] = acc / (1.f + __expf(-acc));
}

// ---------------------------------------------------------------------------
// x_proj: dbc[row][j] = sum_k xc[row][k]*xpw[j][k], j<96.  4 rows per block.
__global__ __launch_bounds__(192) void xproj_kernel(
    const float* __restrict__ xc, const float* __restrict__ xpw,
    float* __restrict__ dbc)
{
  __shared__ float s[4 * DINNER];
  const int r0 = blockIdx.x * 4;
  const float4* src = reinterpret_cast<const float4*>(xc + (size_t)r0 * DINNER);
  for (int i = threadIdx.x; i < 4 * DINNER / 4; i += 192)
    reinterpret_cast<float4*>(s)[i] = src[i];
  __syncthreads();
  const int j  = threadIdx.x % 96;
  const int rh = threadIdx.x / 96;
  const float4* wj = reinterpret_cast<const float4*>(xpw + (size_t)j * DINNER);
  const float4* s0 = reinterpret_cast<const float4*>(s + (rh * 2 + 0) * DINNER);
  const float4* s1 = reinterpret_cast<const float4*>(s + (rh * 2 + 1) * DINNER);
  float a0 = 0.f, a1 = 0.f;
  for (int k4 = 0; k4 < DINNER / 4; ++k4) {
    const float4 w4 = wj[k4];
    const float4 x0 = s0[k4], x1 = s1[k4];
    a0 += w4.x * x0.x + w4.y * x0.y + w4.z * x0.z + w4.w * x0.w;
    a1 += w4.x * x1.x + w4.y * x1.y + w4.z * x1.z + w4.w * x1.w;
  }
  dbc[(size_t)(r0 + rh * 2 + 0) * 96 + j] = a0;
  dbc[(size_t)(r0 + rh * 2 + 1) * 96 + j] = a1;
}

// ---------------------------------------------------------------------------
// Pass A: lane-per-(b,c,e), 16 states in registers.  Block = 256 e-channels
// for one (b,c); B-row staged in LDS (broadcast reads).
// Emits fp32 P (chunk decay) and hfin, layout [b][c][e][n].
__global__ __launch_bounds__(256) void scan_chunk_kernel(
    const float* __restrict__ delta,   // (ROWS, DINNER) softplus'd
    const float* __restrict__ xc,      // (ROWS, DINNER)
    const float* __restrict__ dbc,     // (ROWS, 96): [64..80)=B
    const float* __restrict__ A_log,   // (DINNER, 16)
    float* __restrict__ Pbuf,          // (BATCH, NCHUNK, DINNER, 16) fp32
    float* __restrict__ Hbuf)          // (BATCH, NCHUNK, DINNER, 16) fp32
{
  __shared__ float sB[CHUNK][16];
  const int bc = blockIdx.y;               // b*NCHUNK + c
  const int b = bc >> 6, c = bc & (NCHUNK - 1);
  const int e = blockIdx.x * 256 + threadIdx.x;
  const size_t row96 = ((size_t)b * SEQ + c * CHUNK) * 96;
  {
    const int t = threadIdx.x >> 4, n = threadIdx.x & 15;  // 256 = CHUNK*16
    sB[t][n] = dbc[row96 + t * 96 + DTRANK + n];
  }
  float Aen[16];
  #pragma unroll
  for (int q = 0; q < 4; ++q) {
    const float4 a4 = *reinterpret_cast<const float4*>(&A_log[(size_t)e * 16 + q * 4]);
    Aen[q * 4 + 0] = -__expf(a4.x);
    Aen[q * 4 + 1] = -__expf(a4.y);
    Aen[q * 4 + 2] = -__expf(a4.z);
    Aen[q * 4 + 3] = -__expf(a4.w);
  }
  __syncthreads();

  float h[16];
  #pragma unroll
  for (int n = 0; n < 16; ++n) h[n] = 0.f;
  float sd = 0.f;
  const size_t rowE = ((size_t)b * SEQ + c * CHUNK) * DINNER + e;
  float dv = delta[rowE], xv = xc[rowE];
  for (int t = 0; t < CHUNK; ++t) {
    float dvn = 0.f, xvn = 0.f;
    if (t + 1 < CHUNK) {
      dvn = delta[rowE + (size_t)(t + 1) * DINNER];
      xvn = xc[rowE + (size_t)(t + 1) * DINNER];
    }
    const float dxv = dv * xv;
    sd += dv;
    #pragma unroll
    for (int n = 0; n < 16; ++n) {
      const float dA = __expf(dv * Aen[n]);
      h[n] = dA * h[n] + dxv * sB[t][n];
    }
    dv = dvn; xv = xvn;
  }
  const size_t o = ((size_t)bc * DINNER + e) * 16;
  #pragma unroll
  for (int q = 0; q < 4; ++q) {
    float4 pv, hv;
    pv.x = __expf(Aen[q * 4 + 0] * sd);
    pv.y = __expf(Aen[q * 4 + 1] * sd);
    pv.z = __expf(Aen[q * 4 + 2] * sd);
    pv.w = __expf(Aen[q * 4 + 3] * sd);
    hv.x = h[q * 4 + 0]; hv.y = h[q * 4 + 1];
    hv.z = h[q * 4 + 2]; hv.w = h[q * 4 + 3];
    *reinterpret_cast<float4*>(&Pbuf[o + q * 4]) = pv;
    *reinterpret_cast<float4*>(&Hbuf[o + q * 4]) = hv;
  }
}

// ---------------------------------------------------------------------------
// Pass B: serial combine over NCHUNK summaries; one thread per (b,e,n).
// Overwrites Hbuf[b][c][e][n] with the true initial state of chunk c.
__global__ __launch_bounds__(256) void scan_combine_kernel(
    const float* __restrict__ Pbuf, float* __restrict__ Hbuf)
{
  const int idx = blockIdx.x * 256 + threadIdx.x;   // b*(DINNER*16) + e*16 + n
  const int b = idx >> 15;
  const int en = idx & (DINNER * 16 - 1);
  const size_t base = (size_t)b * NCHUNK * DINNER * 16 + en;
  float H = 0.f;
  float P = Pbuf[base], hf = Hbuf[base];
  for (int c = 0; c < NCHUNK; ++c) {
    const size_t o = base + (size_t)c * DINNER * 16;
    float Pn = 0.f, hfn = 0.f;
    if (c + 1 < NCHUNK) {
      const size_t on = o + (size_t)DINNER * 16;
      Pn = Pbuf[on]; hfn = Hbuf[on];
    }
    Hbuf[o] = H;
    H = P * H + hf;
    P = Pn; hf = hfn;
  }
}

// ---------------------------------------------------------------------------
// Pass C: lane-per-(b,c,e); seeded re-scan fused with C-dot, D skip, z gate.
// Writes bf16 y*silu(z) to yz16 (A operand of out_proj MFMA GEMM).
__global__ __launch_bounds__(256) void scan_out_kernel(
    const float* __restrict__ delta,   // (ROWS, DINNER)
    const float* __restrict__ xc,      // (ROWS, DINNER)
    const float* __restrict__ dbc,     // (ROWS, 96)
    const ushort_t* __restrict__ z16,  // (ROWS, DINNER) bf16 z
    const float* __restrict__ A_log,   // (DINNER, 16)
    const float* __restrict__ Dp,      // (DINNER)
    const float* __restrict__ Hbuf,    // [b][c][e][n] seeds (fp32)
    ushort_t* __restrict__ yz16)       // (ROWS, DINNER) bf16 out
{
  __shared__ float sB[CHUNK][16];
  __shared__ float sC[CHUNK][16];
  const int bc = blockIdx.y;
  const int b = bc >> 6, c = bc & (NCHUNK - 1);
  const int e = blockIdx.x * 256 + threadIdx.x;
  const size_t row96 = ((size_t)b * SEQ + c * CHUNK) * 96;
  #pragma unroll
  for (int p = 0; p < 2; ++p) {
    const int idx = threadIdx.x + p * 256;       // 512 = CHUNK*32
    const int t = idx >> 5, j = idx & 31;
    const float v = dbc[row96 + t * 96 + DTRANK + j];
    if (j < 16) sB[t][j] = v; else sC[t][j - 16] = v;
  }
  float Aen[16];
  #pragma unroll
  for (int q = 0; q < 4; ++q) {
    const float4 a4 = *reinterpret_cast<const float4*>(&A_log[(size_t)e * 16 + q * 4]);
    Aen[q * 4 + 0] = -__expf(a4.x);
    Aen[q * 4 + 1] = -__expf(a4.y);
    Aen[q * 4 + 2] = -__expf(a4.z);
    Aen[q * 4 + 3] = -__expf(a4.w);
  }
  float h[16];
  const size_t oh = ((size_t)bc * DINNER + e) * 16;
  #pragma unroll
  for (int q = 0; q < 4; ++q) {
    const float4 hv = *reinterpret_cast<const float4*>(&Hbuf[oh + q * 4]);
    h[q * 4 + 0] = hv.x; h[q * 4 + 1] = hv.y;
    h[q * 4 + 2] = hv.z; h[q * 4 + 3] = hv.w;
  }
  const float dpe = Dp[e];
  __syncthreads();

  const size_t rowE = ((size_t)b * SEQ + c * CHUNK) * DINNER + e;
  float dv = delta[rowE], xv = xc[rowE];
  float zv = bf2f(z16[rowE]);
  for (int t = 0; t < CHUNK; ++t) {
    float dvn = 0.f, xvn = 0.f, zvn = 0.f;
    if (t + 1 < CHUNK) {
      dvn = delta[rowE + (size_t)(t + 1) * DINNER];
      xvn = xc[rowE + (size_t)(t + 1) * DINNER];
      zvn = bf2f(z16[rowE + (size_t)(t + 1) * DINNER]);
    }
    const float dxv = dv * xv;
    float y = dpe * xv;
    #pragma unroll
    for (int n = 0; n < 16; ++n) {
      const float dA = __expf(dv * Aen[n]);
      h[n] = dA * h[n] + dxv * sB[t][n];
      y += h[n] * sC[t][n];
    }
    const float sz = zv / (1.f + __expf(-zv));
    yz16[rowE + (size_t)t * DINNER] = f2bf(y * sz);
    dv = dvn; xv = xvn; zv = zvn;
  }
}

// ---------------------------------------------------------------------------
extern "C" void kernel_launch(void* const* d_in, const int* in_sizes, int n_in,
                              void* d_out, int out_size, void* d_ws, size_t ws_size,
                              hipStream_t stream)
{
  const float* x         = (const float*)d_in[0];
  const float* norm_w    = (const float*)d_in[1];
  const float* in_proj_w = (const float*)d_in[2];
  const float* conv_w    = (const float*)d_in[3];
  const float* conv_b    = (const float*)d_in[4];
  const float* x_proj_w  = (const float*)d_in[5];
  const float* dt_proj_w = (const float*)d_in[6];
  const float* dt_proj_b = (const float*)d_in[7];
  const float* A_log     = (const float*)d_in[8];
  const float* D_param   = (const float*)d_in[9];
  const float* out_proj_w= (const float*)d_in[10];
  float* out = (float*)d_out;

  // Workspace layout (float offsets), total 18.1875M floats = 72.75 MB.
  // Tightest instant is scan pass A, where ALL of the following coexist and
  // are pairwise disjoint: xc[0,4M) dl[4M,8M) z16[8M,10M) dbc[10M,10.1875M)
  // H[10.1875M,14.1875M) P[14.1875M,18.1875M).  (R5 bug: z16 is 2M floats,
  // was given 1M -> gemm1 clobbered dbc+xcpre -> NaN.)
  // Aliases (each pair never simultaneously live):
  //   h16  [0,1M)            rms..gemm1      (xc written later, at conv)
  //   w16i [4M,8M)           cast..gemm1     (dl written later, at dtproj)
  //   xcpre= H region        gemm1..conv     (H written later, at scanA)
  //   yz16 [14.1875M,16.1875M) scanC..gemm2  (P dead after combine)
  //   w16o [16.1875M,17.1875M) cast..gemm2   (disjoint from yz16)
  const size_t M = 1024 * 1024;
  float* ws = (float*)d_ws;
  float* xc_buf   = ws;                          // [0,4M)
  float* dl_buf   = ws + 4 * M;                  // [4M,8M)
  ushort_t* z16   = (ushort_t*)(ws + 8 * M);     // [8M,10M)
  float* dbc_buf  = ws + 10 * M;                 // [10M,10.1875M)
  float* xcpre    = ws + 10 * M + ROWS * 96;     // [10.1875M,14.1875M)
  float* H_buf    = xcpre;                       // same region, scanA..scanC
  float* P_buf    = ws + 14 * M + ROWS * 96;     // [14.1875M,18.1875M)
  ushort_t* h16   = (ushort_t*)ws;               // [0,1M)
  ushort_t* w16i  = (ushort_t*)dl_buf;           // [4M,8M)
  ushort_t* yz16  = (ushort_t*)P_buf;            // [14.1875M,16.1875M)
  ushort_t* w16o  = (ushort_t*)(P_buf + 2 * M);  // [16.1875M,17.1875M)

  hipMemcpyAsync(out, x, (size_t)ROWS * DMODEL * sizeof(float),
                 hipMemcpyDeviceToDevice, stream);

  for (int layer = 0; layer < NLAYERS; ++layer) {
    const float* nw  = norm_w     + (size_t)layer * DMODEL;
    const float* iw  = in_proj_w  + (size_t)layer * 2 * DINNER * DMODEL;
    const float* cw  = conv_w     + (size_t)layer * DINNER * DCONV;
    const float* cb  = conv_b     + (size_t)layer * DINNER;
    const float* xpw = x_proj_w   + (size_t)layer * 96 * DINNER;
    const float* dtw = dt_proj_w  + (size_t)layer * DINNER * DTRANK;
    const float* dtb = dt_proj_b  + (size_t)layer * DINNER;
    const float* Al  = A_log      + (size_t)layer * DINNER * DSTATE;
    const float* Dpp = D_param    + (size_t)layer * DINNER;
    const float* ow  = out_proj_w + (size_t)layer * DMODEL * DINNER;

    // 1. h = rmsnorm(residual) -> bf16
    rmsnorm_kernel<<<ROWS, 256, 0, stream>>>(out, nw, h16);

    // 1b. cast in_proj weights to bf16
    cast_bf16_kernel<<<(2 * DINNER * DMODEL) / 1024, 256, 0, stream>>>(iw, w16i);

    // 2. xz = h @ in_w^T  (bf16 MFMA); cols<2048 -> xcpre fp32, cols>=2048 -> z16
    gemm_bf16_kernel<false, true>
        <<<dim3(2 * DINNER / 128, ROWS / 128), 256, 0, stream>>>(
            h16, w16i, xcpre, z16, DMODEL, DMODEL, DMODEL, DINNER);

    // 3. xc = silu(causal_conv(xcpre) + cb)
    conv_silu_kernel<<<(size_t)ROWS * DINNER / 256, 256, 0, stream>>>(
        xcpre, cw, cb, xc_buf);

    // 4. dbc = xc @ xpw^T  (2048 x 96 x 2048)
    xproj_kernel<<<ROWS / 4, 192, 0, stream>>>(xc_buf, xpw, dbc_buf);

    // 5+6. delta = softplus(dbc[:, :64] @ dtw^T + dtb)  (fused epilogue)
    gemm_nt_kernel<128, 128, 8, 8, true>
        <<<dim3(DINNER / 128, ROWS / 128), 256, 0, stream>>>(
            dbc_buf, dtw, dl_buf, dtb, DTRANK, 96, DTRANK, DINNER);

    // 7. chunked selective scan (lane-per-channel) + D skip + z gate -> yz16
    scan_chunk_kernel<<<dim3(DINNER / 256, BATCH * NCHUNK), 256, 0, stream>>>(
        dl_buf, xc_buf, dbc_buf, Al, P_buf, H_buf);
    scan_combine_kernel<<<BATCH * DINNER * 16 / 256, 256, 0, stream>>>(
        P_buf, H_buf);
    scan_out_kernel<<<dim3(DINNER / 256, BATCH * NCHUNK), 256, 0, stream>>>(
        dl_buf, xc_buf, dbc_buf, z16, Al, Dpp, H_buf, yz16);

    // 7b. cast out_proj weights to bf16
    cast_bf16_kernel<<<(DMODEL * DINNER) / 1024, 256, 0, stream>>>(ow, w16o);

    // 8. residual += yz @ ow^T  (bf16 MFMA, ACC)
    gemm_bf16_kernel<true, false>
        <<<dim3(DMODEL / 128, ROWS / 128), 256, 0, stream>>>(
            yz16, w16o, out, nullptr, DINNER, DINNER, DINNER, DMODEL);
  }
}

// Round 8
// 434.223 us; speedup vs baseline: 5.8540x; 1.3941x over previous
//
#include <hip/hip_runtime.h>
#include <hip/hip_bf16.h>

// Problem constants
#define BATCH   2
#define SEQ     1024
#define DMODEL  1024
#define DINNER  2048
#define DSTATE  16
#define DTRANK  64
#define DCONV   4
#define NLAYERS 2
#define ROWS    (BATCH*SEQ)        // 2048 (b,l) rows
#define NCHUNK  64
#define CHUNK   16                 // SEQ / NCHUNK
#define KSPLIT  8
#define KSLICE  (DINNER / KSPLIT)  // 256

typedef unsigned short ushort_t;
typedef __attribute__((ext_vector_type(8))) short short8;
typedef __attribute__((ext_vector_type(4))) float f32x4;

// fp32 -> bf16 round-to-nearest-even
__device__ __forceinline__ ushort_t f2bf(float f) {
  union { float f; unsigned u; } v; v.f = f;
  unsigned r = v.u + 0x7fffu + ((v.u >> 16) & 1u);
  return (ushort_t)(r >> 16);
}
__device__ __forceinline__ float bf2f(ushort_t h) {
  union { unsigned u; float f; } v; v.u = ((unsigned)h) << 16;
  return v.f;
}

// async global->LDS 16B
__device__ __forceinline__ void g2lds16(const ushort_t* g, ushort_t* l) {
  __builtin_amdgcn_global_load_lds(
      (const __attribute__((address_space(1))) void*)g,
      (__attribute__((address_space(3))) void*)l, 16, 0, 0);
}

// ---------------------------------------------------------------------------
// cast fp32 -> bf16, 4 elems/thread
__global__ __launch_bounds__(256) void cast_bf16_kernel(
    const float* __restrict__ in, ushort_t* __restrict__ out)
{
  const int i = blockIdx.x * 256 + threadIdx.x;
  const float4 v = reinterpret_cast<const float4*>(in)[i];
  ushort4 o;
  o.x = f2bf(v.x); o.y = f2bf(v.y); o.z = f2bf(v.z); o.w = f2bf(v.w);
  reinterpret_cast<ushort4*>(out)[i] = o;
}

// ---------------------------------------------------------------------------
// RMSNorm: one block per row of DMODEL, bf16 output
__global__ __launch_bounds__(256) void rmsnorm_kernel(
    const float* __restrict__ x, const float* __restrict__ w,
    ushort_t* __restrict__ out)
{
  const int row = blockIdx.x;
  const float* xr = x + (size_t)row * DMODEL;
  float ss = 0.f;
  #pragma unroll
  for (int i = threadIdx.x; i < DMODEL; i += 256) { float v = xr[i]; ss += v * v; }
  #pragma unroll
  for (int m = 1; m < 64; m <<= 1) ss += __shfl_xor(ss, m);
  __shared__ float red[4];
  if ((threadIdx.x & 63) == 0) red[threadIdx.x >> 6] = ss;
  __syncthreads();
  float tot = red[0] + red[1] + red[2] + red[3];
  float scale = rsqrtf(tot * (1.f / DMODEL) + 1e-5f);
  #pragma unroll
  for (int i = threadIdx.x; i < DMODEL; i += 256)
    out[(size_t)row * DMODEL + i] = f2bf(xr[i] * scale * w[i]);
}

// ---------------------------------------------------------------------------
// bf16 MFMA GEMM: D[M][N] = A[M][K] * B[N][K]^T.
// BM=BN=128, BK=32, 256 threads = 4 waves (2x2), 64x64 per wave.
// MODE 0: C=fp32 store.  MODE 1: C += (fp32 acc).
// MODE 2: zsplit - cols<DINNER -> fp32 C, cols>=DINNER -> bf16 C2.
// MODE 3: C = softplus(acc + bias[col]) fp32.
template<int MODE>
__global__ __launch_bounds__(256) void gemm_bf16_kernel(
    const ushort_t* __restrict__ A, const ushort_t* __restrict__ B,
    float* __restrict__ C, ushort_t* __restrict__ C2,
    const float* __restrict__ bias, int K, int lda, int ldb, int ldc)
{
  __shared__ __align__(16) ushort_t As[128 * 32];
  __shared__ __align__(16) ushort_t Bs[128 * 32];
  const int tid = threadIdx.x;
  const int lane = tid & 63, wid = tid >> 6;
  const int wr = wid >> 1, wc = wid & 1;
  const int row0 = blockIdx.y * 128, col0 = blockIdx.x * 128;

  const ushort_t* ga0 = A + (size_t)(row0 + (tid >> 2)) * lda + (tid & 3) * 8;
  const ushort_t* ga1 = A + (size_t)(row0 + 64 + (tid >> 2)) * lda + (tid & 3) * 8;
  const ushort_t* gb0 = B + (size_t)(col0 + (tid >> 2)) * ldb + (tid & 3) * 8;
  const ushort_t* gb1 = B + (size_t)(col0 + 64 + (tid >> 2)) * ldb + (tid & 3) * 8;
  ushort_t* la0 = &As[tid * 8];
  ushort_t* la1 = &As[(256 + tid) * 8];
  ushort_t* lb0 = &Bs[tid * 8];
  ushort_t* lb1 = &Bs[(256 + tid) * 8];

  const int lk = (lane >> 4) * 8;
  const int lr16 = lane & 15;

  f32x4 acc[4][4] = {};

  for (int kb = 0; kb < K; kb += 32) {
    g2lds16(ga0 + kb, la0);
    g2lds16(ga1 + kb, la1);
    g2lds16(gb0 + kb, lb0);
    g2lds16(gb1 + kb, lb1);
    __syncthreads();

    short8 af[4], bfr[4];
    #pragma unroll
    for (int i = 0; i < 4; ++i)
      af[i] = *reinterpret_cast<const short8*>(
          &As[(wr * 64 + i * 16 + lr16) * 32 + lk]);
    #pragma unroll
    for (int j = 0; j < 4; ++j)
      bfr[j] = *reinterpret_cast<const short8*>(
          &Bs[(wc * 64 + j * 16 + lr16) * 32 + lk]);
    #pragma unroll
    for (int i = 0; i < 4; ++i)
      #pragma unroll
      for (int j = 0; j < 4; ++j)
        acc[i][j] = __builtin_amdgcn_mfma_f32_16x16x32_bf16(
            af[i], bfr[j], acc[i][j], 0, 0, 0);
    __syncthreads();
  }

  // C/D layout: col = lane&15, row = (lane>>4)*4 + reg
  const int cr = (lane >> 4) * 4;
  #pragma unroll
  for (int i = 0; i < 4; ++i) {
    #pragma unroll
    for (int j = 0; j < 4; ++j) {
      const int col = col0 + wc * 64 + j * 16 + lr16;
      #pragma unroll
      for (int r = 0; r < 4; ++r) {
        const int row = row0 + wr * 64 + i * 16 + cr + r;
        float v = acc[i][j][r];
        if (MODE == 2) {
          if (col < DINNER)
            C[(size_t)row * ldc + col] = v;
          else
            C2[(size_t)row * DINNER + (col - DINNER)] = f2bf(v);
        } else if (MODE == 3) {
          v += bias[col];
          v = (v > 20.f) ? v : log1pf(__expf(v));
          C[(size_t)row * ldc + col] = v;
        } else {
          const size_t o = (size_t)row * ldc + col;
          C[o] = (MODE == 1 ? C[o] : 0.f) + v;
        }
      }
    }
  }
}

// ---------------------------------------------------------------------------
// x_proj MFMA split-K: partial[kz] = xc16[.,k0:k0+256] @ xpw16[.,k0:k0+256]^T
// BM=128, BN=96 (=6 col fragments), 4 waves of 32 rows each.
__global__ __launch_bounds__(256) void xproj_mfma_kernel(
    const ushort_t* __restrict__ A,    // (ROWS, DINNER) bf16 xc
    const ushort_t* __restrict__ B,    // (96, DINNER) bf16 xpw
    float* __restrict__ partial)       // (KSPLIT, ROWS, 96) fp32
{
  __shared__ __align__(16) ushort_t As[128 * 32];
  __shared__ __align__(16) ushort_t Bs[96 * 32];
  const int tid = threadIdx.x;
  const int lane = tid & 63, wid = tid >> 6;
  const int kz = blockIdx.x, row0 = blockIdx.y * 128;
  const int k0 = kz * KSLICE;

  const ushort_t* ga0 = A + (size_t)(row0 + (tid >> 2)) * DINNER + k0 + (tid & 3) * 8;
  const ushort_t* ga1 = A + (size_t)(row0 + 64 + (tid >> 2)) * DINNER + k0 + (tid & 3) * 8;
  const ushort_t* gb0 = B + (size_t)(tid >> 2) * DINNER + k0 + (tid & 3) * 8;
  const ushort_t* gb1 = B + (size_t)(64 + (tid >> 2)) * DINNER + k0 + (tid & 3) * 8; // tid<128
  ushort_t* la0 = &As[tid * 8];
  ushort_t* la1 = &As[(256 + tid) * 8];
  ushort_t* lb0 = &Bs[tid * 8];
  ushort_t* lb1 = &Bs[(256 + tid) * 8];                                              // tid<128

  const int lk = (lane >> 4) * 8;
  const int lr16 = lane & 15;

  f32x4 acc[2][6] = {};

  for (int kb = 0; kb < KSLICE; kb += 32) {
    g2lds16(ga0 + kb, la0);
    g2lds16(ga1 + kb, la1);
    g2lds16(gb0 + kb, lb0);
    if (tid < 128) g2lds16(gb1 + kb, lb1);   // rows 64..95 of B (wave-uniform branch)
    __syncthreads();

    short8 af[2], bfr[6];
    #pragma unroll
    for (int i = 0; i < 2; ++i)
      af[i] = *reinterpret_cast<const short8*>(
          &As[(wid * 32 + i * 16 + lr16) * 32 + lk]);
    #pragma unroll
    for (int j = 0; j < 6; ++j)
      bfr[j] = *reinterpret_cast<const short8*>(
          &Bs[(j * 16 + lr16) * 32 + lk]);
    #pragma unroll
    for (int i = 0; i < 2; ++i)
      #pragma unroll
      for (int j = 0; j < 6; ++j)
        acc[i][j] = __builtin_amdgcn_mfma_f32_16x16x32_bf16(
            af[i], bfr[j], acc[i][j], 0, 0, 0);
    __syncthreads();
  }

  const int cr = (lane >> 4) * 4;
  #pragma unroll
  for (int i = 0; i < 2; ++i) {
    #pragma unroll
    for (int j = 0; j < 6; ++j) {
      const int col = j * 16 + lr16;
      #pragma unroll
      for (int r = 0; r < 4; ++r) {
        const int row = row0 + wid * 32 + i * 16 + cr + r;
        partial[((size_t)kz * ROWS + row) * 96 + col] = acc[i][j][r];
      }
    }
  }
}

// ---------------------------------------------------------------------------
// x_proj reduce: sum KSPLIT partials.  cols 0..63 -> bf16 dl16 (dt_proj A);
// cols 64..95 -> fp32 dbcBC[row][32] (B,C for scan).
__global__ __launch_bounds__(256) void xproj_reduce_kernel(
    const float* __restrict__ partial, float* __restrict__ dbcBC,
    ushort_t* __restrict__ dl16)
{
  const int idx = blockIdx.x * 256 + threadIdx.x;   // < ROWS*96
  const int row = idx / 96, j = idx % 96;
  float s = 0.f;
  #pragma unroll
  for (int z = 0; z < KSPLIT; ++z)
    s += partial[(size_t)z * ROWS * 96 + idx];
  if (j < DTRANK) dl16[row * DTRANK + j] = f2bf(s);
  else            dbcBC[row * 32 + (j - DTRANK)] = s;
}

// ---------------------------------------------------------------------------
// Depthwise causal conv (k=4) + bias + SiLU.  Emits fp32 xc and bf16 xc16.
__global__ __launch_bounds__(256) void conv_silu_kernel(
    const float* __restrict__ xcpre, const float* __restrict__ cw,
    const float* __restrict__ cb, float* __restrict__ xc,
    ushort_t* __restrict__ xc16)
{
  const int idx = blockIdx.x * 256 + threadIdx.x;
  const int e  = idx % DINNER;
  const int bl = idx / DINNER;
  const int l  = bl % SEQ;
  float acc = cb[e];
  #pragma unroll
  for (int k = 0; k < DCONV; ++k) {
    const int lk = l + k - (DCONV - 1);
    if (lk >= 0)
      acc += xcpre[(size_t)(bl + k - (DCONV - 1)) * DINNER + e] * cw[e * DCONV + k];
  }
  const float v = acc / (1.f + __expf(-acc));
  xc[idx] = v;
  xc16[idx] = f2bf(v);
}

// ---------------------------------------------------------------------------
// Pass A: lane-per-(b,c,e), 16 states in registers.
__global__ __launch_bounds__(256) void scan_chunk_kernel(
    const float* __restrict__ delta,   // (ROWS, DINNER) softplus'd
    const float* __restrict__ xc,      // (ROWS, DINNER)
    const float* __restrict__ dbcBC,   // (ROWS, 32): [0..16)=B, [16..32)=C
    const float* __restrict__ A_log,   // (DINNER, 16)
    float* __restrict__ Pbuf,          // (BATCH, NCHUNK, DINNER, 16) fp32
    float* __restrict__ Hbuf)          // (BATCH, NCHUNK, DINNER, 16) fp32
{
  __shared__ float sB[CHUNK][16];
  const int bc = blockIdx.y;               // b*NCHUNK + c
  const int b = bc >> 6, c = bc & (NCHUNK - 1);
  const int e = blockIdx.x * 256 + threadIdx.x;
  const size_t row32 = ((size_t)b * SEQ + c * CHUNK) * 32;
  {
    const int t = threadIdx.x >> 4, n = threadIdx.x & 15;  // 256 = CHUNK*16
    sB[t][n] = dbcBC[row32 + t * 32 + n];
  }
  float Aen[16];
  #pragma unroll
  for (int q = 0; q < 4; ++q) {
    const float4 a4 = *reinterpret_cast<const float4*>(&A_log[(size_t)e * 16 + q * 4]);
    Aen[q * 4 + 0] = -__expf(a4.x);
    Aen[q * 4 + 1] = -__expf(a4.y);
    Aen[q * 4 + 2] = -__expf(a4.z);
    Aen[q * 4 + 3] = -__expf(a4.w);
  }
  __syncthreads();

  float h[16];
  #pragma unroll
  for (int n = 0; n < 16; ++n) h[n] = 0.f;
  float sd = 0.f;
  const size_t rowE = ((size_t)b * SEQ + c * CHUNK) * DINNER + e;
  float dv = delta[rowE], xv = xc[rowE];
  for (int t = 0; t < CHUNK; ++t) {
    float dvn = 0.f, xvn = 0.f;
    if (t + 1 < CHUNK) {
      dvn = delta[rowE + (size_t)(t + 1) * DINNER];
      xvn = xc[rowE + (size_t)(t + 1) * DINNER];
    }
    const float dxv = dv * xv;
    sd += dv;
    #pragma unroll
    for (int n = 0; n < 16; ++n) {
      const float dA = __expf(dv * Aen[n]);
      h[n] = dA * h[n] + dxv * sB[t][n];
    }
    dv = dvn; xv = xvn;
  }
  const size_t o = ((size_t)bc * DINNER + e) * 16;
  #pragma unroll
  for (int q = 0; q < 4; ++q) {
    float4 pv, hv;
    pv.x = __expf(Aen[q * 4 + 0] * sd);
    pv.y = __expf(Aen[q * 4 + 1] * sd);
    pv.z = __expf(Aen[q * 4 + 2] * sd);
    pv.w = __expf(Aen[q * 4 + 3] * sd);
    hv.x = h[q * 4 + 0]; hv.y = h[q * 4 + 1];
    hv.z = h[q * 4 + 2]; hv.w = h[q * 4 + 3];
    *reinterpret_cast<float4*>(&Pbuf[o + q * 4]) = pv;
    *reinterpret_cast<float4*>(&Hbuf[o + q * 4]) = hv;
  }
}

// ---------------------------------------------------------------------------
// Pass B: serial combine over NCHUNK summaries; one thread per (b,e,n).
__global__ __launch_bounds__(256) void scan_combine_kernel(
    const float* __restrict__ Pbuf, float* __restrict__ Hbuf)
{
  const int idx = blockIdx.x * 256 + threadIdx.x;   // b*(DINNER*16) + e*16 + n
  const int b = idx >> 15;
  const int en = idx & (DINNER * 16 - 1);
  const size_t base = (size_t)b * NCHUNK * DINNER * 16 + en;
  float H = 0.f;
  float P = Pbuf[base], hf = Hbuf[base];
  for (int c = 0; c < NCHUNK; ++c) {
    const size_t o = base + (size_t)c * DINNER * 16;
    float Pn = 0.f, hfn = 0.f;
    if (c + 1 < NCHUNK) {
      const size_t on = o + (size_t)DINNER * 16;
      Pn = Pbuf[on]; hfn = Hbuf[on];
    }
    Hbuf[o] = H;
    H = P * H + hf;
    P = Pn; hf = hfn;
  }
}

// ---------------------------------------------------------------------------
// Pass C: seeded re-scan fused with C-dot, D skip, z gate -> bf16 yz.
__global__ __launch_bounds__(256) void scan_out_kernel(
    const float* __restrict__ delta,   // (ROWS, DINNER)
    const float* __restrict__ xc,      // (ROWS, DINNER)
    const float* __restrict__ dbcBC,   // (ROWS, 32)
    const ushort_t* __restrict__ z16,  // (ROWS, DINNER) bf16 z
    const float* __restrict__ A_log,   // (DINNER, 16)
    const float* __restrict__ Dp,      // (DINNER)
    const float* __restrict__ Hbuf,    // [b][c][e][n] seeds (fp32)
    ushort_t* __restrict__ yz16)       // (ROWS, DINNER) bf16 out
{
  __shared__ float sB[CHUNK][16];
  __shared__ float sC[CHUNK][16];
  const int bc = blockIdx.y;
  const int b = bc >> 6, c = bc & (NCHUNK - 1);
  const int e = blockIdx.x * 256 + threadIdx.x;
  const size_t row32 = ((size_t)b * SEQ + c * CHUNK) * 32;
  #pragma unroll
  for (int p = 0; p < 2; ++p) {
    const int idx = threadIdx.x + p * 256;       // 512 = CHUNK*32
    const int t = idx >> 5, j = idx & 31;
    const float v = dbcBC[row32 + t * 32 + j];
    if (j < 16) sB[t][j] = v; else sC[t][j - 16] = v;
  }
  float Aen[16];
  #pragma unroll
  for (int q = 0; q < 4; ++q) {
    const float4 a4 = *reinterpret_cast<const float4*>(&A_log[(size_t)e * 16 + q * 4]);
    Aen[q * 4 + 0] = -__expf(a4.x);
    Aen[q * 4 + 1] = -__expf(a4.y);
    Aen[q * 4 + 2] = -__expf(a4.z);
    Aen[q * 4 + 3] = -__expf(a4.w);
  }
  float h[16];
  const size_t oh = ((size_t)bc * DINNER + e) * 16;
  #pragma unroll
  for (int q = 0; q < 4; ++q) {
    const float4 hv = *reinterpret_cast<const float4*>(&Hbuf[oh + q * 4]);
    h[q * 4 + 0] = hv.x; h[q * 4 + 1] = hv.y;
    h[q * 4 + 2] = hv.z; h[q * 4 + 3] = hv.w;
  }
  const float dpe = Dp[e];
  __syncthreads();

  const size_t rowE = ((size_t)b * SEQ + c * CHUNK) * DINNER + e;
  float dv = delta[rowE], xv = xc[rowE];
  float zv = bf2f(z16[rowE]);
  for (int t = 0; t < CHUNK; ++t) {
    float dvn = 0.f, xvn = 0.f, zvn = 0.f;
    if (t + 1 < CHUNK) {
      dvn = delta[rowE + (size_t)(t + 1) * DINNER];
      xvn = xc[rowE + (size_t)(t + 1) * DINNER];
      zvn = bf2f(z16[rowE + (size_t)(t + 1) * DINNER]);
    }
    const float dxv = dv * xv;
    float y = dpe * xv;
    #pragma unroll
    for (int n = 0; n < 16; ++n) {
      const float dA = __expf(dv * Aen[n]);
      h[n] = dA * h[n] + dxv * sB[t][n];
      y += h[n] * sC[t][n];
    }
    const float sz = zv / (1.f + __expf(-zv));
    yz16[rowE + (size_t)t * DINNER] = f2bf(y * sz);
    dv = dvn; xv = xvn; zv = zvn;
  }
}

// ---------------------------------------------------------------------------
extern "C" void kernel_launch(void* const* d_in, const int* in_sizes, int n_in,
                              void* d_out, int out_size, void* d_ws, size_t ws_size,
                              hipStream_t stream)
{
  const float* x         = (const float*)d_in[0];
  const float* norm_w    = (const float*)d_in[1];
  const float* in_proj_w = (const float*)d_in[2];
  const float* conv_w    = (const float*)d_in[3];
  const float* conv_b    = (const float*)d_in[4];
  const float* x_proj_w  = (const float*)d_in[5];
  const float* dt_proj_w = (const float*)d_in[6];
  const float* dt_proj_b = (const float*)d_in[7];
  const float* A_log     = (const float*)d_in[8];
  const float* D_param   = (const float*)d_in[9];
  const float* out_proj_w= (const float*)d_in[10];
  float* out = (float*)d_out;

  // Workspace (float offsets), total <= 18.1875M floats = 72.75 MB (proven).
  // Step order: 1 rms(h16) | 2 cast w16i | 3 gemm1(r: h16,w16i; w: xcpre,z16)
  // 4 conv(r: xcpre; w: xc,xc16) | 5 casts xpw16,dtw16 | 6 xproj(r: xc16,xpw16;
  // w: partial) | 7 reduce(r: partial; w: dbcBC,dl16) | 8 dtproj(r: dl16,dtw16;
  // w: dl_buf) | 9 scanA(w: P,H) | 10 scanB | 11 scanC(w: yz16) | 12 cast w16o
  // 13 gemm2(r: yz16,w16o).
  // Disjoint-at-peak (step 9): xc[0,4M) dl[4M,8M) z16[8M,10M) H[10M,14M)
  // P[14M,18M) dbcBC[18M,18.0625M) dl16[18.0625M,18.125M).
  // Time-shared aliases: h16[0,1M) dead before conv writes xc; w16i[4M,6M) and
  // xc16[6M,8M) dead before dtproj writes dl; xcpre=H region dead before scanA;
  // xpw16[14M,14.09375M), dtw16[14.125M,14.1875M), partial[15M,16.5M),
  // yz16[14M,16M), w16o[17M,18M) all inside P region, pairwise time-disjoint.
  const size_t M = 1024 * 1024;
  float* ws = (float*)d_ws;
  float* xc_buf   = ws;                             // [0,4M)
  float* dl_buf   = ws + 4 * M;                     // [4M,8M)
  ushort_t* z16   = (ushort_t*)(ws + 8 * M);        // [8M,10M)
  float* xcpre    = ws + 10 * M;                    // [10M,14M)
  float* H_buf    = xcpre;                          // [10M,14M)
  float* P_buf    = ws + 14 * M;                    // [14M,18M)
  float* dbcBC    = ws + 18 * M;                    // [18M,18.0625M)
  ushort_t* dl16  = (ushort_t*)(ws + 18 * M + ROWS * 32); // [18.0625M,18.125M)
  ushort_t* h16   = (ushort_t*)ws;                  // [0,1M)
  ushort_t* w16i  = (ushort_t*)dl_buf;              // [4M,6M)
  ushort_t* xc16  = (ushort_t*)(ws + 6 * M);        // [6M,8M)
  ushort_t* xpw16 = (ushort_t*)P_buf;               // [14M,14.09375M)
  ushort_t* dtw16 = (ushort_t*)(ws + 14 * M + 128 * 1024); // [14.125M,14.1875M)
  float* partial  = ws + 15 * M;                    // [15M,16.5M)
  ushort_t* yz16  = (ushort_t*)P_buf;               // [14M,16M)
  ushort_t* w16o  = (ushort_t*)(ws + 17 * M);       // [17M,18M)

  hipMemcpyAsync(out, x, (size_t)ROWS * DMODEL * sizeof(float),
                 hipMemcpyDeviceToDevice, stream);

  for (int layer = 0; layer < NLAYERS; ++layer) {
    const float* nw  = norm_w     + (size_t)layer * DMODEL;
    const float* iw  = in_proj_w  + (size_t)layer * 2 * DINNER * DMODEL;
    const float* cw  = conv_w     + (size_t)layer * DINNER * DCONV;
    const float* cb  = conv_b     + (size_t)layer * DINNER;
    const float* xpw = x_proj_w   + (size_t)layer * 96 * DINNER;
    const float* dtw = dt_proj_w  + (size_t)layer * DINNER * DTRANK;
    const float* dtb = dt_proj_b  + (size_t)layer * DINNER;
    const float* Al  = A_log      + (size_t)layer * DINNER * DSTATE;
    const float* Dpp = D_param    + (size_t)layer * DINNER;
    const float* ow  = out_proj_w + (size_t)layer * DMODEL * DINNER;

    // 1. h = rmsnorm(residual) -> bf16
    rmsnorm_kernel<<<ROWS, 256, 0, stream>>>(out, nw, h16);

    // 2. cast in_proj weights to bf16
    cast_bf16_kernel<<<(2 * DINNER * DMODEL) / 1024, 256, 0, stream>>>(iw, w16i);

    // 3. xz = h @ in_w^T (bf16 MFMA); cols<2048 -> xcpre fp32, cols>=2048 -> z16
    gemm_bf16_kernel<2>
        <<<dim3(2 * DINNER / 128, ROWS / 128), 256, 0, stream>>>(
            h16, w16i, xcpre, z16, nullptr, DMODEL, DMODEL, DMODEL, DINNER);

    // 4. xc = silu(causal_conv(xcpre) + cb)  (fp32 + bf16)
    conv_silu_kernel<<<(size_t)ROWS * DINNER / 256, 256, 0, stream>>>(
        xcpre, cw, cb, xc_buf, xc16);

    // 5. cast x_proj / dt_proj weights
    cast_bf16_kernel<<<(96 * DINNER) / 1024, 256, 0, stream>>>(xpw, xpw16);
    cast_bf16_kernel<<<(DINNER * DTRANK) / 1024, 256, 0, stream>>>(dtw, dtw16);

    // 6+7. dbc = xc @ xpw^T  (bf16 MFMA split-K + reduce)
    xproj_mfma_kernel<<<dim3(KSPLIT, ROWS / 128), 256, 0, stream>>>(
        xc16, xpw16, partial);
    xproj_reduce_kernel<<<ROWS * 96 / 256, 256, 0, stream>>>(
        partial, dbcBC, dl16);

    // 8. delta = softplus(dl16 @ dtw^T + dtb)  (bf16 MFMA, fused epilogue)
    gemm_bf16_kernel<3>
        <<<dim3(DINNER / 128, ROWS / 128), 256, 0, stream>>>(
            dl16, dtw16, dl_buf, nullptr, dtb, DTRANK, DTRANK, DTRANK, DINNER);

    // 9-11. chunked selective scan + D skip + z gate -> yz16
    scan_chunk_kernel<<<dim3(DINNER / 256, BATCH * NCHUNK), 256, 0, stream>>>(
        dl_buf, xc_buf, dbcBC, Al, P_buf, H_buf);
    scan_combine_kernel<<<BATCH * DINNER * 16 / 256, 256, 0, stream>>>(
        P_buf, H_buf);
    scan_out_kernel<<<dim3(DINNER / 256, BATCH * NCHUNK), 256, 0, stream>>>(
        dl_buf, xc_buf, dbcBC, z16, Al, Dpp, H_buf, yz16);

    // 12. cast out_proj weights to bf16
    cast_bf16_kernel<<<(DMODEL * DINNER) / 1024, 256, 0, stream>>>(ow, w16o);

    // 13. residual += yz @ ow^T  (bf16 MFMA, ACC)
    gemm_bf16_kernel<1>
        <<<dim3(DMODEL / 128, ROWS / 128), 256, 0, stream>>>(
            yz16, w16o, out, nullptr, nullptr, DINNER, DINNER, DINNER, DMODEL);
  }
}

// Round 9
// 383.054 us; speedup vs baseline: 6.6359x; 1.1336x over previous
//
#include <hip/hip_runtime.h>
#include <hip/hip_bf16.h>

// Problem constants
#define BATCH   2
#define SEQ     1024
#define DMODEL  1024
#define DINNER  2048
#define DSTATE  16
#define DTRANK  64
#define DCONV   4
#define NLAYERS 2
#define ROWS    (BATCH*SEQ)        // 2048 (b,l) rows
#define NCHUNK  64
#define CHUNK   16                 // SEQ / NCHUNK
#define KSPLIT  8
#define KSLICE  (DINNER / KSPLIT)  // 256  (x_proj)
#define KSO     4
#define KSLICE_O (DINNER / KSO)    // 512  (out_proj)

typedef unsigned short ushort_t;
typedef __attribute__((ext_vector_type(8))) short short8;
typedef __attribute__((ext_vector_type(4))) float f32x4;

// fp32 -> bf16 round-to-nearest-even
__device__ __forceinline__ ushort_t f2bf(float f) {
  union { float f; unsigned u; } v; v.f = f;
  unsigned r = v.u + 0x7fffu + ((v.u >> 16) & 1u);
  return (ushort_t)(r >> 16);
}
__device__ __forceinline__ float bf2f(ushort_t h) {
  union { unsigned u; float f; } v; v.u = ((unsigned)h) << 16;
  return v.f;
}

// async global->LDS 16B
__device__ __forceinline__ void g2lds16(const ushort_t* g, ushort_t* l) {
  __builtin_amdgcn_global_load_lds(
      (const __attribute__((address_space(1))) void*)g,
      (__attribute__((address_space(3))) void*)l, 16, 0, 0);
}

// XCD-aware bijective block swizzle (requires gridDim.x*gridDim.y % 8 == 0).
__device__ __forceinline__ void xcd_swz(int& bx, int& by) {
  const int nx = gridDim.x, nwg = nx * gridDim.y;
  int id = by * nx + bx;
  const int q = nwg >> 3;
  id = (id & 7) * q + (id >> 3);
  bx = id % nx; by = id / nx;
}

// LDS quarter-swizzle helpers (store quarter q of row r at q ^ ((r>>1)&3)):
//   staging source quarter for thread tid (dest row tid>>2, dest quarter tid&3)
#define STG_Q(tid) (((tid) & 3) ^ (((tid) >> 3) & 3))
//   fragment read offset (elems) for a row ...+ (lane&15)
#define LDQ(lane)  ((((lane) >> 4) ^ (((lane) >> 1) & 3)) * 8)

// ---------------------------------------------------------------------------
// cast fp32 -> bf16, 4 elems/thread
__global__ __launch_bounds__(256) void cast_bf16_kernel(
    const float* __restrict__ in, ushort_t* __restrict__ out)
{
  const int i = blockIdx.x * 256 + threadIdx.x;
  const float4 v = reinterpret_cast<const float4*>(in)[i];
  ushort4 o;
  o.x = f2bf(v.x); o.y = f2bf(v.y); o.z = f2bf(v.z); o.w = f2bf(v.w);
  reinterpret_cast<ushort4*>(out)[i] = o;
}

// ---------------------------------------------------------------------------
// RMSNorm: one block per row of DMODEL, bf16 output
__global__ __launch_bounds__(256) void rmsnorm_kernel(
    const float* __restrict__ x, const float* __restrict__ w,
    ushort_t* __restrict__ out)
{
  const int row = blockIdx.x;
  const float* xr = x + (size_t)row * DMODEL;
  float ss = 0.f;
  #pragma unroll
  for (int i = threadIdx.x; i < DMODEL; i += 256) { float v = xr[i]; ss += v * v; }
  #pragma unroll
  for (int m = 1; m < 64; m <<= 1) ss += __shfl_xor(ss, m);
  __shared__ float red[4];
  if ((threadIdx.x & 63) == 0) red[threadIdx.x >> 6] = ss;
  __syncthreads();
  float tot = red[0] + red[1] + red[2] + red[3];
  float scale = rsqrtf(tot * (1.f / DMODEL) + 1e-5f);
  #pragma unroll
  for (int i = threadIdx.x; i < DMODEL; i += 256)
    out[(size_t)row * DMODEL + i] = f2bf(xr[i] * scale * w[i]);
}

// ---------------------------------------------------------------------------
// bf16 MFMA GEMM: D[M][N] = A[M][K] * B[N][K]^T.
// BM=BN=128, BK=32, 256 threads = 4 waves (2x2), 64x64 per wave.
// MODE 0: C=fp32 store.  MODE 2: zsplit (cols<DINNER -> fp32 C, else bf16 C2).
// MODE 3: C = softplus(acc + bias[col]) fp32.
template<int MODE>
__global__ __launch_bounds__(256) void gemm_bf16_kernel(
    const ushort_t* __restrict__ A, const ushort_t* __restrict__ B,
    float* __restrict__ C, ushort_t* __restrict__ C2,
    const float* __restrict__ bias, int K, int lda, int ldb, int ldc)
{
  __shared__ __align__(16) ushort_t As[128 * 32];
  __shared__ __align__(16) ushort_t Bs[128 * 32];
  const int tid = threadIdx.x;
  const int lane = tid & 63, wid = tid >> 6;
  const int wr = wid >> 1, wc = wid & 1;
  int bx = blockIdx.x, by = blockIdx.y;
  xcd_swz(bx, by);
  const int row0 = by * 128, col0 = bx * 128;

  const int sq = STG_Q(tid) * 8;
  const ushort_t* ga0 = A + (size_t)(row0 + (tid >> 2)) * lda + sq;
  const ushort_t* ga1 = A + (size_t)(row0 + 64 + (tid >> 2)) * lda + sq;
  const ushort_t* gb0 = B + (size_t)(col0 + (tid >> 2)) * ldb + sq;
  const ushort_t* gb1 = B + (size_t)(col0 + 64 + (tid >> 2)) * ldb + sq;
  ushort_t* la0 = &As[tid * 8];
  ushort_t* la1 = &As[(256 + tid) * 8];
  ushort_t* lb0 = &Bs[tid * 8];
  ushort_t* lb1 = &Bs[(256 + tid) * 8];

  const int lk = LDQ(lane);
  const int lr16 = lane & 15;

  f32x4 acc[4][4] = {};

  for (int kb = 0; kb < K; kb += 32) {
    g2lds16(ga0 + kb, la0);
    g2lds16(ga1 + kb, la1);
    g2lds16(gb0 + kb, lb0);
    g2lds16(gb1 + kb, lb1);
    __syncthreads();

    short8 af[4], bfr[4];
    #pragma unroll
    for (int i = 0; i < 4; ++i)
      af[i] = *reinterpret_cast<const short8*>(
          &As[(wr * 64 + i * 16 + lr16) * 32 + lk]);
    #pragma unroll
    for (int j = 0; j < 4; ++j)
      bfr[j] = *reinterpret_cast<const short8*>(
          &Bs[(wc * 64 + j * 16 + lr16) * 32 + lk]);
    #pragma unroll
    for (int i = 0; i < 4; ++i)
      #pragma unroll
      for (int j = 0; j < 4; ++j)
        acc[i][j] = __builtin_amdgcn_mfma_f32_16x16x32_bf16(
            af[i], bfr[j], acc[i][j], 0, 0, 0);
    __syncthreads();
  }

  // C/D layout: col = lane&15, row = (lane>>4)*4 + reg
  const int cr = (lane >> 4) * 4;
  #pragma unroll
  for (int i = 0; i < 4; ++i) {
    #pragma unroll
    for (int j = 0; j < 4; ++j) {
      const int col = col0 + wc * 64 + j * 16 + lr16;
      #pragma unroll
      for (int r = 0; r < 4; ++r) {
        const int row = row0 + wr * 64 + i * 16 + cr + r;
        float v = acc[i][j][r];
        if (MODE == 2) {
          if (col < DINNER)
            C[(size_t)row * ldc + col] = v;
          else
            C2[(size_t)row * DINNER + (col - DINNER)] = f2bf(v);
        } else if (MODE == 3) {
          v += bias[col];
          v = (v > 20.f) ? v : log1pf(__expf(v));
          C[(size_t)row * ldc + col] = v;
        } else {
          C[(size_t)row * ldc + col] = v;
        }
      }
    }
  }
}

// ---------------------------------------------------------------------------
// out_proj split-K: partial[z] = yz16 @ ow16^T over K slice z (512 wide).
__global__ __launch_bounds__(256) void outproj_splitk_kernel(
    const ushort_t* __restrict__ A,    // (ROWS, DINNER)
    const ushort_t* __restrict__ B,    // (DMODEL, DINNER)
    float* __restrict__ partial)       // (KSO, ROWS, DMODEL)
{
  __shared__ __align__(16) ushort_t As[128 * 32];
  __shared__ __align__(16) ushort_t Bs[128 * 32];
  const int tid = threadIdx.x;
  const int lane = tid & 63, wid = tid >> 6;
  const int wr = wid >> 1, wc = wid & 1;
  int bx = blockIdx.x, by = blockIdx.y;
  xcd_swz(bx, by);
  const int row0 = by * 128, col0 = bx * 128;
  const int k0 = blockIdx.z * KSLICE_O;

  const int sq = STG_Q(tid) * 8;
  const ushort_t* ga0 = A + (size_t)(row0 + (tid >> 2)) * DINNER + k0 + sq;
  const ushort_t* ga1 = A + (size_t)(row0 + 64 + (tid >> 2)) * DINNER + k0 + sq;
  const ushort_t* gb0 = B + (size_t)(col0 + (tid >> 2)) * DINNER + k0 + sq;
  const ushort_t* gb1 = B + (size_t)(col0 + 64 + (tid >> 2)) * DINNER + k0 + sq;
  ushort_t* la0 = &As[tid * 8];
  ushort_t* la1 = &As[(256 + tid) * 8];
  ushort_t* lb0 = &Bs[tid * 8];
  ushort_t* lb1 = &Bs[(256 + tid) * 8];

  const int lk = LDQ(lane);
  const int lr16 = lane & 15;

  f32x4 acc[4][4] = {};

  for (int kb = 0; kb < KSLICE_O; kb += 32) {
    g2lds16(ga0 + kb, la0);
    g2lds16(ga1 + kb, la1);
    g2lds16(gb0 + kb, lb0);
    g2lds16(gb1 + kb, lb1);
    __syncthreads();

    short8 af[4], bfr[4];
    #pragma unroll
    for (int i = 0; i < 4; ++i)
      af[i] = *reinterpret_cast<const short8*>(
          &As[(wr * 64 + i * 16 + lr16) * 32 + lk]);
    #pragma unroll
    for (int j = 0; j < 4; ++j)
      bfr[j] = *reinterpret_cast<const short8*>(
          &Bs[(wc * 64 + j * 16 + lr16) * 32 + lk]);
    #pragma unroll
    for (int i = 0; i < 4; ++i)
      #pragma unroll
      for (int j = 0; j < 4; ++j)
        acc[i][j] = __builtin_amdgcn_mfma_f32_16x16x32_bf16(
            af[i], bfr[j], acc[i][j], 0, 0, 0);
    __syncthreads();
  }

  float* Cz = partial + (size_t)blockIdx.z * ROWS * DMODEL;
  const int cr = (lane >> 4) * 4;
  #pragma unroll
  for (int i = 0; i < 4; ++i) {
    #pragma unroll
    for (int j = 0; j < 4; ++j) {
      const int col = col0 + wc * 64 + j * 16 + lr16;
      #pragma unroll
      for (int r = 0; r < 4; ++r) {
        const int row = row0 + wr * 64 + i * 16 + cr + r;
        Cz[(size_t)row * DMODEL + col] = acc[i][j][r];
      }
    }
  }
}

// out += sum_z partial[z]   (float4, 4 elems/thread)
__global__ __launch_bounds__(256) void outproj_reduce_kernel(
    const float* __restrict__ partial, float* __restrict__ out)
{
  const int i = blockIdx.x * 256 + threadIdx.x;
  float4 s = reinterpret_cast<float4*>(out)[i];
  #pragma unroll
  for (int z = 0; z < KSO; ++z) {
    const float4 p = reinterpret_cast<const float4*>(
        partial + (size_t)z * ROWS * DMODEL)[i];
    s.x += p.x; s.y += p.y; s.z += p.z; s.w += p.w;
  }
  reinterpret_cast<float4*>(out)[i] = s;
}

// ---------------------------------------------------------------------------
// x_proj MFMA split-K: partial[kz] = xc16[.,k0:k0+256] @ xpw16[.,k0:k0+256]^T
__global__ __launch_bounds__(256) void xproj_mfma_kernel(
    const ushort_t* __restrict__ A,    // (ROWS, DINNER) bf16 xc
    const ushort_t* __restrict__ B,    // (96, DINNER) bf16 xpw
    float* __restrict__ partial)       // (KSPLIT, ROWS, 96) fp32
{
  __shared__ __align__(16) ushort_t As[128 * 32];
  __shared__ __align__(16) ushort_t Bs[96 * 32];
  const int tid = threadIdx.x;
  const int lane = tid & 63, wid = tid >> 6;
  int bx = blockIdx.x, by = blockIdx.y;
  xcd_swz(bx, by);
  const int kz = bx, row0 = by * 128;
  const int k0 = kz * KSLICE;

  const int sq = STG_Q(tid) * 8;
  const ushort_t* ga0 = A + (size_t)(row0 + (tid >> 2)) * DINNER + k0 + sq;
  const ushort_t* ga1 = A + (size_t)(row0 + 64 + (tid >> 2)) * DINNER + k0 + sq;
  const ushort_t* gb0 = B + (size_t)(tid >> 2) * DINNER + k0 + sq;
  const ushort_t* gb1 = B + (size_t)(64 + (tid >> 2)) * DINNER + k0 + sq; // tid<128
  ushort_t* la0 = &As[tid * 8];
  ushort_t* la1 = &As[(256 + tid) * 8];
  ushort_t* lb0 = &Bs[tid * 8];
  ushort_t* lb1 = &Bs[(256 + tid) * 8];                                  // tid<128

  const int lk = LDQ(lane);
  const int lr16 = lane & 15;

  f32x4 acc[2][6] = {};

  for (int kb = 0; kb < KSLICE; kb += 32) {
    g2lds16(ga0 + kb, la0);
    g2lds16(ga1 + kb, la1);
    g2lds16(gb0 + kb, lb0);
    if (tid < 128) g2lds16(gb1 + kb, lb1);   // rows 64..95 of B
    __syncthreads();

    short8 af[2], bfr[6];
    #pragma unroll
    for (int i = 0; i < 2; ++i)
      af[i] = *reinterpret_cast<const short8*>(
          &As[(wid * 32 + i * 16 + lr16) * 32 + lk]);
    #pragma unroll
    for (int j = 0; j < 6; ++j)
      bfr[j] = *reinterpret_cast<const short8*>(
          &Bs[(j * 16 + lr16) * 32 + lk]);
    #pragma unroll
    for (int i = 0; i < 2; ++i)
      #pragma unroll
      for (int j = 0; j < 6; ++j)
        acc[i][j] = __builtin_amdgcn_mfma_f32_16x16x32_bf16(
            af[i], bfr[j], acc[i][j], 0, 0, 0);
    __syncthreads();
  }

  const int cr = (lane >> 4) * 4;
  #pragma unroll
  for (int i = 0; i < 2; ++i) {
    #pragma unroll
    for (int j = 0; j < 6; ++j) {
      const int col = j * 16 + lr16;
      #pragma unroll
      for (int r = 0; r < 4; ++r) {
        const int row = row0 + wid * 32 + i * 16 + cr + r;
        partial[((size_t)kz * ROWS + row) * 96 + col] = acc[i][j][r];
      }
    }
  }
}

// ---------------------------------------------------------------------------
// x_proj reduce: sum KSPLIT partials.  cols 0..63 -> bf16 dl16 (dt_proj A);
// cols 64..95 -> fp32 dbcBC[row][32] (B,C for scan).
__global__ __launch_bounds__(256) void xproj_reduce_kernel(
    const float* __restrict__ partial, float* __restrict__ dbcBC,
    ushort_t* __restrict__ dl16)
{
  const int idx = blockIdx.x * 256 + threadIdx.x;   // < ROWS*96
  const int row = idx / 96, j = idx % 96;
  float s = 0.f;
  #pragma unroll
  for (int z = 0; z < KSPLIT; ++z)
    s += partial[(size_t)z * ROWS * 96 + idx];
  if (j < DTRANK) dl16[row * DTRANK + j] = f2bf(s);
  else            dbcBC[row * 32 + (j - DTRANK)] = s;
}

// ---------------------------------------------------------------------------
// Depthwise causal conv (k=4) + bias + SiLU.  Emits fp32 xc and bf16 xc16.
__global__ __launch_bounds__(256) void conv_silu_kernel(
    const float* __restrict__ xcpre, const float* __restrict__ cw,
    const float* __restrict__ cb, float* __restrict__ xc,
    ushort_t* __restrict__ xc16)
{
  const int idx = blockIdx.x * 256 + threadIdx.x;
  const int e  = idx % DINNER;
  const int bl = idx / DINNER;
  const int l  = bl % SEQ;
  float acc = cb[e];
  #pragma unroll
  for (int k = 0; k < DCONV; ++k) {
    const int lk = l + k - (DCONV - 1);
    if (lk >= 0)
      acc += xcpre[(size_t)(bl + k - (DCONV - 1)) * DINNER + e] * cw[e * DCONV + k];
  }
  const float v = acc / (1.f + __expf(-acc));
  xc[idx] = v;
  xc16[idx] = f2bf(v);
}

// ---------------------------------------------------------------------------
// Pass A: lane-per-(b,c,e), 16 states in registers.
__global__ __launch_bounds__(256) void scan_chunk_kernel(
    const float* __restrict__ delta,   // (ROWS, DINNER) softplus'd
    const float* __restrict__ xc,      // (ROWS, DINNER)
    const float* __restrict__ dbcBC,   // (ROWS, 32): [0..16)=B, [16..32)=C
    const float* __restrict__ A_log,   // (DINNER, 16)
    float* __restrict__ Pbuf,          // (BATCH, NCHUNK, DINNER, 16) fp32
    float* __restrict__ Hbuf)          // (BATCH, NCHUNK, DINNER, 16) fp32
{
  __shared__ float sB[CHUNK][16];
  const int bc = blockIdx.y;               // b*NCHUNK + c
  const int b = bc >> 6, c = bc & (NCHUNK - 1);
  const int e = blockIdx.x * 256 + threadIdx.x;
  const size_t row32 = ((size_t)b * SEQ + c * CHUNK) * 32;
  {
    const int t = threadIdx.x >> 4, n = threadIdx.x & 15;  // 256 = CHUNK*16
    sB[t][n] = dbcBC[row32 + t * 32 + n];
  }
  float Aen[16];
  #pragma unroll
  for (int q = 0; q < 4; ++q) {
    const float4 a4 = *reinterpret_cast<const float4*>(&A_log[(size_t)e * 16 + q * 4]);
    Aen[q * 4 + 0] = -__expf(a4.x);
    Aen[q * 4 + 1] = -__expf(a4.y);
    Aen[q * 4 + 2] = -__expf(a4.z);
    Aen[q * 4 + 3] = -__expf(a4.w);
  }
  __syncthreads();

  float h[16];
  #pragma unroll
  for (int n = 0; n < 16; ++n) h[n] = 0.f;
  float sd = 0.f;
  const size_t rowE = ((size_t)b * SEQ + c * CHUNK) * DINNER + e;
  float dv = delta[rowE], xv = xc[rowE];
  for (int t = 0; t < CHUNK; ++t) {
    float dvn = 0.f, xvn = 0.f;
    if (t + 1 < CHUNK) {
      dvn = delta[rowE + (size_t)(t + 1) * DINNER];
      xvn = xc[rowE + (size_t)(t + 1) * DINNER];
    }
    const float dxv = dv * xv;
    sd += dv;
    #pragma unroll
    for (int n = 0; n < 16; ++n) {
      const float dA = __expf(dv * Aen[n]);
      h[n] = dA * h[n] + dxv * sB[t][n];
    }
    dv = dvn; xv = xvn;
  }
  const size_t o = ((size_t)bc * DINNER + e) * 16;
  #pragma unroll
  for (int q = 0; q < 4; ++q) {
    float4 pv, hv;
    pv.x = __expf(Aen[q * 4 + 0] * sd);
    pv.y = __expf(Aen[q * 4 + 1] * sd);
    pv.z = __expf(Aen[q * 4 + 2] * sd);
    pv.w = __expf(Aen[q * 4 + 3] * sd);
    hv.x = h[q * 4 + 0]; hv.y = h[q * 4 + 1];
    hv.z = h[q * 4 + 2]; hv.w = h[q * 4 + 3];
    *reinterpret_cast<float4*>(&Pbuf[o + q * 4]) = pv;
    *reinterpret_cast<float4*>(&Hbuf[o + q * 4]) = hv;
  }
}

// ---------------------------------------------------------------------------
// Pass B: serial combine over NCHUNK summaries; one thread per (b,e,n).
__global__ __launch_bounds__(256) void scan_combine_kernel(
    const float* __restrict__ Pbuf, float* __restrict__ Hbuf)
{
  const int idx = blockIdx.x * 256 + threadIdx.x;   // b*(DINNER*16) + e*16 + n
  const int b = idx >> 15;
  const int en = idx & (DINNER * 16 - 1);
  const size_t base = (size_t)b * NCHUNK * DINNER * 16 + en;
  float H = 0.f;
  float P = Pbuf[base], hf = Hbuf[base];
  for (int c = 0; c < NCHUNK; ++c) {
    const size_t o = base + (size_t)c * DINNER * 16;
    float Pn = 0.f, hfn = 0.f;
    if (c + 1 < NCHUNK) {
      const size_t on = o + (size_t)DINNER * 16;
      Pn = Pbuf[on]; hfn = Hbuf[on];
    }
    Hbuf[o] = H;
    H = P * H + hf;
    P = Pn; hf = hfn;
  }
}

// ---------------------------------------------------------------------------
// Pass C: seeded re-scan fused with C-dot, D skip, z gate -> bf16 yz.
__global__ __launch_bounds__(256) void scan_out_kernel(
    const float* __restrict__ delta,   // (ROWS, DINNER)
    const float* __restrict__ xc,      // (ROWS, DINNER)
    const float* __restrict__ dbcBC,   // (ROWS, 32)
    const ushort_t* __restrict__ z16,  // (ROWS, DINNER) bf16 z
    const float* __restrict__ A_log,   // (DINNER, 16)
    const float* __restrict__ Dp,      // (DINNER)
    const float* __restrict__ Hbuf,    // [b][c][e][n] seeds (fp32)
    ushort_t* __restrict__ yz16)       // (ROWS, DINNER) bf16 out
{
  __shared__ float sB[CHUNK][16];
  __shared__ float sC[CHUNK][16];
  const int bc = blockIdx.y;
  const int b = bc >> 6, c = bc & (NCHUNK - 1);
  const int e = blockIdx.x * 256 + threadIdx.x;
  const size_t row32 = ((size_t)b * SEQ + c * CHUNK) * 32;
  #pragma unroll
  for (int p = 0; p < 2; ++p) {
    const int idx = threadIdx.x + p * 256;       // 512 = CHUNK*32
    const int t = idx >> 5, j = idx & 31;
    const float v = dbcBC[row32 + t * 32 + j];
    if (j < 16) sB[t][j] = v; else sC[t][j - 16] = v;
  }
  float Aen[16];
  #pragma unroll
  for (int q = 0; q < 4; ++q) {
    const float4 a4 = *reinterpret_cast<const float4*>(&A_log[(size_t)e * 16 + q * 4]);
    Aen[q * 4 + 0] = -__expf(a4.x);
    Aen[q * 4 + 1] = -__expf(a4.y);
    Aen[q * 4 + 2] = -__expf(a4.z);
    Aen[q * 4 + 3] = -__expf(a4.w);
  }
  float h[16];
  const size_t oh = ((size_t)bc * DINNER + e) * 16;
  #pragma unroll
  for (int q = 0; q < 4; ++q) {
    const float4 hv = *reinterpret_cast<const float4*>(&Hbuf[oh + q * 4]);
    h[q * 4 + 0] = hv.x; h[q * 4 + 1] = hv.y;
    h[q * 4 + 2] = hv.z; h[q * 4 + 3] = hv.w;
  }
  const float dpe = Dp[e];
  __syncthreads();

  const size_t rowE = ((size_t)b * SEQ + c * CHUNK) * DINNER + e;
  float dv = delta[rowE], xv = xc[rowE];
  float zv = bf2f(z16[rowE]);
  for (int t = 0; t < CHUNK; ++t) {
    float dvn = 0.f, xvn = 0.f, zvn = 0.f;
    if (t + 1 < CHUNK) {
      dvn = delta[rowE + (size_t)(t + 1) * DINNER];
      xvn = xc[rowE + (size_t)(t + 1) * DINNER];
      zvn = bf2f(z16[rowE + (size_t)(t + 1) * DINNER]);
    }
    const float dxv = dv * xv;
    float y = dpe * xv;
    #pragma unroll
    for (int n = 0; n < 16; ++n) {
      const float dA = __expf(dv * Aen[n]);
      h[n] = dA * h[n] + dxv * sB[t][n];
      y += h[n] * sC[t][n];
    }
    const float sz = zv / (1.f + __expf(-zv));
    yz16[rowE + (size_t)t * DINNER] = f2bf(y * sz);
    dv = dvn; xv = xvn; zv = zvn;
  }
}

// ---------------------------------------------------------------------------
extern "C" void kernel_launch(void* const* d_in, const int* in_sizes, int n_in,
                              void* d_out, int out_size, void* d_ws, size_t ws_size,
                              hipStream_t stream)
{
  const float* x         = (const float*)d_in[0];
  const float* norm_w    = (const float*)d_in[1];
  const float* in_proj_w = (const float*)d_in[2];
  const float* conv_w    = (const float*)d_in[3];
  const float* conv_b    = (const float*)d_in[4];
  const float* x_proj_w  = (const float*)d_in[5];
  const float* dt_proj_w = (const float*)d_in[6];
  const float* dt_proj_b = (const float*)d_in[7];
  const float* A_log     = (const float*)d_in[8];
  const float* D_param   = (const float*)d_in[9];
  const float* out_proj_w= (const float*)d_in[10];
  float* out = (float*)d_out;

  // Workspace (float offsets), total <= 18.1875M floats = 72.75 MB (proven).
  // Same liveness-checked layout as R8 + partialO[0,8M) for out_proj split-K
  // (xc and dl are both dead after scanC, before gemm2 launches).
  const size_t M = 1024 * 1024;
  float* ws = (float*)d_ws;
  float* xc_buf   = ws;                             // [0,4M)
  float* dl_buf   = ws + 4 * M;                     // [4M,8M)
  ushort_t* z16   = (ushort_t*)(ws + 8 * M);        // [8M,10M)
  float* xcpre    = ws + 10 * M;                    // [10M,14M)
  float* H_buf    = xcpre;                          // [10M,14M)
  float* P_buf    = ws + 14 * M;                    // [14M,18M)
  float* dbcBC    = ws + 18 * M;                    // [18M,18.0625M)
  ushort_t* dl16  = (ushort_t*)(ws + 18 * M + ROWS * 32); // [18.0625M,18.125M)
  ushort_t* h16   = (ushort_t*)ws;                  // [0,1M)
  ushort_t* w16i  = (ushort_t*)dl_buf;              // [4M,6M)
  ushort_t* xc16  = (ushort_t*)(ws + 6 * M);        // [6M,8M)
  ushort_t* xpw16 = (ushort_t*)P_buf;               // [14M,14.09375M)
  ushort_t* dtw16 = (ushort_t*)(ws + 14 * M + 128 * 1024); // [14.125M,14.1875M)
  float* partial  = ws + 15 * M;                    // [15M,16.5M)
  ushort_t* yz16  = (ushort_t*)P_buf;               // [14M,16M)
  ushort_t* w16o  = (ushort_t*)(ws + 17 * M);       // [17M,18M)
  float* partialO = ws;                             // [0,8M)  gemm2 only

  hipMemcpyAsync(out, x, (size_t)ROWS * DMODEL * sizeof(float),
                 hipMemcpyDeviceToDevice, stream);

  for (int layer = 0; layer < NLAYERS; ++layer) {
    const float* nw  = norm_w     + (size_t)layer * DMODEL;
    const float* iw  = in_proj_w  + (size_t)layer * 2 * DINNER * DMODEL;
    const float* cw  = conv_w     + (size_t)layer * DINNER * DCONV;
    const float* cb  = conv_b     + (size_t)layer * DINNER;
    const float* xpw = x_proj_w   + (size_t)layer * 96 * DINNER;
    const float* dtw = dt_proj_w  + (size_t)layer * DINNER * DTRANK;
    const float* dtb = dt_proj_b  + (size_t)layer * DINNER;
    const float* Al  = A_log      + (size_t)layer * DINNER * DSTATE;
    const float* Dpp = D_param    + (size_t)layer * DINNER;
    const float* ow  = out_proj_w + (size_t)layer * DMODEL * DINNER;

    // 1. h = rmsnorm(residual) -> bf16
    rmsnorm_kernel<<<ROWS, 256, 0, stream>>>(out, nw, h16);

    // 2. cast in_proj weights to bf16
    cast_bf16_kernel<<<(2 * DINNER * DMODEL) / 1024, 256, 0, stream>>>(iw, w16i);

    // 3. xz = h @ in_w^T (bf16 MFMA); cols<2048 -> xcpre fp32, cols>=2048 -> z16
    gemm_bf16_kernel<2>
        <<<dim3(2 * DINNER / 128, ROWS / 128), 256, 0, stream>>>(
            h16, w16i, xcpre, z16, nullptr, DMODEL, DMODEL, DMODEL, DINNER);

    // 4. xc = silu(causal_conv(xcpre) + cb)  (fp32 + bf16)
    conv_silu_kernel<<<(size_t)ROWS * DINNER / 256, 256, 0, stream>>>(
        xcpre, cw, cb, xc_buf, xc16);

    // 5. cast x_proj / dt_proj weights
    cast_bf16_kernel<<<(96 * DINNER) / 1024, 256, 0, stream>>>(xpw, xpw16);
    cast_bf16_kernel<<<(DINNER * DTRANK) / 1024, 256, 0, stream>>>(dtw, dtw16);

    // 6+7. dbc = xc @ xpw^T  (bf16 MFMA split-K + reduce)
    xproj_mfma_kernel<<<dim3(KSPLIT, ROWS / 128), 256, 0, stream>>>(
        xc16, xpw16, partial);
    xproj_reduce_kernel<<<ROWS * 96 / 256, 256, 0, stream>>>(
        partial, dbcBC, dl16);

    // 8. delta = softplus(dl16 @ dtw^T + dtb)  (bf16 MFMA, fused epilogue)
    gemm_bf16_kernel<3>
        <<<dim3(DINNER / 128, ROWS / 128), 256, 0, stream>>>(
            dl16, dtw16, dl_buf, nullptr, dtb, DTRANK, DTRANK, DTRANK, DINNER);

    // 9-11. chunked selective scan + D skip + z gate -> yz16
    scan_chunk_kernel<<<dim3(DINNER / 256, BATCH * NCHUNK), 256, 0, stream>>>(
        dl_buf, xc_buf, dbcBC, Al, P_buf, H_buf);
    scan_combine_kernel<<<BATCH * DINNER * 16 / 256, 256, 0, stream>>>(
        P_buf, H_buf);
    scan_out_kernel<<<dim3(DINNER / 256, BATCH * NCHUNK), 256, 0, stream>>>(
        dl_buf, xc_buf, dbcBC, z16, Al, Dpp, H_buf, yz16);

    // 12. cast out_proj weights to bf16
    cast_bf16_kernel<<<(DMODEL * DINNER) / 1024, 256, 0, stream>>>(ow, w16o);

    // 13a. out_proj split-K: partialO[z] = yz @ ow^T (K slice z)
    outproj_splitk_kernel
        <<<dim3(DMODEL / 128, ROWS / 128, KSO), 256, 0, stream>>>(
            yz16, w16o, partialO);
    // 13b. residual += sum_z partialO[z]
    outproj_reduce_kernel<<<ROWS * DMODEL / 1024, 256, 0, stream>>>(
        partialO, out);
  }
}

// Round 10
// 344.473 us; speedup vs baseline: 7.3792x; 1.1120x over previous
//
#include <hip/hip_runtime.h>
#include <hip/hip_bf16.h>

// Problem constants
#define BATCH   2
#define SEQ     1024
#define DMODEL  1024
#define DINNER  2048
#define DSTATE  16
#define DTRANK  64
#define DCONV   4
#define NLAYERS 2
#define ROWS    (BATCH*SEQ)        // 2048 (b,l) rows
#define NCHUNK  32
#define CHUNK   32                 // SEQ / NCHUNK
#define KSPLIT  8
#define KSLICE  (DINNER / KSPLIT)  // 256  (x_proj)
#define KSO     4
#define KSLICE_O (DINNER / KSO)    // 512  (out_proj)

typedef unsigned short ushort_t;
typedef __attribute__((ext_vector_type(8))) short short8;
typedef __attribute__((ext_vector_type(4))) float f32x4;

// fp32 -> bf16 round-to-nearest-even
__device__ __forceinline__ ushort_t f2bf(float f) {
  union { float f; unsigned u; } v; v.f = f;
  unsigned r = v.u + 0x7fffu + ((v.u >> 16) & 1u);
  return (ushort_t)(r >> 16);
}
__device__ __forceinline__ float bf2f(ushort_t h) {
  union { unsigned u; float f; } v; v.u = ((unsigned)h) << 16;
  return v.f;
}

// async global->LDS 16B
__device__ __forceinline__ void g2lds16(const ushort_t* g, ushort_t* l) {
  __builtin_amdgcn_global_load_lds(
      (const __attribute__((address_space(1))) void*)g,
      (__attribute__((address_space(3))) void*)l, 16, 0, 0);
}

// XCD-aware bijective block swizzle (requires gridDim.x*gridDim.y % 8 == 0).
__device__ __forceinline__ void xcd_swz(int& bx, int& by) {
  const int nx = gridDim.x, nwg = nx * gridDim.y;
  int id = by * nx + bx;
  const int q = nwg >> 3;
  id = (id & 7) * q + (id >> 3);
  bx = id % nx; by = id / nx;
}

// LDS quarter-swizzle (store quarter q of row r at q ^ ((r>>1)&3)):
#define STG_Q(tid) (((tid) & 3) ^ (((tid) >> 3) & 3))
#define LDQ(lane)  ((((lane) >> 4) ^ (((lane) >> 1) & 3)) * 8)

// ---------------------------------------------------------------------------
// cast fp32 -> bf16, 4 elems/thread
__global__ __launch_bounds__(256) void cast_bf16_kernel(
    const float* __restrict__ in, ushort_t* __restrict__ out)
{
  const int i = blockIdx.x * 256 + threadIdx.x;
  const float4 v = reinterpret_cast<const float4*>(in)[i];
  ushort4 o;
  o.x = f2bf(v.x); o.y = f2bf(v.y); o.z = f2bf(v.z); o.w = f2bf(v.w);
  reinterpret_cast<ushort4*>(out)[i] = o;
}

// ---------------------------------------------------------------------------
// RMSNorm: one block per row of DMODEL, bf16 output
__global__ __launch_bounds__(256) void rmsnorm_kernel(
    const float* __restrict__ x, const float* __restrict__ w,
    ushort_t* __restrict__ out)
{
  const int row = blockIdx.x;
  const float* xr = x + (size_t)row * DMODEL;
  float ss = 0.f;
  #pragma unroll
  for (int i = threadIdx.x; i < DMODEL; i += 256) { float v = xr[i]; ss += v * v; }
  #pragma unroll
  for (int m = 1; m < 64; m <<= 1) ss += __shfl_xor(ss, m);
  __shared__ float red[4];
  if ((threadIdx.x & 63) == 0) red[threadIdx.x >> 6] = ss;
  __syncthreads();
  float tot = red[0] + red[1] + red[2] + red[3];
  float scale = rsqrtf(tot * (1.f / DMODEL) + 1e-5f);
  #pragma unroll
  for (int i = threadIdx.x; i < DMODEL; i += 256)
    out[(size_t)row * DMODEL + i] = f2bf(xr[i] * scale * w[i]);
}

// ---------------------------------------------------------------------------
// bf16 MFMA GEMM: D[M][N] = A[M][K] * B[N][K]^T, bf16 output to C2.
// BM=BN=128, BK=32, 256 threads = 4 waves (2x2), 64x64 per wave.
// MODE 2: C2 = bf16(acc).  MODE 3: C2 = bf16(softplus(acc + bias[col])).
template<int MODE>
__global__ __launch_bounds__(256) void gemm_bf16_kernel(
    const ushort_t* __restrict__ A, const ushort_t* __restrict__ B,
    ushort_t* __restrict__ C2, const float* __restrict__ bias,
    int K, int lda, int ldb, int ldc)
{
  __shared__ __align__(16) ushort_t As[128 * 32];
  __shared__ __align__(16) ushort_t Bs[128 * 32];
  const int tid = threadIdx.x;
  const int lane = tid & 63, wid = tid >> 6;
  const int wr = wid >> 1, wc = wid & 1;
  int bx = blockIdx.x, by = blockIdx.y;
  xcd_swz(bx, by);
  const int row0 = by * 128, col0 = bx * 128;

  const int sq = STG_Q(tid) * 8;
  const ushort_t* ga0 = A + (size_t)(row0 + (tid >> 2)) * lda + sq;
  const ushort_t* ga1 = A + (size_t)(row0 + 64 + (tid >> 2)) * lda + sq;
  const ushort_t* gb0 = B + (size_t)(col0 + (tid >> 2)) * ldb + sq;
  const ushort_t* gb1 = B + (size_t)(col0 + 64 + (tid >> 2)) * ldb + sq;
  ushort_t* la0 = &As[tid * 8];
  ushort_t* la1 = &As[(256 + tid) * 8];
  ushort_t* lb0 = &Bs[tid * 8];
  ushort_t* lb1 = &Bs[(256 + tid) * 8];

  const int lk = LDQ(lane);
  const int lr16 = lane & 15;

  f32x4 acc[4][4] = {};

  for (int kb = 0; kb < K; kb += 32) {
    g2lds16(ga0 + kb, la0);
    g2lds16(ga1 + kb, la1);
    g2lds16(gb0 + kb, lb0);
    g2lds16(gb1 + kb, lb1);
    __syncthreads();

    short8 af[4], bfr[4];
    #pragma unroll
    for (int i = 0; i < 4; ++i)
      af[i] = *reinterpret_cast<const short8*>(
          &As[(wr * 64 + i * 16 + lr16) * 32 + lk]);
    #pragma unroll
    for (int j = 0; j < 4; ++j)
      bfr[j] = *reinterpret_cast<const short8*>(
          &Bs[(wc * 64 + j * 16 + lr16) * 32 + lk]);
    #pragma unroll
    for (int i = 0; i < 4; ++i)
      #pragma unroll
      for (int j = 0; j < 4; ++j)
        acc[i][j] = __builtin_amdgcn_mfma_f32_16x16x32_bf16(
            af[i], bfr[j], acc[i][j], 0, 0, 0);
    __syncthreads();
  }

  // C/D layout: col = lane&15, row = (lane>>4)*4 + reg
  const int cr = (lane >> 4) * 4;
  #pragma unroll
  for (int i = 0; i < 4; ++i) {
    #pragma unroll
    for (int j = 0; j < 4; ++j) {
      const int col = col0 + wc * 64 + j * 16 + lr16;
      #pragma unroll
      for (int r = 0; r < 4; ++r) {
        const int row = row0 + wr * 64 + i * 16 + cr + r;
        float v = acc[i][j][r];
        if (MODE == 3) {
          v += bias[col];
          v = (v > 20.f) ? v : log1pf(__expf(v));
        }
        C2[(size_t)row * ldc + col] = f2bf(v);
      }
    }
  }
}

// ---------------------------------------------------------------------------
// out_proj split-K: partial[z] = yz16 @ ow16^T over K slice z (bf16 partials).
__global__ __launch_bounds__(256) void outproj_splitk_kernel(
    const ushort_t* __restrict__ A,    // (ROWS, DINNER)
    const ushort_t* __restrict__ B,    // (DMODEL, DINNER)
    ushort_t* __restrict__ partial)    // (KSO, ROWS, DMODEL) bf16
{
  __shared__ __align__(16) ushort_t As[128 * 32];
  __shared__ __align__(16) ushort_t Bs[128 * 32];
  const int tid = threadIdx.x;
  const int lane = tid & 63, wid = tid >> 6;
  const int wr = wid >> 1, wc = wid & 1;
  int bx = blockIdx.x, by = blockIdx.y;
  xcd_swz(bx, by);
  const int row0 = by * 128, col0 = bx * 128;
  const int k0 = blockIdx.z * KSLICE_O;

  const int sq = STG_Q(tid) * 8;
  const ushort_t* ga0 = A + (size_t)(row0 + (tid >> 2)) * DINNER + k0 + sq;
  const ushort_t* ga1 = A + (size_t)(row0 + 64 + (tid >> 2)) * DINNER + k0 + sq;
  const ushort_t* gb0 = B + (size_t)(col0 + (tid >> 2)) * DINNER + k0 + sq;
  const ushort_t* gb1 = B + (size_t)(col0 + 64 + (tid >> 2)) * DINNER + k0 + sq;
  ushort_t* la0 = &As[tid * 8];
  ushort_t* la1 = &As[(256 + tid) * 8];
  ushort_t* lb0 = &Bs[tid * 8];
  ushort_t* lb1 = &Bs[(256 + tid) * 8];

  const int lk = LDQ(lane);
  const int lr16 = lane & 15;

  f32x4 acc[4][4] = {};

  for (int kb = 0; kb < KSLICE_O; kb += 32) {
    g2lds16(ga0 + kb, la0);
    g2lds16(ga1 + kb, la1);
    g2lds16(gb0 + kb, lb0);
    g2lds16(gb1 + kb, lb1);
    __syncthreads();

    short8 af[4], bfr[4];
    #pragma unroll
    for (int i = 0; i < 4; ++i)
      af[i] = *reinterpret_cast<const short8*>(
          &As[(wr * 64 + i * 16 + lr16) * 32 + lk]);
    #pragma unroll
    for (int j = 0; j < 4; ++j)
      bfr[j] = *reinterpret_cast<const short8*>(
          &Bs[(wc * 64 + j * 16 + lr16) * 32 + lk]);
    #pragma unroll
    for (int i = 0; i < 4; ++i)
      #pragma unroll
      for (int j = 0; j < 4; ++j)
        acc[i][j] = __builtin_amdgcn_mfma_f32_16x16x32_bf16(
            af[i], bfr[j], acc[i][j], 0, 0, 0);
    __syncthreads();
  }

  ushort_t* Cz = partial + (size_t)blockIdx.z * ROWS * DMODEL;
  const int cr = (lane >> 4) * 4;
  #pragma unroll
  for (int i = 0; i < 4; ++i) {
    #pragma unroll
    for (int j = 0; j < 4; ++j) {
      const int col = col0 + wc * 64 + j * 16 + lr16;
      #pragma unroll
      for (int r = 0; r < 4; ++r) {
        const int row = row0 + wr * 64 + i * 16 + cr + r;
        Cz[(size_t)row * DMODEL + col] = f2bf(acc[i][j][r]);
      }
    }
  }
}

// out += sum_z partial[z]   (4 elems/thread)
__global__ __launch_bounds__(256) void outproj_reduce_kernel(
    const ushort_t* __restrict__ partial, float* __restrict__ out)
{
  const int i = blockIdx.x * 256 + threadIdx.x;
  float4 s = reinterpret_cast<float4*>(out)[i];
  #pragma unroll
  for (int z = 0; z < KSO; ++z) {
    const ushort4 p = reinterpret_cast<const ushort4*>(
        partial + (size_t)z * ROWS * DMODEL)[i];
    s.x += bf2f(p.x); s.y += bf2f(p.y); s.z += bf2f(p.z); s.w += bf2f(p.w);
  }
  reinterpret_cast<float4*>(out)[i] = s;
}

// ---------------------------------------------------------------------------
// x_proj MFMA split-K: partial[kz] = xc16 @ xpw16^T over K slice kz (bf16).
__global__ __launch_bounds__(256) void xproj_mfma_kernel(
    const ushort_t* __restrict__ A,    // (ROWS, DINNER) bf16 xc
    const ushort_t* __restrict__ B,    // (96, DINNER) bf16 xpw
    ushort_t* __restrict__ partial)    // (KSPLIT, ROWS, 96) bf16
{
  __shared__ __align__(16) ushort_t As[128 * 32];
  __shared__ __align__(16) ushort_t Bs[96 * 32];
  const int tid = threadIdx.x;
  const int lane = tid & 63, wid = tid >> 6;
  int bx = blockIdx.x, by = blockIdx.y;
  xcd_swz(bx, by);
  const int kz = bx, row0 = by * 128;
  const int k0 = kz * KSLICE;

  const int sq = STG_Q(tid) * 8;
  const ushort_t* ga0 = A + (size_t)(row0 + (tid >> 2)) * DINNER + k0 + sq;
  const ushort_t* ga1 = A + (size_t)(row0 + 64 + (tid >> 2)) * DINNER + k0 + sq;
  const ushort_t* gb0 = B + (size_t)(tid >> 2) * DINNER + k0 + sq;
  const ushort_t* gb1 = B + (size_t)(64 + (tid >> 2)) * DINNER + k0 + sq; // tid<128
  ushort_t* la0 = &As[tid * 8];
  ushort_t* la1 = &As[(256 + tid) * 8];
  ushort_t* lb0 = &Bs[tid * 8];
  ushort_t* lb1 = &Bs[(256 + tid) * 8];                                  // tid<128

  const int lk = LDQ(lane);
  const int lr16 = lane & 15;

  f32x4 acc[2][6] = {};

  for (int kb = 0; kb < KSLICE; kb += 32) {
    g2lds16(ga0 + kb, la0);
    g2lds16(ga1 + kb, la1);
    g2lds16(gb0 + kb, lb0);
    if (tid < 128) g2lds16(gb1 + kb, lb1);   // rows 64..95 of B
    __syncthreads();

    short8 af[2], bfr[6];
    #pragma unroll
    for (int i = 0; i < 2; ++i)
      af[i] = *reinterpret_cast<const short8*>(
          &As[(wid * 32 + i * 16 + lr16) * 32 + lk]);
    #pragma unroll
    for (int j = 0; j < 6; ++j)
      bfr[j] = *reinterpret_cast<const short8*>(
          &Bs[(j * 16 + lr16) * 32 + lk]);
    #pragma unroll
    for (int i = 0; i < 2; ++i)
      #pragma unroll
      for (int j = 0; j < 6; ++j)
        acc[i][j] = __builtin_amdgcn_mfma_f32_16x16x32_bf16(
            af[i], bfr[j], acc[i][j], 0, 0, 0);
    __syncthreads();
  }

  const int cr = (lane >> 4) * 4;
  #pragma unroll
  for (int i = 0; i < 2; ++i) {
    #pragma unroll
    for (int j = 0; j < 6; ++j) {
      const int col = j * 16 + lr16;
      #pragma unroll
      for (int r = 0; r < 4; ++r) {
        const int row = row0 + wid * 32 + i * 16 + cr + r;
        partial[((size_t)kz * ROWS + row) * 96 + col] = f2bf(acc[i][j][r]);
      }
    }
  }
}

// ---------------------------------------------------------------------------
// x_proj reduce: sum KSPLIT bf16 partials.  cols 0..63 -> bf16 dl16;
// cols 64..95 -> fp32 dbcBC[row][32] (B,C for scan).
__global__ __launch_bounds__(256) void xproj_reduce_kernel(
    const ushort_t* __restrict__ partial, float* __restrict__ dbcBC,
    ushort_t* __restrict__ dl16)
{
  const int idx = blockIdx.x * 256 + threadIdx.x;   // < ROWS*96
  const int row = idx / 96, j = idx % 96;
  float s = 0.f;
  #pragma unroll
  for (int z = 0; z < KSPLIT; ++z)
    s += bf2f(partial[(size_t)z * ROWS * 96 + idx]);
  if (j < DTRANK) dl16[row * DTRANK + j] = f2bf(s);
  else            dbcBC[row * 32 + (j - DTRANK)] = s;
}

// ---------------------------------------------------------------------------
// Depthwise causal conv (k=4) + bias + SiLU over bf16 xz; 8 channels/thread.
__global__ __launch_bounds__(256) void conv_silu_kernel(
    const ushort_t* __restrict__ xz16,  // (ROWS, 2*DINNER) conv input = cols<DINNER
    const float* __restrict__ cw, const float* __restrict__ cb,
    ushort_t* __restrict__ xc16)        // (ROWS, DINNER)
{
  const int idx = blockIdx.x * 256 + threadIdx.x;  // over ROWS*DINNER/8
  const int e0 = (idx * 8) % DINNER;
  const int bl = (idx * 8) / DINNER;
  const int l  = bl % SEQ;
  float acc[8];
  #pragma unroll
  for (int j = 0; j < 8; ++j) acc[j] = cb[e0 + j];
  float4 w4[8];
  #pragma unroll
  for (int j = 0; j < 8; ++j)
    w4[j] = *reinterpret_cast<const float4*>(&cw[(e0 + j) * DCONV]);
  #pragma unroll
  for (int k = 0; k < DCONV; ++k) {
    const int lk = l + k - (DCONV - 1);
    if (lk >= 0) {
      const short8 v = *reinterpret_cast<const short8*>(
          &xz16[(size_t)(bl + k - (DCONV - 1)) * (2 * DINNER) + e0]);
      #pragma unroll
      for (int j = 0; j < 8; ++j) {
        const float wv = (k == 0) ? w4[j].x : (k == 1) ? w4[j].y
                        : (k == 2) ? w4[j].z : w4[j].w;
        acc[j] += bf2f((ushort_t)v[j]) * wv;
      }
    }
  }
  short8 o;
  #pragma unroll
  for (int j = 0; j < 8; ++j) {
    const float v = acc[j] / (1.f + __expf(-acc[j]));
    o[j] = (short)f2bf(v);
  }
  *reinterpret_cast<short8*>(&xc16[(size_t)bl * DINNER + e0]) = o;
}

// ---------------------------------------------------------------------------
// Pass A: lane-per-(b,c,e), 16 states in registers; bf16 delta/xc inputs.
__global__ __launch_bounds__(256) void scan_chunk_kernel(
    const ushort_t* __restrict__ d16,  // (ROWS, DINNER) softplus'd delta, bf16
    const ushort_t* __restrict__ xc16, // (ROWS, DINNER) bf16
    const float* __restrict__ dbcBC,   // (ROWS, 32): [0..16)=B
    const float* __restrict__ A_log,   // (DINNER, 16)
    float* __restrict__ Pbuf,          // (BATCH, NCHUNK, DINNER, 16) fp32
    float* __restrict__ Hbuf)          // (BATCH, NCHUNK, DINNER, 16) fp32
{
  __shared__ float sB[CHUNK][16];
  const int bc = blockIdx.y;               // b*NCHUNK + c
  const int b = bc / NCHUNK, c = bc % NCHUNK;
  const int e = blockIdx.x * 256 + threadIdx.x;
  const size_t row32 = ((size_t)b * SEQ + c * CHUNK) * 32;
  #pragma unroll
  for (int p = 0; p < (CHUNK * 16) / 256; ++p) {
    const int idx = threadIdx.x + p * 256;
    sB[idx >> 4][idx & 15] = dbcBC[row32 + (idx >> 4) * 32 + (idx & 15)];
  }
  float Aen[16];
  #pragma unroll
  for (int q = 0; q < 4; ++q) {
    const float4 a4 = *reinterpret_cast<const float4*>(&A_log[(size_t)e * 16 + q * 4]);
    Aen[q * 4 + 0] = -__expf(a4.x);
    Aen[q * 4 + 1] = -__expf(a4.y);
    Aen[q * 4 + 2] = -__expf(a4.z);
    Aen[q * 4 + 3] = -__expf(a4.w);
  }
  __syncthreads();

  float h[16];
  #pragma unroll
  for (int n = 0; n < 16; ++n) h[n] = 0.f;
  float sd = 0.f;
  const size_t rowE = ((size_t)b * SEQ + c * CHUNK) * DINNER + e;
  float dv = bf2f(d16[rowE]), xv = bf2f(xc16[rowE]);
  for (int t = 0; t < CHUNK; ++t) {
    float dvn = 0.f, xvn = 0.f;
    if (t + 1 < CHUNK) {
      dvn = bf2f(d16[rowE + (size_t)(t + 1) * DINNER]);
      xvn = bf2f(xc16[rowE + (size_t)(t + 1) * DINNER]);
    }
    const float dxv = dv * xv;
    sd += dv;
    #pragma unroll
    for (int n = 0; n < 16; ++n) {
      const float dA = __expf(dv * Aen[n]);
      h[n] = dA * h[n] + dxv * sB[t][n];
    }
    dv = dvn; xv = xvn;
  }
  const size_t o = ((size_t)bc * DINNER + e) * 16;
  #pragma unroll
  for (int q = 0; q < 4; ++q) {
    float4 pv, hv;
    pv.x = __expf(Aen[q * 4 + 0] * sd);
    pv.y = __expf(Aen[q * 4 + 1] * sd);
    pv.z = __expf(Aen[q * 4 + 2] * sd);
    pv.w = __expf(Aen[q * 4 + 3] * sd);
    hv.x = h[q * 4 + 0]; hv.y = h[q * 4 + 1];
    hv.z = h[q * 4 + 2]; hv.w = h[q * 4 + 3];
    *reinterpret_cast<float4*>(&Pbuf[o + q * 4]) = pv;
    *reinterpret_cast<float4*>(&Hbuf[o + q * 4]) = hv;
  }
}

// ---------------------------------------------------------------------------
// Pass B: serial combine over NCHUNK summaries; one thread per (b,e,n).
__global__ __launch_bounds__(256) void scan_combine_kernel(
    const float* __restrict__ Pbuf, float* __restrict__ Hbuf)
{
  const int idx = blockIdx.x * 256 + threadIdx.x;   // b*(DINNER*16) + e*16 + n
  const int b = idx >> 15;
  const int en = idx & (DINNER * 16 - 1);
  const size_t base = (size_t)b * NCHUNK * DINNER * 16 + en;
  float H = 0.f;
  float P = Pbuf[base], hf = Hbuf[base];
  for (int c = 0; c < NCHUNK; ++c) {
    const size_t o = base + (size_t)c * DINNER * 16;
    float Pn = 0.f, hfn = 0.f;
    if (c + 1 < NCHUNK) {
      const size_t on = o + (size_t)DINNER * 16;
      Pn = Pbuf[on]; hfn = Hbuf[on];
    }
    Hbuf[o] = H;
    H = P * H + hf;
    P = Pn; hf = hfn;
  }
}

// ---------------------------------------------------------------------------
// Pass C: seeded re-scan fused with C-dot, D skip, z gate -> bf16 yz.
__global__ __launch_bounds__(256) void scan_out_kernel(
    const ushort_t* __restrict__ d16,  // (ROWS, DINNER) bf16
    const ushort_t* __restrict__ xc16, // (ROWS, DINNER) bf16
    const float* __restrict__ dbcBC,   // (ROWS, 32)
    const ushort_t* __restrict__ xz16, // (ROWS, 2*DINNER): z at col DINNER+e
    const float* __restrict__ A_log,   // (DINNER, 16)
    const float* __restrict__ Dp,      // (DINNER)
    const float* __restrict__ Hbuf,    // [b][c][e][n] seeds (fp32)
    ushort_t* __restrict__ yz16)       // (ROWS, DINNER) bf16 out
{
  __shared__ float sB[CHUNK][16];
  __shared__ float sC[CHUNK][16];
  const int bc = blockIdx.y;
  const int b = bc / NCHUNK, c = bc % NCHUNK;
  const int e = blockIdx.x * 256 + threadIdx.x;
  const size_t row32 = ((size_t)b * SEQ + c * CHUNK) * 32;
  #pragma unroll
  for (int p = 0; p < (CHUNK * 32) / 256; ++p) {
    const int idx = threadIdx.x + p * 256;
    const int t = idx >> 5, j = idx & 31;
    const float v = dbcBC[row32 + t * 32 + j];
    if (j < 16) sB[t][j] = v; else sC[t][j - 16] = v;
  }
  float Aen[16];
  #pragma unroll
  for (int q = 0; q < 4; ++q) {
    const float4 a4 = *reinterpret_cast<const float4*>(&A_log[(size_t)e * 16 + q * 4]);
    Aen[q * 4 + 0] = -__expf(a4.x);
    Aen[q * 4 + 1] = -__expf(a4.y);
    Aen[q * 4 + 2] = -__expf(a4.z);
    Aen[q * 4 + 3] = -__expf(a4.w);
  }
  float h[16];
  const size_t oh = ((size_t)bc * DINNER + e) * 16;
  #pragma unroll
  for (int q = 0; q < 4; ++q) {
    const float4 hv = *reinterpret_cast<const float4*>(&Hbuf[oh + q * 4]);
    h[q * 4 + 0] = hv.x; h[q * 4 + 1] = hv.y;
    h[q * 4 + 2] = hv.z; h[q * 4 + 3] = hv.w;
  }
  const float dpe = Dp[e];
  __syncthreads();

  const size_t rowE = ((size_t)b * SEQ + c * CHUNK) * DINNER + e;
  const size_t rowZ = ((size_t)b * SEQ + c * CHUNK) * (2 * DINNER) + DINNER + e;
  float dv = bf2f(d16[rowE]), xv = bf2f(xc16[rowE]);
  float zv = bf2f(xz16[rowZ]);
  for (int t = 0; t < CHUNK; ++t) {
    float dvn = 0.f, xvn = 0.f, zvn = 0.f;
    if (t + 1 < CHUNK) {
      dvn = bf2f(d16[rowE + (size_t)(t + 1) * DINNER]);
      xvn = bf2f(xc16[rowE + (size_t)(t + 1) * DINNER]);
      zvn = bf2f(xz16[rowZ + (size_t)(t + 1) * (2 * DINNER)]);
    }
    const float dxv = dv * xv;
    float y = dpe * xv;
    #pragma unroll
    for (int n = 0; n < 16; ++n) {
      const float dA = __expf(dv * Aen[n]);
      h[n] = dA * h[n] + dxv * sB[t][n];
      y += h[n] * sC[t][n];
    }
    const float sz = zv / (1.f + __expf(-zv));
    yz16[rowE + (size_t)t * DINNER] = f2bf(y * sz);
    dv = dvn; xv = xvn; zv = zvn;
  }
}

// ---------------------------------------------------------------------------
extern "C" void kernel_launch(void* const* d_in, const int* in_sizes, int n_in,
                              void* d_out, int out_size, void* d_ws, size_t ws_size,
                              hipStream_t stream)
{
  const float* x         = (const float*)d_in[0];
  const float* norm_w    = (const float*)d_in[1];
  const float* in_proj_w = (const float*)d_in[2];
  const float* conv_w    = (const float*)d_in[3];
  const float* conv_b    = (const float*)d_in[4];
  const float* x_proj_w  = (const float*)d_in[5];
  const float* dt_proj_w = (const float*)d_in[6];
  const float* dt_proj_b = (const float*)d_in[7];
  const float* A_log     = (const float*)d_in[8];
  const float* D_param   = (const float*)d_in[9];
  const float* out_proj_w= (const float*)d_in[10];
  float* out = (float*)d_out;

  // Workspace (float offsets), total <= 18.04M floats < 18.1875M (proven cap).
  // Mostly disjoint regions; only two time-shared aliases:
  //  * region0 [0,5M): {h16[0,1M) + w16i[1,5M)} live rms..gemm1  ||
  //                    {partO[0,4M) + w16o[4,5M)} live cast..reduceO (step 12+)
  //  * yz16 [13,15M) aliases P_buf: P dead after scanB, yz written in scanC.
  const size_t M = 1024 * 1024;
  float* ws = (float*)d_ws;
  ushort_t* h16   = (ushort_t*)ws;                   // [0,1M)
  ushort_t* w16i  = (ushort_t*)(ws + 1 * M);         // [1,5M)
  ushort_t* partO = (ushort_t*)ws;                   // [0,4M)   late
  ushort_t* w16o  = (ushort_t*)(ws + 4 * M);         // [4,5M)   late
  ushort_t* xz16  = (ushort_t*)(ws + 5 * M);         // [5,9M)   gemm1..scanC
  ushort_t* xc16  = (ushort_t*)(ws + 9 * M);         // [9,11M)  conv..scanC
  ushort_t* d16   = (ushort_t*)(ws + 11 * M);        // [11,13M) dtproj..scanC
  float* P_buf    = ws + 13 * M;                     // [13,15M) scanA..scanB
  ushort_t* yz16  = (ushort_t*)P_buf;                // [13,15M) scanC..reduceO
  float* H_buf    = ws + 15 * M;                     // [15,17M) scanA..scanC
  ushort_t* partX = (ushort_t*)(ws + 17 * M);        // 0.75M floats
  ushort_t* xpw16 = (ushort_t*)(ws + 17 * M + 786432);          // 96K floats
  ushort_t* dtw16 = (ushort_t*)(ws + 17 * M + 786432 + 98304);  // 64K floats
  float* dbcBC    = ws + 17 * M + 786432 + 98304 + 65536;       // 64K floats
  ushort_t* dl16  = (ushort_t*)(dbcBC + 65536);                 // 64K floats

  hipMemcpyAsync(out, x, (size_t)ROWS * DMODEL * sizeof(float),
                 hipMemcpyDeviceToDevice, stream);

  for (int layer = 0; layer < NLAYERS; ++layer) {
    const float* nw  = norm_w     + (size_t)layer * DMODEL;
    const float* iw  = in_proj_w  + (size_t)layer * 2 * DINNER * DMODEL;
    const float* cw  = conv_w     + (size_t)layer * DINNER * DCONV;
    const float* cb  = conv_b     + (size_t)layer * DINNER;
    const float* xpw = x_proj_w   + (size_t)layer * 96 * DINNER;
    const float* dtw = dt_proj_w  + (size_t)layer * DINNER * DTRANK;
    const float* dtb = dt_proj_b  + (size_t)layer * DINNER;
    const float* Al  = A_log      + (size_t)layer * DINNER * DSTATE;
    const float* Dpp = D_param    + (size_t)layer * DINNER;
    const float* ow  = out_proj_w + (size_t)layer * DMODEL * DINNER;

    // 1. h = rmsnorm(residual) -> bf16
    rmsnorm_kernel<<<ROWS, 256, 0, stream>>>(out, nw, h16);

    // 2. cast in_proj weights to bf16
    cast_bf16_kernel<<<(2 * DINNER * DMODEL) / 1024, 256, 0, stream>>>(iw, w16i);

    // 3. xz = h @ in_w^T (bf16 MFMA) -> bf16 xz16 (both halves)
    gemm_bf16_kernel<2>
        <<<dim3(2 * DINNER / 128, ROWS / 128), 256, 0, stream>>>(
            h16, w16i, xz16, nullptr, DMODEL, DMODEL, DMODEL, 2 * DINNER);

    // 4. xc16 = bf16(silu(causal_conv(xz16[:, :DINNER]) + cb))
    conv_silu_kernel<<<(size_t)ROWS * DINNER / 8 / 256, 256, 0, stream>>>(
        xz16, cw, cb, xc16);

    // 5. cast x_proj / dt_proj weights
    cast_bf16_kernel<<<(96 * DINNER) / 1024, 256, 0, stream>>>(xpw, xpw16);
    cast_bf16_kernel<<<(DINNER * DTRANK) / 1024, 256, 0, stream>>>(dtw, dtw16);

    // 6+7. dbc = xc @ xpw^T  (bf16 MFMA split-K + reduce)
    xproj_mfma_kernel<<<dim3(KSPLIT, ROWS / 128), 256, 0, stream>>>(
        xc16, xpw16, partX);
    xproj_reduce_kernel<<<ROWS * 96 / 256, 256, 0, stream>>>(
        partX, dbcBC, dl16);

    // 8. delta = softplus(dl16 @ dtw^T + dtb) -> bf16 d16
    gemm_bf16_kernel<3>
        <<<dim3(DINNER / 128, ROWS / 128), 256, 0, stream>>>(
            dl16, dtw16, d16, dtb, DTRANK, DTRANK, DTRANK, DINNER);

    // 9-11. chunked selective scan + D skip + z gate -> yz16
    scan_chunk_kernel<<<dim3(DINNER / 256, BATCH * NCHUNK), 256, 0, stream>>>(
        d16, xc16, dbcBC, Al, P_buf, H_buf);
    scan_combine_kernel<<<BATCH * DINNER * 16 / 256, 256, 0, stream>>>(
        P_buf, H_buf);
    scan_out_kernel<<<dim3(DINNER / 256, BATCH * NCHUNK), 256, 0, stream>>>(
        d16, xc16, dbcBC, xz16, Al, Dpp, H_buf, yz16);

    // 12. cast out_proj weights to bf16
    cast_bf16_kernel<<<(DMODEL * DINNER) / 1024, 256, 0, stream>>>(ow, w16o);

    // 13a. out_proj split-K (bf16 partials)
    outproj_splitk_kernel
        <<<dim3(DMODEL / 128, ROWS / 128, KSO), 256, 0, stream>>>(
            yz16, w16o, partO);
    // 13b. residual += sum_z partO[z]
    outproj_reduce_kernel<<<ROWS * DMODEL / 1024, 256, 0, stream>>>(
        partO, out);
  }
}

// Round 12
// 315.200 us; speedup vs baseline: 8.0645x; 1.0929x over previous
//
#include <hip/hip_runtime.h>
#include <hip/hip_bf16.h>

// Problem constants
#define BATCH   2
#define SEQ     1024
#define DMODEL  1024
#define DINNER  2048
#define DSTATE  16
#define DTRANK  64
#define DCONV   4
#define NLAYERS 2
#define ROWS    (BATCH*SEQ)        // 2048 (b,l) rows
#define NCHUNK  32
#define CHUNK   32                 // SEQ / NCHUNK
#define KSPLIT  8
#define KSLICE  (DINNER / KSPLIT)  // 256  (x_proj)
#define KSO     4
#define KSLICE_O (DINNER / KSO)    // 512  (out_proj)

typedef unsigned short ushort_t;
typedef __attribute__((ext_vector_type(8))) short short8;
typedef __attribute__((ext_vector_type(4))) float f32x4;

// fp32 -> bf16 round-to-nearest-even
__device__ __forceinline__ ushort_t f2bf(float f) {
  union { float f; unsigned u; } v; v.f = f;
  unsigned r = v.u + 0x7fffu + ((v.u >> 16) & 1u);
  return (ushort_t)(r >> 16);
}
__device__ __forceinline__ float bf2f(ushort_t h) {
  union { unsigned u; float f; } v; v.u = ((unsigned)h) << 16;
  return v.f;
}

// async global->LDS 16B
__device__ __forceinline__ void g2lds16(const ushort_t* g, ushort_t* l) {
  __builtin_amdgcn_global_load_lds(
      (const __attribute__((address_space(1))) void*)g,
      (__attribute__((address_space(3))) void*)l, 16, 0, 0);
}

// XCD-aware bijective block swizzle (requires gridDim.x*gridDim.y % 8 == 0).
__device__ __forceinline__ void xcd_swz(int& bx, int& by) {
  const int nx = gridDim.x, nwg = nx * gridDim.y;
  int id = by * nx + bx;
  const int q = nwg >> 3;
  id = (id & 7) * q + (id >> 3);
  bx = id % nx; by = id / nx;
}

// LDS quarter-swizzle (store quarter q of row r at q ^ ((r>>1)&3)):
#define STG_Q(tid) (((tid) & 3) ^ (((tid) >> 3) & 3))
#define LDQ(lane)  ((((lane) >> 4) ^ (((lane) >> 1) & 3)) * 8)

// ---------------------------------------------------------------------------
// cast fp32 -> bf16, 4 elems/thread
__global__ __launch_bounds__(256) void cast_bf16_kernel(
    const float* __restrict__ in, ushort_t* __restrict__ out)
{
  const int i = blockIdx.x * 256 + threadIdx.x;
  const float4 v = reinterpret_cast<const float4*>(in)[i];
  ushort4 o;
  o.x = f2bf(v.x); o.y = f2bf(v.y); o.z = f2bf(v.z); o.w = f2bf(v.w);
  reinterpret_cast<ushort4*>(out)[i] = o;
}

// ---------------------------------------------------------------------------
// init: out = x; h16 = bf16(rms(x) * w).  One block per row, 4 elems/thread.
__global__ __launch_bounds__(256) void init_rms_kernel(
    const float* __restrict__ x, const float* __restrict__ w,
    float* __restrict__ out, ushort_t* __restrict__ h16)
{
  const int row = blockIdx.x, t = threadIdx.x;
  const size_t base = (size_t)row * DMODEL + 4 * t;
  const float4 s = *reinterpret_cast<const float4*>(&x[base]);
  *reinterpret_cast<float4*>(&out[base]) = s;
  float ss = s.x * s.x + s.y * s.y + s.z * s.z + s.w * s.w;
  #pragma unroll
  for (int m = 1; m < 64; m <<= 1) ss += __shfl_xor(ss, m);
  __shared__ float red[4];
  if ((t & 63) == 0) red[t >> 6] = ss;
  __syncthreads();
  const float tot = red[0] + red[1] + red[2] + red[3];
  const float scale = rsqrtf(tot * (1.f / DMODEL) + 1e-5f);
  const float4 w4 = *reinterpret_cast<const float4*>(&w[4 * t]);
  ushort4 o;
  o.x = f2bf(s.x * scale * w4.x); o.y = f2bf(s.y * scale * w4.y);
  o.z = f2bf(s.z * scale * w4.z); o.w = f2bf(s.w * scale * w4.w);
  *reinterpret_cast<ushort4*>(&h16[base]) = o;
}

// ---------------------------------------------------------------------------
// bf16 MFMA GEMM: D[M][N] = A[M][K] * B[N][K]^T, bf16 output to C2.
// BM=BN=128, BK=32, 256 threads = 4 waves (2x2), 64x64 per wave.
// MODE 2: C2 = bf16(acc).  MODE 3: C2 = bf16(softplus(acc + bias[col])).
template<int MODE>
__global__ __launch_bounds__(256) void gemm_bf16_kernel(
    const ushort_t* __restrict__ A, const ushort_t* __restrict__ B,
    ushort_t* __restrict__ C2, const float* __restrict__ bias,
    int K, int lda, int ldb, int ldc)
{
  __shared__ __align__(16) ushort_t As[128 * 32];
  __shared__ __align__(16) ushort_t Bs[128 * 32];
  const int tid = threadIdx.x;
  const int lane = tid & 63, wid = tid >> 6;
  const int wr = wid >> 1, wc = wid & 1;
  int bx = blockIdx.x, by = blockIdx.y;
  xcd_swz(bx, by);
  const int row0 = by * 128, col0 = bx * 128;

  const int sq = STG_Q(tid) * 8;
  const ushort_t* ga0 = A + (size_t)(row0 + (tid >> 2)) * lda + sq;
  const ushort_t* ga1 = A + (size_t)(row0 + 64 + (tid >> 2)) * lda + sq;
  const ushort_t* gb0 = B + (size_t)(col0 + (tid >> 2)) * ldb + sq;
  const ushort_t* gb1 = B + (size_t)(col0 + 64 + (tid >> 2)) * ldb + sq;
  ushort_t* la0 = &As[tid * 8];
  ushort_t* la1 = &As[(256 + tid) * 8];
  ushort_t* lb0 = &Bs[tid * 8];
  ushort_t* lb1 = &Bs[(256 + tid) * 8];

  const int lk = LDQ(lane);
  const int lr16 = lane & 15;

  f32x4 acc[4][4] = {};

  for (int kb = 0; kb < K; kb += 32) {
    g2lds16(ga0 + kb, la0);
    g2lds16(ga1 + kb, la1);
    g2lds16(gb0 + kb, lb0);
    g2lds16(gb1 + kb, lb1);
    __syncthreads();

    short8 af[4], bfr[4];
    #pragma unroll
    for (int i = 0; i < 4; ++i)
      af[i] = *reinterpret_cast<const short8*>(
          &As[(wr * 64 + i * 16 + lr16) * 32 + lk]);
    #pragma unroll
    for (int j = 0; j < 4; ++j)
      bfr[j] = *reinterpret_cast<const short8*>(
          &Bs[(wc * 64 + j * 16 + lr16) * 32 + lk]);
    #pragma unroll
    for (int i = 0; i < 4; ++i)
      #pragma unroll
      for (int j = 0; j < 4; ++j)
        acc[i][j] = __builtin_amdgcn_mfma_f32_16x16x32_bf16(
            af[i], bfr[j], acc[i][j], 0, 0, 0);
    __syncthreads();
  }

  // C/D layout: col = lane&15, row = (lane>>4)*4 + reg
  const int cr = (lane >> 4) * 4;
  #pragma unroll
  for (int i = 0; i < 4; ++i) {
    #pragma unroll
    for (int j = 0; j < 4; ++j) {
      const int col = col0 + wc * 64 + j * 16 + lr16;
      #pragma unroll
      for (int r = 0; r < 4; ++r) {
        const int row = row0 + wr * 64 + i * 16 + cr + r;
        float v = acc[i][j][r];
        if (MODE == 3) {
          v += bias[col];
          v = (v > 20.f) ? v : log1pf(__expf(v));
        }
        C2[(size_t)row * ldc + col] = f2bf(v);
      }
    }
  }
}

// ---------------------------------------------------------------------------
// out_proj split-K: partial[z] = yz16 @ ow16^T over K slice z (bf16 partials).
__global__ __launch_bounds__(256) void outproj_splitk_kernel(
    const ushort_t* __restrict__ A,    // (ROWS, DINNER)
    const ushort_t* __restrict__ B,    // (DMODEL, DINNER)
    ushort_t* __restrict__ partial)    // (KSO, ROWS, DMODEL) bf16
{
  __shared__ __align__(16) ushort_t As[128 * 32];
  __shared__ __align__(16) ushort_t Bs[128 * 32];
  const int tid = threadIdx.x;
  const int lane = tid & 63, wid = tid >> 6;
  const int wr = wid >> 1, wc = wid & 1;
  int bx = blockIdx.x, by = blockIdx.y;
  xcd_swz(bx, by);
  const int row0 = by * 128, col0 = bx * 128;
  const int k0 = blockIdx.z * KSLICE_O;

  const int sq = STG_Q(tid) * 8;
  const ushort_t* ga0 = A + (size_t)(row0 + (tid >> 2)) * DINNER + k0 + sq;
  const ushort_t* ga1 = A + (size_t)(row0 + 64 + (tid >> 2)) * DINNER + k0 + sq;
  const ushort_t* gb0 = B + (size_t)(col0 + (tid >> 2)) * DINNER + k0 + sq;
  const ushort_t* gb1 = B + (size_t)(col0 + 64 + (tid >> 2)) * DINNER + k0 + sq;
  ushort_t* la0 = &As[tid * 8];
  ushort_t* la1 = &As[(256 + tid) * 8];
  ushort_t* lb0 = &Bs[tid * 8];
  ushort_t* lb1 = &Bs[(256 + tid) * 8];

  const int lk = LDQ(lane);
  const int lr16 = lane & 15;

  f32x4 acc[4][4] = {};

  for (int kb = 0; kb < KSLICE_O; kb += 32) {
    g2lds16(ga0 + kb, la0);
    g2lds16(ga1 + kb, la1);
    g2lds16(gb0 + kb, lb0);
    g2lds16(gb1 + kb, lb1);
    __syncthreads();

    short8 af[4], bfr[4];
    #pragma unroll
    for (int i = 0; i < 4; ++i)
      af[i] = *reinterpret_cast<const short8*>(
          &As[(wr * 64 + i * 16 + lr16) * 32 + lk]);
    #pragma unroll
    for (int j = 0; j < 4; ++j)
      bfr[j] = *reinterpret_cast<const short8*>(
          &Bs[(wc * 64 + j * 16 + lr16) * 32 + lk]);
    #pragma unroll
    for (int i = 0; i < 4; ++i)
      #pragma unroll
      for (int j = 0; j < 4; ++j)
        acc[i][j] = __builtin_amdgcn_mfma_f32_16x16x32_bf16(
            af[i], bfr[j], acc[i][j], 0, 0, 0);
    __syncthreads();
  }

  ushort_t* Cz = partial + (size_t)blockIdx.z * ROWS * DMODEL;
  const int cr = (lane >> 4) * 4;
  #pragma unroll
  for (int i = 0; i < 4; ++i) {
    #pragma unroll
    for (int j = 0; j < 4; ++j) {
      const int col = col0 + wc * 64 + j * 16 + lr16;
      #pragma unroll
      for (int r = 0; r < 4; ++r) {
        const int row = row0 + wr * 64 + i * 16 + cr + r;
        Cz[(size_t)row * DMODEL + col] = f2bf(acc[i][j][r]);
      }
    }
  }
}

// ---------------------------------------------------------------------------
// out += sum_z partial[z]; if RMS, also emit h16 = bf16(rms(out_row) * nw).
// One block per row (256 threads x 4 elems = DMODEL).
template<bool RMS>
__global__ __launch_bounds__(256) void outproj_reduce_rms_kernel(
    const ushort_t* __restrict__ partial, const float* __restrict__ nw,
    float* __restrict__ out, ushort_t* __restrict__ h16)
{
  const int row = blockIdx.x, t = threadIdx.x;
  const size_t base = (size_t)row * DMODEL + 4 * t;
  float4 s = *reinterpret_cast<float4*>(&out[base]);
  #pragma unroll
  for (int z = 0; z < KSO; ++z) {
    const ushort4 p = *reinterpret_cast<const ushort4*>(
        &partial[(size_t)z * ROWS * DMODEL + base]);
    s.x += bf2f(p.x); s.y += bf2f(p.y); s.z += bf2f(p.z); s.w += bf2f(p.w);
  }
  *reinterpret_cast<float4*>(&out[base]) = s;
  if (RMS) {
    float ss = s.x * s.x + s.y * s.y + s.z * s.z + s.w * s.w;
    #pragma unroll
    for (int m = 1; m < 64; m <<= 1) ss += __shfl_xor(ss, m);
    __shared__ float red[4];
    if ((t & 63) == 0) red[t >> 6] = ss;
    __syncthreads();
    const float tot = red[0] + red[1] + red[2] + red[3];
    const float scale = rsqrtf(tot * (1.f / DMODEL) + 1e-5f);
    const float4 w4 = *reinterpret_cast<const float4*>(&nw[4 * t]);
    ushort4 o;
    o.x = f2bf(s.x * scale * w4.x); o.y = f2bf(s.y * scale * w4.y);
    o.z = f2bf(s.z * scale * w4.z); o.w = f2bf(s.w * scale * w4.w);
    *reinterpret_cast<ushort4*>(&h16[base]) = o;
  }
}

// ---------------------------------------------------------------------------
// x_proj MFMA split-K: partial[kz] = xc16 @ xpw16^T over K slice kz (bf16).
__global__ __launch_bounds__(256) void xproj_mfma_kernel(
    const ushort_t* __restrict__ A,    // (ROWS, DINNER) bf16 xc
    const ushort_t* __restrict__ B,    // (96, DINNER) bf16 xpw
    ushort_t* __restrict__ partial)    // (KSPLIT, ROWS, 96) bf16
{
  __shared__ __align__(16) ushort_t As[128 * 32];
  __shared__ __align__(16) ushort_t Bs[96 * 32];
  const int tid = threadIdx.x;
  const int lane = tid & 63, wid = tid >> 6;
  int bx = blockIdx.x, by = blockIdx.y;
  xcd_swz(bx, by);
  const int kz = bx, row0 = by * 128;
  const int k0 = kz * KSLICE;

  const int sq = STG_Q(tid) * 8;
  const ushort_t* ga0 = A + (size_t)(row0 + (tid >> 2)) * DINNER + k0 + sq;
  const ushort_t* ga1 = A + (size_t)(row0 + 64 + (tid >> 2)) * DINNER + k0 + sq;
  const ushort_t* gb0 = B + (size_t)(tid >> 2) * DINNER + k0 + sq;
  const ushort_t* gb1 = B + (size_t)(64 + (tid >> 2)) * DINNER + k0 + sq; // tid<128
  ushort_t* la0 = &As[tid * 8];
  ushort_t* la1 = &As[(256 + tid) * 8];
  ushort_t* lb0 = &Bs[tid * 8];
  ushort_t* lb1 = &Bs[(256 + tid) * 8];                                  // tid<128

  const int lk = LDQ(lane);
  const int lr16 = lane & 15;

  f32x4 acc[2][6] = {};

  for (int kb = 0; kb < KSLICE; kb += 32) {
    g2lds16(ga0 + kb, la0);
    g2lds16(ga1 + kb, la1);
    g2lds16(gb0 + kb, lb0);
    if (tid < 128) g2lds16(gb1 + kb, lb1);   // rows 64..95 of B
    __syncthreads();

    short8 af[2], bfr[6];
    #pragma unroll
    for (int i = 0; i < 2; ++i)
      af[i] = *reinterpret_cast<const short8*>(
          &As[(wid * 32 + i * 16 + lr16) * 32 + lk]);
    #pragma unroll
    for (int j = 0; j < 6; ++j)
      bfr[j] = *reinterpret_cast<const short8*>(
          &Bs[(j * 16 + lr16) * 32 + lk]);
    #pragma unroll
    for (int i = 0; i < 2; ++i)
      #pragma unroll
      for (int j = 0; j < 6; ++j)
        acc[i][j] = __builtin_amdgcn_mfma_f32_16x16x32_bf16(
            af[i], bfr[j], acc[i][j], 0, 0, 0);
    __syncthreads();
  }

  const int cr = (lane >> 4) * 4;
  #pragma unroll
  for (int i = 0; i < 2; ++i) {
    #pragma unroll
    for (int j = 0; j < 6; ++j) {
      const int col = j * 16 + lr16;
      #pragma unroll
      for (int r = 0; r < 4; ++r) {
        const int row = row0 + wid * 32 + i * 16 + cr + r;
        partial[((size_t)kz * ROWS + row) * 96 + col] = f2bf(acc[i][j][r]);
      }
    }
  }
}

// ---------------------------------------------------------------------------
// x_proj reduce: sum KSPLIT bf16 partials.  cols 0..63 -> bf16 dl16;
// cols 64..95 -> fp32 dbcBC[row][32] (B,C for scan).
__global__ __launch_bounds__(256) void xproj_reduce_kernel(
    const ushort_t* __restrict__ partial, float* __restrict__ dbcBC,
    ushort_t* __restrict__ dl16)
{
  const int idx = blockIdx.x * 256 + threadIdx.x;   // < ROWS*96
  const int row = idx / 96, j = idx % 96;
  float s = 0.f;
  #pragma unroll
  for (int z = 0; z < KSPLIT; ++z)
    s += bf2f(partial[(size_t)z * ROWS * 96 + idx]);
  if (j < DTRANK) dl16[row * DTRANK + j] = f2bf(s);
  else            dbcBC[row * 32 + (j - DTRANK)] = s;
}

// ---------------------------------------------------------------------------
// Depthwise causal conv (k=4) + bias + SiLU over bf16 xz; 8 channels/thread.
__global__ __launch_bounds__(256) void conv_silu_kernel(
    const ushort_t* __restrict__ xz16,  // (ROWS, 2*DINNER) conv input = cols<DINNER
    const float* __restrict__ cw, const float* __restrict__ cb,
    ushort_t* __restrict__ xc16)        // (ROWS, DINNER)
{
  const int idx = blockIdx.x * 256 + threadIdx.x;  // over ROWS*DINNER/8
  const int e0 = (idx * 8) % DINNER;
  const int bl = (idx * 8) / DINNER;
  const int l  = bl % SEQ;
  float acc[8];
  #pragma unroll
  for (int j = 0; j < 8; ++j) acc[j] = cb[e0 + j];
  float4 w4[8];
  #pragma unroll
  for (int j = 0; j < 8; ++j)
    w4[j] = *reinterpret_cast<const float4*>(&cw[(e0 + j) * DCONV]);
  #pragma unroll
  for (int k = 0; k < DCONV; ++k) {
    const int lk = l + k - (DCONV - 1);
    if (lk >= 0) {
      const short8 v = *reinterpret_cast<const short8*>(
          &xz16[(size_t)(bl + k - (DCONV - 1)) * (2 * DINNER) + e0]);
      #pragma unroll
      for (int j = 0; j < 8; ++j) {
        const float wv = (k == 0) ? w4[j].x : (k == 1) ? w4[j].y
                        : (k == 2) ? w4[j].z : w4[j].w;
        acc[j] += bf2f((ushort_t)v[j]) * wv;
      }
    }
  }
  short8 o;
  #pragma unroll
  for (int j = 0; j < 8; ++j) {
    const float v = acc[j] / (1.f + __expf(-acc[j]));
    o[j] = (short)f2bf(v);
  }
  *reinterpret_cast<short8*>(&xc16[(size_t)bl * DINNER + e0]) = o;
}

// ---------------------------------------------------------------------------
// Pass A: lane-per-(b,c,e), 16 states in registers; bf16 in, bf16 P/H out.
__global__ __launch_bounds__(256) void scan_chunk_kernel(
    const ushort_t* __restrict__ d16,  // (ROWS, DINNER) softplus'd delta, bf16
    const ushort_t* __restrict__ xc16, // (ROWS, DINNER) bf16
    const float* __restrict__ dbcBC,   // (ROWS, 32): [0..16)=B
    const float* __restrict__ A_log,   // (DINNER, 16)
    ushort_t* __restrict__ P16,        // (BATCH, NCHUNK, DINNER, 16) bf16
    ushort_t* __restrict__ H16)        // (BATCH, NCHUNK, DINNER, 16) bf16
{
  __shared__ float sB[CHUNK][16];
  const int bc = blockIdx.y;               // b*NCHUNK + c
  const int b = bc / NCHUNK, c = bc % NCHUNK;
  const int e = blockIdx.x * 256 + threadIdx.x;
  const size_t row32 = ((size_t)b * SEQ + c * CHUNK) * 32;
  #pragma unroll
  for (int p = 0; p < (CHUNK * 16) / 256; ++p) {
    const int idx = threadIdx.x + p * 256;
    sB[idx >> 4][idx & 15] = dbcBC[row32 + (idx >> 4) * 32 + (idx & 15)];
  }
  float Aen[16];
  #pragma unroll
  for (int q = 0; q < 4; ++q) {
    const float4 a4 = *reinterpret_cast<const float4*>(&A_log[(size_t)e * 16 + q * 4]);
    Aen[q * 4 + 0] = -__expf(a4.x);
    Aen[q * 4 + 1] = -__expf(a4.y);
    Aen[q * 4 + 2] = -__expf(a4.z);
    Aen[q * 4 + 3] = -__expf(a4.w);
  }
  __syncthreads();

  float h[16];
  #pragma unroll
  for (int n = 0; n < 16; ++n) h[n] = 0.f;
  float sd = 0.f;
  const size_t rowE = ((size_t)b * SEQ + c * CHUNK) * DINNER + e;
  float dv = bf2f(d16[rowE]), xv = bf2f(xc16[rowE]);
  for (int t = 0; t < CHUNK; ++t) {
    float dvn = 0.f, xvn = 0.f;
    if (t + 1 < CHUNK) {
      dvn = bf2f(d16[rowE + (size_t)(t + 1) * DINNER]);
      xvn = bf2f(xc16[rowE + (size_t)(t + 1) * DINNER]);
    }
    const float dxv = dv * xv;
    sd += dv;
    #pragma unroll
    for (int n = 0; n < 16; ++n) {
      const float dA = __expf(dv * Aen[n]);
      h[n] = dA * h[n] + dxv * sB[t][n];
    }
    dv = dvn; xv = xvn;
  }
  const size_t o = ((size_t)bc * DINNER + e) * 16;
  #pragma unroll
  for (int q = 0; q < 4; ++q) {
    ushort4 pv, hv;
    pv.x = f2bf(__expf(Aen[q * 4 + 0] * sd));
    pv.y = f2bf(__expf(Aen[q * 4 + 1] * sd));
    pv.z = f2bf(__expf(Aen[q * 4 + 2] * sd));
    pv.w = f2bf(__expf(Aen[q * 4 + 3] * sd));
    hv.x = f2bf(h[q * 4 + 0]); hv.y = f2bf(h[q * 4 + 1]);
    hv.z = f2bf(h[q * 4 + 2]); hv.w = f2bf(h[q * 4 + 3]);
    *reinterpret_cast<ushort4*>(&P16[o + q * 4]) = pv;
    *reinterpret_cast<ushort4*>(&H16[o + q * 4]) = hv;
  }
}

// ---------------------------------------------------------------------------
// Pass B: serial combine over NCHUNK summaries; one thread per (b,e,n).
__global__ __launch_bounds__(256) void scan_combine_kernel(
    const ushort_t* __restrict__ P16, ushort_t* __restrict__ H16)
{
  const int idx = blockIdx.x * 256 + threadIdx.x;   // b*(DINNER*16) + e*16 + n
  const int b = idx >> 15;
  const int en = idx & (DINNER * 16 - 1);
  const size_t base = (size_t)b * NCHUNK * DINNER * 16 + en;
  float H = 0.f;
  float P = bf2f(P16[base]), hf = bf2f(H16[base]);
  for (int c = 0; c < NCHUNK; ++c) {
    const size_t o = base + (size_t)c * DINNER * 16;
    float Pn = 0.f, hfn = 0.f;
    if (c + 1 < NCHUNK) {
      const size_t on = o + (size_t)DINNER * 16;
      Pn = bf2f(P16[on]); hfn = bf2f(H16[on]);
    }
    H16[o] = f2bf(H);
    H = P * H + hf;
    P = Pn; hf = hfn;
  }
}

// ---------------------------------------------------------------------------
// Pass C: seeded re-scan fused with C-dot, D skip, z gate -> bf16 yz.
__global__ __launch_bounds__(256) void scan_out_kernel(
    const ushort_t* __restrict__ d16,  // (ROWS, DINNER) bf16
    const ushort_t* __restrict__ xc16, // (ROWS, DINNER) bf16
    const float* __restrict__ dbcBC,   // (ROWS, 32)
    const ushort_t* __restrict__ xz16, // (ROWS, 2*DINNER): z at col DINNER+e
    const float* __restrict__ A_log,   // (DINNER, 16)
    const float* __restrict__ Dp,      // (DINNER)
    const ushort_t* __restrict__ H16,  // [b][c][e][n] seeds (bf16)
    ushort_t* __restrict__ yz16)       // (ROWS, DINNER) bf16 out
{
  __shared__ float sB[CHUNK][16];
  __shared__ float sC[CHUNK][16];
  const int bc = blockIdx.y;
  const int b = bc / NCHUNK, c = bc % NCHUNK;
  const int e = blockIdx.x * 256 + threadIdx.x;
  const size_t row32 = ((size_t)b * SEQ + c * CHUNK) * 32;
  #pragma unroll
  for (int p = 0; p < (CHUNK * 32) / 256; ++p) {
    const int idx = threadIdx.x + p * 256;
    const int t = idx >> 5, j = idx & 31;
    const float v = dbcBC[row32 + t * 32 + j];
    if (j < 16) sB[t][j] = v; else sC[t][j - 16] = v;
  }
  float Aen[16];
  #pragma unroll
  for (int q = 0; q < 4; ++q) {
    const float4 a4 = *reinterpret_cast<const float4*>(&A_log[(size_t)e * 16 + q * 4]);
    Aen[q * 4 + 0] = -__expf(a4.x);
    Aen[q * 4 + 1] = -__expf(a4.y);
    Aen[q * 4 + 2] = -__expf(a4.z);
    Aen[q * 4 + 3] = -__expf(a4.w);
  }
  float h[16];
  const size_t oh = ((size_t)bc * DINNER + e) * 16;
  #pragma unroll
  for (int q = 0; q < 4; ++q) {
    const ushort4 hv = *reinterpret_cast<const ushort4*>(&H16[oh + q * 4]);
    h[q * 4 + 0] = bf2f(hv.x); h[q * 4 + 1] = bf2f(hv.y);
    h[q * 4 + 2] = bf2f(hv.z); h[q * 4 + 3] = bf2f(hv.w);
  }
  const float dpe = Dp[e];
  __syncthreads();

  const size_t rowE = ((size_t)b * SEQ + c * CHUNK) * DINNER + e;
  const size_t rowZ = ((size_t)b * SEQ + c * CHUNK) * (2 * DINNER) + DINNER + e;
  float dv = bf2f(d16[rowE]), xv = bf2f(xc16[rowE]);
  float zv = bf2f(xz16[rowZ]);
  for (int t = 0; t < CHUNK; ++t) {
    float dvn = 0.f, xvn = 0.f, zvn = 0.f;
    if (t + 1 < CHUNK) {
      dvn = bf2f(d16[rowE + (size_t)(t + 1) * DINNER]);
      xvn = bf2f(xc16[rowE + (size_t)(t + 1) * DINNER]);
      zvn = bf2f(xz16[rowZ + (size_t)(t + 1) * (2 * DINNER)]);
    }
    const float dxv = dv * xv;
    float y = dpe * xv;
    #pragma unroll
    for (int n = 0; n < 16; ++n) {
      const float dA = __expf(dv * Aen[n]);
      h[n] = dA * h[n] + dxv * sB[t][n];
      y += h[n] * sC[t][n];
    }
    const float sz = zv / (1.f + __expf(-zv));
    yz16[rowE + (size_t)t * DINNER] = f2bf(y * sz);
    dv = dvn; xv = xvn; zv = zvn;
  }
}

// ---------------------------------------------------------------------------
extern "C" void kernel_launch(void* const* d_in, const int* in_sizes, int n_in,
                              void* d_out, int out_size, void* d_ws, size_t ws_size,
                              hipStream_t stream)
{
  const float* x         = (const float*)d_in[0];
  const float* norm_w    = (const float*)d_in[1];
  const float* in_proj_w = (const float*)d_in[2];
  const float* conv_w    = (const float*)d_in[3];
  const float* conv_b    = (const float*)d_in[4];
  const float* x_proj_w  = (const float*)d_in[5];
  const float* dt_proj_w = (const float*)d_in[6];
  const float* dt_proj_b = (const float*)d_in[7];
  const float* A_log     = (const float*)d_in[8];
  const float* D_param   = (const float*)d_in[9];
  const float* out_proj_w= (const float*)d_in[10];
  float* out = (float*)d_out;

  // Workspace (float offsets), total 20.25M floats = 81 MB.  ws_size is
  // 256 MB (poison fill WRITE_SIZE = 262144 KB) -> all regions DISJOINT
  // except partO, which aliases xz16 (xz16 dead after scanC; partO written
  // in step 9 which launches after scanC on the same stream).
  const size_t M = 1024 * 1024;
  float* ws = (float*)d_ws;
  ushort_t* w16i_all = (ushort_t*)ws;                 // [0,4M)    persistent
  ushort_t* w16o_all = (ushort_t*)(ws + 4 * M);       // [4M,6M)   persistent
  ushort_t* xpw16_all= (ushort_t*)(ws + 6 * M);       // 192K fl   persistent
  ushort_t* dtw16_all= (ushort_t*)(ws + 6 * M + 196608); // 128K fl persistent
  float* dbcBC    = ws + 6 * M + 327680;              // 64K fl
  ushort_t* dl16  = (ushort_t*)(ws + 6 * M + 393216); // 64K fl
  ushort_t* xz16  = (ushort_t*)(ws + 6 * M + 524288); // [6.5M,10.5M)
  ushort_t* partO = xz16;                             // alias (time-disjoint)
  ushort_t* xc16  = (ushort_t*)(ws + 10 * M + 524288);// [10.5M,12.5M)
  ushort_t* d16   = (ushort_t*)(ws + 12 * M + 524288);// [12.5M,14.5M)
  ushort_t* P16   = (ushort_t*)(ws + 14 * M + 524288);// [14.5M,15.5M)
  ushort_t* H16   = (ushort_t*)(ws + 15 * M + 524288);// [15.5M,16.5M)
  ushort_t* yz16  = (ushort_t*)(ws + 16 * M + 524288);// [16.5M,18.5M)
  ushort_t* h16   = (ushort_t*)(ws + 18 * M + 524288);// [18.5M,19.5M)
  ushort_t* partX = (ushort_t*)(ws + 19 * M + 524288);// [19.5M,20.25M)

  // Upfront: cast ALL layers' weights to bf16 (weights are layer-contiguous).
  cast_bf16_kernel<<<NLAYERS * 2 * DINNER * DMODEL / 1024, 256, 0, stream>>>(
      in_proj_w, w16i_all);
  cast_bf16_kernel<<<NLAYERS * DMODEL * DINNER / 1024, 256, 0, stream>>>(
      out_proj_w, w16o_all);
  cast_bf16_kernel<<<NLAYERS * 96 * DINNER / 1024, 256, 0, stream>>>(
      x_proj_w, xpw16_all);
  cast_bf16_kernel<<<NLAYERS * DINNER * DTRANK / 1024, 256, 0, stream>>>(
      dt_proj_w, dtw16_all);

  // Init: residual = x, h16 = rms(x) * norm_w[0]
  init_rms_kernel<<<ROWS, 256, 0, stream>>>(x, norm_w, out, h16);

  for (int layer = 0; layer < NLAYERS; ++layer) {
    const float* cw  = conv_w     + (size_t)layer * DINNER * DCONV;
    const float* cb  = conv_b     + (size_t)layer * DINNER;
    const float* dtb = dt_proj_b  + (size_t)layer * DINNER;
    const float* Al  = A_log      + (size_t)layer * DINNER * DSTATE;
    const float* Dpp = D_param    + (size_t)layer * DINNER;
    const ushort_t* w16i  = w16i_all  + (size_t)layer * 2 * DINNER * DMODEL;
    const ushort_t* w16o  = w16o_all  + (size_t)layer * DMODEL * DINNER;
    const ushort_t* xpw16 = xpw16_all + (size_t)layer * 96 * DINNER;
    const ushort_t* dtw16 = dtw16_all + (size_t)layer * DINNER * DTRANK;

    // 1. xz = h @ in_w^T (bf16 MFMA) -> bf16 xz16 (both halves)
    gemm_bf16_kernel<2>
        <<<dim3(2 * DINNER / 128, ROWS / 128), 256, 0, stream>>>(
            h16, w16i, xz16, nullptr, DMODEL, DMODEL, DMODEL, 2 * DINNER);

    // 2. xc16 = bf16(silu(causal_conv(xz16[:, :DINNER]) + cb))
    conv_silu_kernel<<<(size_t)ROWS * DINNER / 8 / 256, 256, 0, stream>>>(
        xz16, cw, cb, xc16);

    // 3+4. dbc = xc @ xpw^T  (bf16 MFMA split-K + reduce)
    xproj_mfma_kernel<<<dim3(KSPLIT, ROWS / 128), 256, 0, stream>>>(
        xc16, xpw16, partX);
    xproj_reduce_kernel<<<ROWS * 96 / 256, 256, 0, stream>>>(
        partX, dbcBC, dl16);

    // 5. delta = softplus(dl16 @ dtw^T + dtb) -> bf16 d16
    gemm_bf16_kernel<3>
        <<<dim3(DINNER / 128, ROWS / 128), 256, 0, stream>>>(
            dl16, dtw16, d16, dtb, DTRANK, DTRANK, DTRANK, DINNER);

    // 6-8. chunked selective scan + D skip + z gate -> yz16
    scan_chunk_kernel<<<dim3(DINNER / 256, BATCH * NCHUNK), 256, 0, stream>>>(
        d16, xc16, dbcBC, Al, P16, H16);
    scan_combine_kernel<<<BATCH * DINNER * 16 / 256, 256, 0, stream>>>(
        P16, H16);
    scan_out_kernel<<<dim3(DINNER / 256, BATCH * NCHUNK), 256, 0, stream>>>(
        d16, xc16, dbcBC, xz16, Al, Dpp, H16, yz16);

    // 9. out_proj split-K (bf16 partials; partO aliases xz16 - now dead)
    outproj_splitk_kernel
        <<<dim3(DMODEL / 128, ROWS / 128, KSO), 256, 0, stream>>>(
            yz16, w16o, partO);

    // 10. residual += sum_z partO[z]; fuse next layer's rmsnorm
    if (layer + 1 < NLAYERS) {
      outproj_reduce_rms_kernel<true><<<ROWS, 256, 0, stream>>>(
          partO, norm_w + (size_t)(layer + 1) * DMODEL, out, h16);
    } else {
      outproj_reduce_rms_kernel<false><<<ROWS, 256, 0, stream>>>(
          partO, nullptr, out, nullptr);
    }
  }
}